// Round 5
// baseline (1229.449 us; speedup 1.0000x reference)
//
#include <hip/hip_runtime.h>
#include <hip/hip_bf16.h>

#define N_ 2
#define C_ 64
#define D_ 8
#define H_ 56
#define W_ 56
#define HW_ (H_*W_)        // 3136
#define P_ (D_*HW_)        // 25088
#define G_ 8
#define CPG_ 8
#define K_ 27
#define CO_OFF_ 648        // G * 3 * K
#define MP_ 768            // conv_off M padded to 6*128
#define KK_ 1728           // GEMM K dim (= 64*27)
#define KB_ (KK_*2)        // bytes per bf16 row of A / Bt

typedef __attribute__((ext_vector_type(8))) short shortx8;
typedef __attribute__((ext_vector_type(4))) float floatx4;
#define AS1 __attribute__((address_space(1)))
#define AS3 __attribute__((address_space(3)))

__device__ inline float b2f(unsigned short u) {
    union { unsigned u; float f; } x; x.u = ((unsigned)u) << 16; return x.f;
}
__device__ inline unsigned short f2b(float f) {
    union { float f; unsigned u; } x; x.f = f;
    unsigned r = (x.u + 0x7fffu + ((x.u >> 16) & 1u)) >> 16;   // RNE
    return (unsigned short)r;
}
__device__ inline float lof(unsigned u) { union { unsigned u; float f; } x; x.u = u << 16; return x.f; }
__device__ inline float hif(unsigned u) { union { unsigned u; float f; } x; x.u = u & 0xffff0000u; return x.f; }

// ---------------------------------------------------------------------------
__global__ __launch_bounds__(256) void cast_f2b_kernel(
    const float* __restrict__ src, unsigned short* __restrict__ dst, int count)
{
    int i = blockIdx.x*256 + threadIdx.x;
    if (i < count) dst[i] = f2b(src[i]);
}

// w_off [648][1728] fp32 -> A1 [768][1728] bf16, zero rows >= 648
__global__ __launch_bounds__(256) void pad_w_kernel(
    const float* __restrict__ w, unsigned short* __restrict__ A)
{
    int i = blockIdx.x*256 + threadIdx.x;
    if (i >= MP_*KK_) return;
    int row = i / KK_;
    A[i] = (row < CO_OFF_) ? f2b(w[i]) : (unsigned short)0;
}

// w1 [O=64][I=64][Ktap=27] fp32 -> A1t[o][k*64+i] bf16 (k-major K-order)
__global__ __launch_bounds__(256) void perm_w1_kernel(
    const float* __restrict__ w1, unsigned short* __restrict__ A1t)
{
    int tid = blockIdx.x*256 + threadIdx.x;
    if (tid >= C_*KK_) return;
    int o  = tid / KK_;
    int r  = tid % KK_;
    int k  = r / 64, i = r % 64;
    A1t[tid] = f2b(w1[((size_t)o*C_ + i)*K_ + k]);
}

// xb [N][64][P] bf16 -> xt [N][P][64] bf16  (64p x 64c LDS tile transpose)
__global__ __launch_bounds__(256) void transpose_xt_kernel(
    const unsigned short* __restrict__ xb, unsigned short* __restrict__ xt)
{
    __shared__ unsigned short tile[64][65];
    int b  = blockIdx.x;
    int n  = b / (P_/64);
    int p0 = (b % (P_/64))*64;
    int tid = threadIdx.x;
    int j  = tid & 63;
    int c0 = (tid >> 6)*16;
    for (int r = 0; r < 16; ++r)
        tile[c0 + r][j] = xb[((size_t)n*C_ + c0 + r)*P_ + p0 + j];
    __syncthreads();
    unsigned* dst = (unsigned*)(xt + ((size_t)n*P_ + p0)*C_);
    #pragma unroll
    for (int it = 0; it < 8; ++it) {
        int wi  = it*256 + tid;
        int row = wi >> 5;
        int c   = (wi & 31)*2;
        unsigned lo = tile[c][row], hi = tile[c+1][row];
        dst[(size_t)row*32 + (wi & 31)] = lo | (hi << 16);
    }
}

// ---------------------------------------------------------------------------
// p-major im2col for conv_off: Bt[p][ci*27+kk], full P
// ---------------------------------------------------------------------------
__global__ __launch_bounds__(256) void im2col_kernel(
    const unsigned short* __restrict__ src,   // [64][P_] bf16 (pre-offset by n)
    unsigned short* __restrict__ Bt)          // [P_][1728] bf16
{
    int wave = threadIdx.x >> 6, lane = threadIdx.x & 63;
    int p = blockIdx.x*4 + wave;
    int d = p / HW_, hw = p % HW_;
    int h = hw / W_, w = hw % W_;
    unsigned short* dst = Bt + (size_t)p*KK_;
    #pragma unroll
    for (int i = 0; i < 27; ++i) {
        int idx = i*64 + lane;
        int ci = idx / 27, kk = idx % 27;
        int kd = kk/9 - 1;
        int r9 = kk % 9;
        int kh = r9/3 - 1, kw = r9%3 - 1;
        bool v = ((unsigned)(d+kd) < (unsigned)D_) &&
                 ((unsigned)(h+kh) < (unsigned)H_) &&
                 ((unsigned)(w+kw) < (unsigned)W_);
        unsigned short bits = 0;
        if (v) bits = src[(size_t)ci*P_ + p + kd*HW_ + kh*W_ + kw];
        dst[idx] = bits;
    }
}

// im2col for conv2 with fused BN1+ReLU on the read
__global__ __launch_bounds__(256) void im2col_bn_kernel(
    const unsigned short* __restrict__ src,   // y1 raw [64][P_] bf16
    const float* __restrict__ stats,
    const float* __restrict__ gamma, const float* __restrict__ beta,
    unsigned short* __restrict__ Bt)
{
    int wave = threadIdx.x >> 6, lane = threadIdx.x & 63;
    int p = blockIdx.x*4 + wave;
    int d = p / HW_, hw = p % HW_;
    int h = hw / W_, w = hw % W_;
    unsigned short* dst = Bt + (size_t)p*KK_;
    #pragma unroll
    for (int i = 0; i < 27; ++i) {
        int idx = i*64 + lane;
        int ci = idx / 27, kk = idx % 27;
        int kd = kk/9 - 1;
        int r9 = kk % 9;
        int kh = r9/3 - 1, kw = r9%3 - 1;
        bool v = ((unsigned)(d+kd) < (unsigned)D_) &&
                 ((unsigned)(h+kh) < (unsigned)H_) &&
                 ((unsigned)(w+kw) < (unsigned)W_);
        unsigned short bits = 0;
        if (v) {
            float val = b2f(src[(size_t)ci*P_ + p + kd*HW_ + kh*W_ + kw]);
            val = fmaxf((val - stats[ci])*stats[C_+ci]*gamma[ci] + beta[ci], 0.f);
            bits = f2b(val);
        }
        dst[idx] = bits;
    }
}

// ---------------------------------------------------------------------------
// Deform gather: thread = (k, p), loops g=0..7 internally.
// The 8 g-chunks Bt[p][k*64 + g*8 + c] are ONE 128-B cache line, fully
// written by this thread (8x 16-B stores) -> no cross-block RMW.
// ---------------------------------------------------------------------------
__global__ __launch_bounds__(256) void gather_kernel(
    const unsigned short* __restrict__ xt,   // [N][P][64] bf16
    const unsigned short* __restrict__ off,  // [G][K][3][P] bf16 (per-n)
    unsigned short* __restrict__ Bt,         // [P_][1728] bf16 (k-major)
    int n)
{
    int bid  = blockIdx.x;
    int pblk = bid % (P_/256);
    int k    = bid / (P_/256);       // 0..26
    int p = pblk*256 + threadIdx.x;
    int d = p / HW_, hw = p % HW_;
    int h = hw / W_, w = hw % W_;
    int kd = k/9 - 1, kh = (k/3)%3 - 1, kw = k%3 - 1;
    float bpd = (float)(d + kd);
    float bph = (float)(h + kh);
    float bpw = (float)(w + kw);

    const uint4* xg0 = (const uint4*)(xt + ((size_t)n*P_)*C_);
    unsigned short* dstrow = Bt + (size_t)p*KK_ + k*64;

    for (int g = 0; g < G_; ++g) {
        size_t ob = (((size_t)g*K_ + k)*3)*P_ + p;
        float pd = bpd + b2f(off[ob]);
        float ph = bph + b2f(off[ob + P_]);
        float pw = bpw + b2f(off[ob + 2*(size_t)P_]);
        float fd0 = floorf(pd), fh0 = floorf(ph), fw0 = floorf(pw);
        int d0 = (int)fd0, h0 = (int)fh0, w0i = (int)fw0;
        float fd = pd - fd0, fh = ph - fh0, fw = pw - fw0;

        const uint4* xg = xg0 + g;   // + g*8 bf16 = g-th uint4 of the row
        float res[CPG_];
        #pragma unroll
        for (int c = 0; c < CPG_; ++c) res[c] = 0.f;
        #pragma unroll
        for (int cd = 0; cd < 2; ++cd) {
            int id = d0 + cd;
            float wdt = cd ? fd : 1.f - fd;
            bool vdd = (unsigned)id < (unsigned)D_;
            int idc = min(max(id, 0), D_-1);
            #pragma unroll
            for (int ch = 0; ch < 2; ++ch) {
                int ih = h0 + ch;
                float wht = ch ? fh : 1.f - fh;
                bool vhh = (unsigned)ih < (unsigned)H_;
                int ihc = min(max(ih, 0), H_-1);
                #pragma unroll
                for (int cw = 0; cw < 2; ++cw) {
                    int iw = w0i + cw;
                    float wwt = cw ? fw : 1.f - fw;
                    bool vww = (unsigned)iw < (unsigned)W_;
                    int iwc = min(max(iw, 0), W_-1);
                    float wgt = (vdd && vhh && vww) ? wdt*wht*wwt : 0.f;
                    int lin = (idc*H_ + ihc)*W_ + iwc;
                    uint4 v4 = xg[(size_t)lin*(C_/8)];
                    res[0] = fmaf(wgt, lof(v4.x), res[0]);
                    res[1] = fmaf(wgt, hif(v4.x), res[1]);
                    res[2] = fmaf(wgt, lof(v4.y), res[2]);
                    res[3] = fmaf(wgt, hif(v4.y), res[3]);
                    res[4] = fmaf(wgt, lof(v4.z), res[4]);
                    res[5] = fmaf(wgt, hif(v4.z), res[5]);
                    res[6] = fmaf(wgt, lof(v4.w), res[6]);
                    res[7] = fmaf(wgt, hif(v4.w), res[7]);
                }
            }
        }
        uint4 o4;
        o4.x = (unsigned)f2b(res[0]) | ((unsigned)f2b(res[1]) << 16);
        o4.y = (unsigned)f2b(res[2]) | ((unsigned)f2b(res[3]) << 16);
        o4.z = (unsigned)f2b(res[4]) | ((unsigned)f2b(res[5]) << 16);
        o4.w = (unsigned)f2b(res[6]) | ((unsigned)f2b(res[7]) << 16);
        *(uint4*)(dstrow + g*CPG_) = o4;
    }
}

// ---------------------------------------------------------------------------
// 128x128 MFMA GEMM (m97 structure): M=768, N=P_, K=1728, BK=32.
// ---------------------------------------------------------------------------
__global__ __launch_bounds__(256) void gemm128_kernel(
    const unsigned short* __restrict__ A,    // [768][1728] bf16
    const unsigned short* __restrict__ Bt,   // [P_][1728] bf16
    const float* __restrict__ bias,          // [648]
    unsigned short* __restrict__ out)        // out[co*P_ + col], co < 648
{
    __shared__ __align__(16) short As[8*512];
    __shared__ __align__(16) short Bs[8*512];
    int w = threadIdx.x >> 6, lane = threadIdx.x & 63;
    int bid = blockIdx.x, mt, nt;
    if (bid < 1152) { int c = bid/48, r = bid%48; mt = r >> 3; nt = c*8 + (r&7); }
    else            { int r = bid - 1152;         mt = r >> 2; nt = 192 + (r&3); }
    int m0 = mt*128, p0 = nt*128;
    int lm = lane & 15, lq = lane >> 4;

    const char* Ab = (const char*)A  + (size_t)(m0 + w*32 + lm)*KB_ + lq*16;
    const char* Bb = (const char*)Bt + (size_t)(p0 + w*32 + lm)*KB_ + lq*16;

    auto ldsA0 = (AS3 unsigned*)(As + (2*w)*512);
    auto ldsA1 = (AS3 unsigned*)(As + (2*w+1)*512);
    auto ldsB0 = (AS3 unsigned*)(Bs + (2*w)*512);
    auto ldsB1 = (AS3 unsigned*)(Bs + (2*w+1)*512);

    int mh = w >> 1, nh = w & 1;
    floatx4 acc[4][4];
    #pragma unroll
    for (int i = 0; i < 4; ++i)
        #pragma unroll
        for (int j = 0; j < 4; ++j)
            acc[i][j] = (floatx4){0.f, 0.f, 0.f, 0.f};

    for (int kt = 0; kt < 54; ++kt) {
        __syncthreads();
        __builtin_amdgcn_global_load_lds((const AS1 unsigned*)(Ab + kt*64),              ldsA0, 16, 0, 0);
        __builtin_amdgcn_global_load_lds((const AS1 unsigned*)(Ab + 16*KB_ + kt*64),     ldsA1, 16, 0, 0);
        __builtin_amdgcn_global_load_lds((const AS1 unsigned*)(Bb + kt*64),              ldsB0, 16, 0, 0);
        __builtin_amdgcn_global_load_lds((const AS1 unsigned*)(Bb + 16*KB_ + kt*64),     ldsB1, 16, 0, 0);
        __syncthreads();
        shortx8 a[4], b[4];
        #pragma unroll
        for (int i = 0; i < 4; ++i) a[i] = *(const shortx8*)&As[(4*mh+i)*512 + lane*8];
        #pragma unroll
        for (int j = 0; j < 4; ++j) b[j] = *(const shortx8*)&Bs[(4*nh+j)*512 + lane*8];
        #pragma unroll
        for (int i = 0; i < 4; ++i)
            #pragma unroll
            for (int j = 0; j < 4; ++j)
                acc[i][j] = __builtin_amdgcn_mfma_f32_16x16x32_bf16(a[i], b[j], acc[i][j], 0, 0, 0);
    }

    #pragma unroll
    for (int i = 0; i < 4; ++i) {
        int cob = m0 + (4*mh+i)*16 + lq*4;
        #pragma unroll
        for (int r = 0; r < 4; ++r) {
            int co = cob + r;
            if (co < CO_OFF_) {
                float bv = bias[co];
                #pragma unroll
                for (int j = 0; j < 4; ++j) {
                    int col = p0 + (4*nh+j)*16 + lm;
                    out[(size_t)co*P_ + col] = f2b(acc[i][j][r] + bv);
                }
            }
        }
    }
}

// ---------------------------------------------------------------------------
// 64x64 MFMA GEMM, BK=64: M=64, N=P_, K=1728 in 27 steps.
// ---------------------------------------------------------------------------
__global__ __launch_bounds__(256) void gemm64_kernel(
    const unsigned short* __restrict__ A,    // [64][1728] bf16
    const unsigned short* __restrict__ Bt,   // [P_][1728] bf16
    const float* __restrict__ bias,          // [64] or nullptr
    unsigned short* __restrict__ out)        // out[co*P_ + col]
{
    __shared__ __align__(16) short As[8*512];
    __shared__ __align__(16) short Bs[8*512];
    int w = threadIdx.x >> 6, lane = threadIdx.x & 63;
    int p0 = blockIdx.x*64;
    int lm = lane & 15, lq = lane >> 4;

    const char* Ab = (const char*)A  + (size_t)(w*16 + lm)*KB_ + lq*16;
    const char* Bb = (const char*)Bt + (size_t)(p0 + w*16 + lm)*KB_ + lq*16;

    auto ldsA0 = (AS3 unsigned*)(As + w*512);
    auto ldsA1 = (AS3 unsigned*)(As + (4+w)*512);
    auto ldsB0 = (AS3 unsigned*)(Bs + w*512);
    auto ldsB1 = (AS3 unsigned*)(Bs + (4+w)*512);

    int mh = w >> 1, nh = w & 1;
    floatx4 acc[2][2];
    #pragma unroll
    for (int i = 0; i < 2; ++i)
        #pragma unroll
        for (int j = 0; j < 2; ++j)
            acc[i][j] = (floatx4){0.f, 0.f, 0.f, 0.f};

    for (int kt = 0; kt < 27; ++kt) {
        __syncthreads();
        __builtin_amdgcn_global_load_lds((const AS1 unsigned*)(Ab + kt*128),      ldsA0, 16, 0, 0);
        __builtin_amdgcn_global_load_lds((const AS1 unsigned*)(Ab + kt*128 + 64), ldsA1, 16, 0, 0);
        __builtin_amdgcn_global_load_lds((const AS1 unsigned*)(Bb + kt*128),      ldsB0, 16, 0, 0);
        __builtin_amdgcn_global_load_lds((const AS1 unsigned*)(Bb + kt*128 + 64), ldsB1, 16, 0, 0);
        __syncthreads();
        #pragma unroll
        for (int ks = 0; ks < 2; ++ks) {
            shortx8 a[2], b[2];
            #pragma unroll
            for (int i = 0; i < 2; ++i) a[i] = *(const shortx8*)&As[(ks*4 + 2*mh+i)*512 + lane*8];
            #pragma unroll
            for (int j = 0; j < 2; ++j) b[j] = *(const shortx8*)&Bs[(ks*4 + 2*nh+j)*512 + lane*8];
            #pragma unroll
            for (int i = 0; i < 2; ++i)
                #pragma unroll
                for (int j = 0; j < 2; ++j)
                    acc[i][j] = __builtin_amdgcn_mfma_f32_16x16x32_bf16(a[i], b[j], acc[i][j], 0, 0, 0);
        }
    }

    #pragma unroll
    for (int i = 0; i < 2; ++i) {
        int cob = (2*mh+i)*16 + lq*4;
        #pragma unroll
        for (int r = 0; r < 4; ++r) {
            int co = cob + r;
            float bv = bias ? bias[co] : 0.f;
            #pragma unroll
            for (int j = 0; j < 2; ++j) {
                int col = p0 + (2*nh+j)*16 + lm;
                out[(size_t)co*P_ + col] = f2b(acc[i][j][r] + bv);
            }
        }
    }
}

// ---------------------------------------------------------------------------
__global__ __launch_bounds__(256) void bn_stats_kernel(
    const unsigned short* __restrict__ src, float* __restrict__ stats)
{
    int c   = blockIdx.x;
    int tid = threadIdx.x;
    float s = 0.f, q = 0.f;
    for (int n = 0; n < N_; ++n) {
        const unsigned short* p = src + ((size_t)n*C_ + c)*P_;
        for (int i = tid; i < P_; i += 256) {
            float v = b2f(p[i]);
            s += v;
            q = fmaf(v, v, q);
        }
    }
    #pragma unroll
    for (int o = 32; o; o >>= 1) {
        s += __shfl_down(s, o);
        q += __shfl_down(q, o);
    }
    __shared__ float sh[2][4];
    int wave = tid >> 6;
    if ((tid & 63) == 0) { sh[0][wave] = s; sh[1][wave] = q; }
    __syncthreads();
    if (tid == 0) {
        float S = sh[0][0] + sh[0][1] + sh[0][2] + sh[0][3];
        float Q = sh[1][0] + sh[1][1] + sh[1][2] + sh[1][3];
        const float inv = 1.f / (float)(N_*P_);
        float m  = S * inv;
        float var = Q * inv - m*m;
        stats[c]      = m;
        stats[C_ + c] = rsqrtf(var + 1e-5f);
    }
}

// out = relu(gamma*(y2-mean)*rstd + beta + x)   fp32 out
__global__ __launch_bounds__(256) void bn_add_relu_kernel(
    const unsigned short* __restrict__ y2, const float* __restrict__ x,
    const float* __restrict__ stats,
    const float* __restrict__ gamma, const float* __restrict__ beta,
    float* __restrict__ out)
{
    size_t idx = (size_t)blockIdx.x*256 + threadIdx.x;
    int c = (int)((idx / P_) % C_);
    float v = (b2f(y2[idx]) - stats[c]) * stats[C_ + c] * gamma[c] + beta[c] + x[idx];
    out[idx] = fmaxf(v, 0.f);
}

// ---------------------------------------------------------------------------
extern "C" void kernel_launch(void* const* d_in, const int* in_sizes, int n_in,
                              void* d_out, int out_size, void* d_ws, size_t ws_size,
                              hipStream_t stream) {
    const float* x     = (const float*)d_in[0];
    const float* w_off = (const float*)d_in[1];
    const float* b_off = (const float*)d_in[2];
    const float* w1    = (const float*)d_in[3];
    const float* g1    = (const float*)d_in[4];
    const float* be1   = (const float*)d_in[5];
    const float* w2    = (const float*)d_in[6];
    const float* b2    = (const float*)d_in[7];
    const float* g2    = (const float*)d_in[8];
    const float* be2   = (const float*)d_in[9];
    float* out = (float*)d_out;

    // workspace (~148 MB; 149 MB proven safe in Round 1)
    float* st1 = (float*)d_ws;                               // 128
    float* st2 = st1 + 128;                                  // 128
    unsigned short* Bt  = (unsigned short*)(st2 + 128);      // P_*1728 (86.7 MB, reused)
    unsigned short* off = Bt  + (size_t)P_*KK_;              // 648*P bf16 (32.5 MB, per-n)
    unsigned short* xb  = off + (size_t)CO_OFF_*P_;          // N*64*P bf16 (6.4 MB)
    unsigned short* xt  = xb  + (size_t)N_*C_*P_;            // N*P*64 bf16 (6.4 MB)
    unsigned short* y1  = xt  + (size_t)N_*C_*P_;            // N*64*P bf16 (6.4 MB)
    unsigned short* y2  = y1  + (size_t)N_*C_*P_;            // N*64*P bf16 (6.4 MB)
    unsigned short* A1  = y2  + (size_t)N_*C_*P_;            // 768*1728 bf16 (2.65 MB)
    unsigned short* A2  = A1  + (size_t)MP_*KK_;             // 64*1728 bf16
    unsigned short* A1t = A2  + (size_t)C_*KK_;              // 64*1728 bf16

    // prep
    cast_f2b_kernel<<<(N_*C_*P_+255)/256, 256, 0, stream>>>(x, xb, N_*C_*P_);
    transpose_xt_kernel<<<N_*(P_/64), 256, 0, stream>>>(xb, xt);
    pad_w_kernel<<<(MP_*KK_+255)/256, 256, 0, stream>>>(w_off, A1);
    cast_f2b_kernel<<<(C_*KK_+255)/256, 256, 0, stream>>>(w2, A2, C_*KK_);
    perm_w1_kernel<<<(C_*KK_+255)/256, 256, 0, stream>>>(w1, A1t);

    // per-n: conv_off (im2col + 128-tile GEMM) then deform (gather + 64-tile GEMM)
    for (int n = 0; n < N_; ++n) {
        im2col_kernel<<<P_/4, 256, 0, stream>>>(xb + (size_t)n*C_*P_, Bt);
        gemm128_kernel<<<1176, 256, 0, stream>>>(A1, Bt, b_off, off);
        gather_kernel<<<27*(P_/256), 256, 0, stream>>>(xt, off, Bt, n);
        gemm64_kernel<<<P_/64, 256, 0, stream>>>(A1t, Bt, (const float*)nullptr,
            y1 + (size_t)n*C_*P_);
    }

    // BN1 stats (apply fused into conv2's im2col)
    bn_stats_kernel<<<C_, 256, 0, stream>>>(y1, st1);

    // conv2: im2col(+BN1+ReLU) + 64-tile GEMM -> y2 bf16
    for (int n = 0; n < N_; ++n) {
        im2col_bn_kernel<<<P_/4, 256, 0, stream>>>(y1 + (size_t)n*C_*P_, st1, g1, be1, Bt);
        gemm64_kernel<<<P_/64, 256, 0, stream>>>(A2, Bt, b2, y2 + (size_t)n*C_*P_);
    }

    // BN2 + residual + ReLU -> out (fp32)
    bn_stats_kernel<<<C_, 256, 0, stream>>>(y2, st2);
    bn_add_relu_kernel<<<(N_*C_*P_)/256, 256, 0, stream>>>(y2, x, st2, g2, be2, out);
}

// Round 6
// 902.267 us; speedup vs baseline: 1.3626x; 1.3626x over previous
//
#include <hip/hip_runtime.h>
#include <hip/hip_bf16.h>

#define N_ 2
#define C_ 64
#define D_ 8
#define H_ 56
#define W_ 56
#define HW_ (H_*W_)        // 3136
#define P_ (D_*HW_)        // 25088
#define G_ 8
#define CPG_ 8
#define K_ 27
#define CO_OFF_ 648        // G * 3 * K
#define MP_ 768            // conv_off M padded to 6*128
#define KK_ 1728           // GEMM K dim (= 27*64, k-major: ktap*64 + ci)
#define KB_ (KK_*2)        // bytes per bf16 row

typedef __attribute__((ext_vector_type(8))) short shortx8;
typedef __attribute__((ext_vector_type(4))) float floatx4;
#define AS1 __attribute__((address_space(1)))
#define AS3 __attribute__((address_space(3)))

__device__ inline float b2f(unsigned short u) {
    union { unsigned u; float f; } x; x.u = ((unsigned)u) << 16; return x.f;
}
__device__ inline unsigned short f2b(float f) {
    union { float f; unsigned u; } x; x.f = f;
    unsigned r = (x.u + 0x7fffu + ((x.u >> 16) & 1u)) >> 16;   // RNE
    return (unsigned short)r;
}
__device__ inline float lof(unsigned u) { union { unsigned u; float f; } x; x.u = u << 16; return x.f; }
__device__ inline float hif(unsigned u) { union { unsigned u; float f; } x; x.u = u & 0xffff0000u; return x.f; }

// ---------------------------------------------------------------------------
// x [N][64][P] fp32 -> xt [N][P][64] bf16  (64p x 64c LDS tile transpose)
// ---------------------------------------------------------------------------
__global__ __launch_bounds__(256) void transpose_xt_kernel(
    const float* __restrict__ x, unsigned short* __restrict__ xt)
{
    __shared__ unsigned short tile[64][65];
    int b  = blockIdx.x;
    int n  = b / (P_/64);
    int p0 = (b % (P_/64))*64;
    int tid = threadIdx.x;
    int j  = tid & 63;
    int c0 = (tid >> 6)*16;
    for (int r = 0; r < 16; ++r)
        tile[c0 + r][j] = f2b(x[((size_t)n*C_ + c0 + r)*P_ + p0 + j]);
    __syncthreads();
    unsigned* dst = (unsigned*)(xt + ((size_t)n*P_ + p0)*C_);
    #pragma unroll
    for (int it = 0; it < 8; ++it) {
        int wi  = it*256 + tid;
        int row = wi >> 5;
        int c   = (wi & 31)*2;
        unsigned lo = tile[c][row], hi = tile[c+1][row];
        dst[(size_t)row*32 + (wi & 31)] = lo | (hi << 16);
    }
}

// w_off [648][64][27] fp32 -> A1k [768][kk*64+ci] bf16 (k-major, zero-pad rows)
__global__ __launch_bounds__(256) void permA1k_kernel(
    const float* __restrict__ w, unsigned short* __restrict__ A)
{
    int i = blockIdx.x*256 + threadIdx.x;
    if (i >= MP_*KK_) return;
    int m = i / KK_, r = i % KK_;
    int kk = r / 64, ci = r % 64;
    A[i] = (m < CO_OFF_) ? f2b(w[((size_t)m*C_ + ci)*K_ + kk]) : (unsigned short)0;
}

// w [O=64][I=64][27] fp32 -> At[o][k*64+i] bf16 (k-major)
__global__ __launch_bounds__(256) void perm_w_kernel(
    const float* __restrict__ w, unsigned short* __restrict__ At)
{
    int tid = blockIdx.x*256 + threadIdx.x;
    if (tid >= C_*KK_) return;
    int o  = tid / KK_;
    int r  = tid % KK_;
    int k  = r / 64, i = r % 64;
    At[tid] = f2b(w[((size_t)o*C_ + i)*K_ + k]);
}

// ---------------------------------------------------------------------------
// conv_off fused: 128x128 tile, BK=64 (one tap), B built in-kernel from xt.
// Per kt: A staged via global_load_lds (4x16B/thread), B via shifted 16B
// loads (4 tasks/thread, oct-fastest => coalesced), LDS in fragment order.
// ---------------------------------------------------------------------------
__global__ __launch_bounds__(256) void conv_off_fused(
    const unsigned short* __restrict__ A,    // A1k [768][1728]
    const unsigned short* __restrict__ xt,   // [P][64] bf16 (per-n)
    const float* __restrict__ bias,          // [648]
    unsigned short* __restrict__ out)        // off [648][P] bf16
{
    __shared__ __align__(16) short As[16*512];
    __shared__ __align__(16) short Bs[16*512];
    int tid = threadIdx.x;
    int w = tid >> 6, lane = tid & 63;
    int bid = blockIdx.x, mt, nt;
    if (bid < 1152) { int c = bid/48, r = bid%48; mt = r >> 3; nt = c*8 + (r&7); }
    else            { int r = bid - 1152;         mt = r >> 2; nt = 192 + (r&3); }
    int m0 = mt*128, p0 = nt*128;
    int lm = lane & 15, lq = lane >> 4;

    const char* Ab0 = (const char*)A + (size_t)(m0 + w*32 + lm)*KB_ + lq*16;
    const char* Ab1 = Ab0 + (size_t)16*KB_;

    // per-task invariants (4 tasks/thread, fixed across kt)
    int octj[4], rj[4], pj[4], dj[4], hj[4], wj[4];
    #pragma unroll
    for (int j = 0; j < 4; ++j) {
        int flat = j*256 + tid;
        octj[j] = flat & 7;
        rj[j]   = flat >> 3;
        pj[j]   = p0 + rj[j];
        dj[j]   = pj[j] / HW_;
        int hw2 = pj[j] % HW_;
        hj[j]   = hw2 / W_;
        wj[j]   = hw2 % W_;
    }

    int mh = w >> 1, nh = w & 1;
    floatx4 acc[4][4];
    #pragma unroll
    for (int i = 0; i < 4; ++i)
        #pragma unroll
        for (int j = 0; j < 4; ++j)
            acc[i][j] = (floatx4){0.f, 0.f, 0.f, 0.f};

    for (int kt = 0; kt < 27; ++kt) {
        int kd = kt/9 - 1, kh = (kt/3)%3 - 1, kw = kt%3 - 1;
        int delta = kd*HW_ + kh*W_ + kw;
        __syncthreads();
        __builtin_amdgcn_global_load_lds((const AS1 unsigned*)(Ab0 + kt*128),      (AS3 unsigned*)(As + (w*2)*512),     16, 0, 0);
        __builtin_amdgcn_global_load_lds((const AS1 unsigned*)(Ab1 + kt*128),      (AS3 unsigned*)(As + (w*2+1)*512),   16, 0, 0);
        __builtin_amdgcn_global_load_lds((const AS1 unsigned*)(Ab0 + kt*128 + 64), (AS3 unsigned*)(As + (8+w*2)*512),   16, 0, 0);
        __builtin_amdgcn_global_load_lds((const AS1 unsigned*)(Ab1 + kt*128 + 64), (AS3 unsigned*)(As + (8+w*2+1)*512), 16, 0, 0);
        #pragma unroll
        for (int j = 0; j < 4; ++j) {
            bool v = ((unsigned)(dj[j]+kd) < (unsigned)D_) &&
                     ((unsigned)(hj[j]+kh) < (unsigned)H_) &&
                     ((unsigned)(wj[j]+kw) < (unsigned)W_);
            uint4 val = {0u,0u,0u,0u};
            if (v) val = *(const uint4*)(xt + (size_t)(pj[j] + delta)*C_ + octj[j]*8);
            int chunk = (octj[j]>>2)*8 + (rj[j]>>4);
            *(uint4*)&Bs[chunk*512 + ((octj[j]&3)*16 + (rj[j]&15))*8] = val;
        }
        __syncthreads();
        #pragma unroll
        for (int ks = 0; ks < 2; ++ks) {
            shortx8 a[4], b[4];
            #pragma unroll
            for (int i = 0; i < 4; ++i) a[i] = *(const shortx8*)&As[(ks*8 + 4*mh + i)*512 + lane*8];
            #pragma unroll
            for (int j = 0; j < 4; ++j) b[j] = *(const shortx8*)&Bs[(ks*8 + 4*nh + j)*512 + lane*8];
            #pragma unroll
            for (int i = 0; i < 4; ++i)
                #pragma unroll
                for (int j = 0; j < 4; ++j)
                    acc[i][j] = __builtin_amdgcn_mfma_f32_16x16x32_bf16(a[i], b[j], acc[i][j], 0, 0, 0);
        }
    }

    #pragma unroll
    for (int i = 0; i < 4; ++i) {
        int cob = m0 + (4*mh+i)*16 + lq*4;
        #pragma unroll
        for (int r = 0; r < 4; ++r) {
            int co = cob + r;
            if (co < CO_OFF_) {
                float bv = bias[co];
                #pragma unroll
                for (int j = 0; j < 4; ++j) {
                    int col = p0 + (4*nh+j)*16 + lm;
                    out[(size_t)co*P_ + col] = f2b(acc[i][j][r] + bv);
                }
            }
        }
    }
}

// ---------------------------------------------------------------------------
// deform fused: 64x64 tile, BK=64 (one tap, 8 groups x 8ch). B built by
// trilinear gather from xt. Output y1t [P][64] via LDS transpose epilogue.
// ---------------------------------------------------------------------------
__global__ __launch_bounds__(256) void deform_fused(
    const unsigned short* __restrict__ xt,   // [P][64] bf16 (per-n)
    const unsigned short* __restrict__ off,  // [648][P] bf16 (per-n)
    const unsigned short* __restrict__ A,    // A1t [64][1728]
    unsigned short* __restrict__ y1t)        // [P][64] bf16 (per-n)
{
    __shared__ __align__(16) short SH[8192];  // As = SH[0..4095], Bs = SH[4096..]
    short* Asb = SH;
    short* Bsb = SH + 4096;
    int tid = threadIdx.x;
    int w = tid >> 6, lane = tid & 63;
    int p0 = blockIdx.x*64;
    int lm = lane & 15, lq = lane >> 4;

    const char* Ab = (const char*)A + (size_t)(w*16 + lm)*KB_ + lq*16;

    // task invariants: r = lane, g = w (+4)
    int r = lane;
    int p = p0 + r;
    int d = p / HW_;
    int hw2 = p % HW_;
    int h = hw2 / W_;
    int ww = hw2 % W_;
    const uint4* xg0 = (const uint4*)xt;

    int mh = w >> 1, nh = w & 1;
    floatx4 acc[2][2];
    #pragma unroll
    for (int i = 0; i < 2; ++i)
        #pragma unroll
        for (int j = 0; j < 2; ++j)
            acc[i][j] = (floatx4){0.f, 0.f, 0.f, 0.f};

    for (int kt = 0; kt < 27; ++kt) {
        int kd = kt/9 - 1, kh = (kt/3)%3 - 1, kw = kt%3 - 1;
        __syncthreads();
        __builtin_amdgcn_global_load_lds((const AS1 unsigned*)(Ab + kt*128),      (AS3 unsigned*)(Asb + w*512),     16, 0, 0);
        __builtin_amdgcn_global_load_lds((const AS1 unsigned*)(Ab + kt*128 + 64), (AS3 unsigned*)(Asb + (4+w)*512), 16, 0, 0);
        #pragma unroll
        for (int it = 0; it < 2; ++it) {
            int g = w + it*4;
            size_t ob = ((size_t)(g*K_ + kt)*3)*P_ + p;
            float pd = (float)(d + kd) + b2f(off[ob]);
            float ph = (float)(h + kh) + b2f(off[ob + P_]);
            float pw = (float)(ww + kw) + b2f(off[ob + 2*(size_t)P_]);
            float fd0 = floorf(pd), fh0 = floorf(ph), fw0 = floorf(pw);
            int d0 = (int)fd0, h0 = (int)fh0, w0i = (int)fw0;
            float fd = pd - fd0, fh = ph - fh0, fw = pw - fw0;
            float res[CPG_];
            #pragma unroll
            for (int c = 0; c < CPG_; ++c) res[c] = 0.f;
            #pragma unroll
            for (int cd = 0; cd < 2; ++cd) {
                int id = d0 + cd;
                float wdt = cd ? fd : 1.f - fd;
                bool vdd = (unsigned)id < (unsigned)D_;
                int idc = min(max(id, 0), D_-1);
                #pragma unroll
                for (int ch = 0; ch < 2; ++ch) {
                    int ih = h0 + ch;
                    float wht = ch ? fh : 1.f - fh;
                    bool vhh = (unsigned)ih < (unsigned)H_;
                    int ihc = min(max(ih, 0), H_-1);
                    #pragma unroll
                    for (int cw = 0; cw < 2; ++cw) {
                        int iw = w0i + cw;
                        float wwt = cw ? fw : 1.f - fw;
                        bool vww = (unsigned)iw < (unsigned)W_;
                        int iwc = min(max(iw, 0), W_-1);
                        float wgt = (vdd && vhh && vww) ? wdt*wht*wwt : 0.f;
                        int lin = (idc*H_ + ihc)*W_ + iwc;
                        uint4 v4 = xg0[(size_t)lin*(C_/8) + g];
                        res[0] = fmaf(wgt, lof(v4.x), res[0]);
                        res[1] = fmaf(wgt, hif(v4.x), res[1]);
                        res[2] = fmaf(wgt, lof(v4.y), res[2]);
                        res[3] = fmaf(wgt, hif(v4.y), res[3]);
                        res[4] = fmaf(wgt, lof(v4.z), res[4]);
                        res[5] = fmaf(wgt, hif(v4.z), res[5]);
                        res[6] = fmaf(wgt, lof(v4.w), res[6]);
                        res[7] = fmaf(wgt, hif(v4.w), res[7]);
                    }
                }
            }
            uint4 o4;
            o4.x = (unsigned)f2b(res[0]) | ((unsigned)f2b(res[1]) << 16);
            o4.y = (unsigned)f2b(res[2]) | ((unsigned)f2b(res[3]) << 16);
            o4.z = (unsigned)f2b(res[4]) | ((unsigned)f2b(res[5]) << 16);
            o4.w = (unsigned)f2b(res[6]) | ((unsigned)f2b(res[7]) << 16);
            int chunk = (g>>2)*4 + (r>>4);
            *(uint4*)&Bsb[chunk*512 + ((g&3)*16 + (r&15))*8] = o4;
        }
        __syncthreads();
        #pragma unroll
        for (int ks = 0; ks < 2; ++ks) {
            shortx8 a[2], b[2];
            #pragma unroll
            for (int i = 0; i < 2; ++i) a[i] = *(const shortx8*)&Asb[(ks*4 + 2*mh+i)*512 + lane*8];
            #pragma unroll
            for (int j = 0; j < 2; ++j) b[j] = *(const shortx8*)&Bsb[(ks*4 + 2*nh+j)*512 + lane*8];
            #pragma unroll
            for (int i = 0; i < 2; ++i)
                #pragma unroll
                for (int j = 0; j < 2; ++j)
                    acc[i][j] = __builtin_amdgcn_mfma_f32_16x16x32_bf16(a[i], b[j], acc[i][j], 0, 0, 0);
        }
    }

    // epilogue: transpose 64o x 64p tile to y1t[p][o] via LDS (stride 72)
    __syncthreads();
    #pragma unroll
    for (int i = 0; i < 2; ++i) {
        int ob = mh*32 + i*16 + lq*4;
        #pragma unroll
        for (int j = 0; j < 2; ++j) {
            int pc = nh*32 + j*16 + lm;
            #pragma unroll
            for (int rr = 0; rr < 4; ++rr)
                SH[pc*72 + ob + rr] = (short)f2b(acc[i][j][rr]);
        }
    }
    __syncthreads();
    {
        int row = tid >> 2, seg = tid & 3;
        uint4 v0 = *(const uint4*)&SH[row*72 + seg*16];
        uint4 v1 = *(const uint4*)&SH[row*72 + seg*16 + 8];
        uint4* dst = (uint4*)(y1t + (size_t)(p0 + row)*C_ + seg*16);
        dst[0] = v0;
        dst[1] = v1;
    }
}

// ---------------------------------------------------------------------------
// conv2 fused: 64x64 tile, BK=64 (one tap, 64 ci). B = BN1+ReLU(y1t) shifted.
// Output y2 [64][P] (channel-major) for BN2 stats / residual.
// ---------------------------------------------------------------------------
__global__ __launch_bounds__(256) void conv2_fused(
    const unsigned short* __restrict__ y1t,  // [P][64] bf16 (per-n)
    const float* __restrict__ st1,           // [64] scale, [64] shift
    const unsigned short* __restrict__ A,    // A2t [64][1728]
    const float* __restrict__ bias,          // [64]
    unsigned short* __restrict__ y2)         // [64][P] bf16 (per-n)
{
    __shared__ __align__(16) short SH[8192];
    short* Asb = SH;
    short* Bsb = SH + 4096;
    __shared__ float sc[64], sf[64];
    int tid = threadIdx.x;
    if (tid < 64) sc[tid] = st1[tid];
    else if (tid < 128) sf[tid-64] = st1[tid];
    int w = tid >> 6, lane = tid & 63;
    int p0 = blockIdx.x*64;
    int lm = lane & 15, lq = lane >> 4;

    const char* Ab = (const char*)A + (size_t)(w*16 + lm)*KB_ + lq*16;

    // task invariants (2 tasks/thread, oct-fastest)
    int octj[2], rj[2], pj[2], dj[2], hj[2], wj[2];
    #pragma unroll
    for (int j = 0; j < 2; ++j) {
        int flat = j*256 + tid;
        octj[j] = flat & 7;
        rj[j]   = flat >> 3;
        pj[j]   = p0 + rj[j];
        dj[j]   = pj[j] / HW_;
        int hw2 = pj[j] % HW_;
        hj[j]   = hw2 / W_;
        wj[j]   = hw2 % W_;
    }

    int mh = w >> 1, nh = w & 1;
    floatx4 acc[2][2];
    #pragma unroll
    for (int i = 0; i < 2; ++i)
        #pragma unroll
        for (int j = 0; j < 2; ++j)
            acc[i][j] = (floatx4){0.f, 0.f, 0.f, 0.f};

    for (int kt = 0; kt < 27; ++kt) {
        int kd = kt/9 - 1, kh = (kt/3)%3 - 1, kw = kt%3 - 1;
        int delta = kd*HW_ + kh*W_ + kw;
        __syncthreads();
        __builtin_amdgcn_global_load_lds((const AS1 unsigned*)(Ab + kt*128),      (AS3 unsigned*)(Asb + w*512),     16, 0, 0);
        __builtin_amdgcn_global_load_lds((const AS1 unsigned*)(Ab + kt*128 + 64), (AS3 unsigned*)(Asb + (4+w)*512), 16, 0, 0);
        #pragma unroll
        for (int j = 0; j < 2; ++j) {
            bool v = ((unsigned)(dj[j]+kd) < (unsigned)D_) &&
                     ((unsigned)(hj[j]+kh) < (unsigned)H_) &&
                     ((unsigned)(wj[j]+kw) < (unsigned)W_);
            uint4 o4 = {0u,0u,0u,0u};
            if (v) {
                uint4 val = *(const uint4*)(y1t + (size_t)(pj[j] + delta)*C_ + octj[j]*8);
                int cb = octj[j]*8;
                float r0 = fmaxf(lof(val.x)*sc[cb+0] + sf[cb+0], 0.f);
                float r1 = fmaxf(hif(val.x)*sc[cb+1] + sf[cb+1], 0.f);
                float r2 = fmaxf(lof(val.y)*sc[cb+2] + sf[cb+2], 0.f);
                float r3 = fmaxf(hif(val.y)*sc[cb+3] + sf[cb+3], 0.f);
                float r4 = fmaxf(lof(val.z)*sc[cb+4] + sf[cb+4], 0.f);
                float r5 = fmaxf(hif(val.z)*sc[cb+5] + sf[cb+5], 0.f);
                float r6 = fmaxf(lof(val.w)*sc[cb+6] + sf[cb+6], 0.f);
                float r7 = fmaxf(hif(val.w)*sc[cb+7] + sf[cb+7], 0.f);
                o4.x = (unsigned)f2b(r0) | ((unsigned)f2b(r1) << 16);
                o4.y = (unsigned)f2b(r2) | ((unsigned)f2b(r3) << 16);
                o4.z = (unsigned)f2b(r4) | ((unsigned)f2b(r5) << 16);
                o4.w = (unsigned)f2b(r6) | ((unsigned)f2b(r7) << 16);
            }
            int chunk = (octj[j]>>2)*4 + (rj[j]>>4);
            *(uint4*)&Bsb[chunk*512 + ((octj[j]&3)*16 + (rj[j]&15))*8] = o4;
        }
        __syncthreads();
        #pragma unroll
        for (int ks = 0; ks < 2; ++ks) {
            shortx8 a[2], b[2];
            #pragma unroll
            for (int i = 0; i < 2; ++i) a[i] = *(const shortx8*)&Asb[(ks*4 + 2*mh+i)*512 + lane*8];
            #pragma unroll
            for (int j = 0; j < 2; ++j) b[j] = *(const shortx8*)&Bsb[(ks*4 + 2*nh+j)*512 + lane*8];
            #pragma unroll
            for (int i = 0; i < 2; ++i)
                #pragma unroll
                for (int j = 0; j < 2; ++j)
                    acc[i][j] = __builtin_amdgcn_mfma_f32_16x16x32_bf16(a[i], b[j], acc[i][j], 0, 0, 0);
        }
    }

    #pragma unroll
    for (int i = 0; i < 2; ++i) {
        int cob = (2*mh+i)*16 + lq*4;
        #pragma unroll
        for (int r = 0; r < 4; ++r) {
            int co = cob + r;
            float bv = bias[co];
            #pragma unroll
            for (int j = 0; j < 2; ++j) {
                int col = p0 + (2*nh+j)*16 + lm;
                y2[(size_t)co*P_ + col] = f2b(acc[i][j][r] + bv);
            }
        }
    }
}

// ---------------------------------------------------------------------------
// BN1 stats from y1t [N*P][64]: partial sums per 512-row block, then finalize
// ---------------------------------------------------------------------------
__global__ __launch_bounds__(256) void stats_partial_kernel(
    const unsigned short* __restrict__ y1t, float* __restrict__ part)
{
    int b = blockIdx.x, tid = threadIdx.x;
    int c = tid & 63, sub = tid >> 6;
    float s = 0.f, q = 0.f;
    for (int rr = 0; rr < 128; ++rr) {
        int row = b*512 + sub*128 + rr;
        float v = b2f(y1t[(size_t)row*C_ + c]);
        s += v;
        q = fmaf(v, v, q);
    }
    __shared__ float ss[256], qq[256];
    ss[tid] = s; qq[tid] = q;
    __syncthreads();
    if (tid < 64) {
        float S = ss[tid] + ss[64+tid] + ss[128+tid] + ss[192+tid];
        float Q = qq[tid] + qq[64+tid] + qq[128+tid] + qq[192+tid];
        part[b*128 + tid]      = S;
        part[b*128 + 64 + tid] = Q;
    }
}

__global__ void stats_final_kernel(
    const float* __restrict__ part,
    const float* __restrict__ gamma, const float* __restrict__ beta,
    float* __restrict__ st1)
{
    int c = threadIdx.x;  // 64 threads
    float S = 0.f, Q = 0.f;
    for (int b = 0; b < 98; ++b) {
        S += part[b*128 + c];
        Q += part[b*128 + 64 + c];
    }
    const float inv = 1.f / (float)(N_*P_);
    float m = S * inv;
    float var = Q * inv - m*m;
    float scale = rsqrtf(var + 1e-5f) * gamma[c];
    st1[c]      = scale;
    st1[64 + c] = beta[c] - m*scale;
}

// ---------------------------------------------------------------------------
// BN2 stats (y2 channel-major) + fused add/relu (unchanged)
// ---------------------------------------------------------------------------
__global__ __launch_bounds__(256) void bn_stats_kernel(
    const unsigned short* __restrict__ src, float* __restrict__ stats)
{
    int c   = blockIdx.x;
    int tid = threadIdx.x;
    float s = 0.f, q = 0.f;
    for (int n = 0; n < N_; ++n) {
        const unsigned short* p = src + ((size_t)n*C_ + c)*P_;
        for (int i = tid; i < P_; i += 256) {
            float v = b2f(p[i]);
            s += v;
            q = fmaf(v, v, q);
        }
    }
    #pragma unroll
    for (int o = 32; o; o >>= 1) {
        s += __shfl_down(s, o);
        q += __shfl_down(q, o);
    }
    __shared__ float sh[2][4];
    int wave = tid >> 6;
    if ((tid & 63) == 0) { sh[0][wave] = s; sh[1][wave] = q; }
    __syncthreads();
    if (tid == 0) {
        float S = sh[0][0] + sh[0][1] + sh[0][2] + sh[0][3];
        float Q = sh[1][0] + sh[1][1] + sh[1][2] + sh[1][3];
        const float inv = 1.f / (float)(N_*P_);
        float m  = S * inv;
        float var = Q * inv - m*m;
        stats[c]      = m;
        stats[C_ + c] = rsqrtf(var + 1e-5f);
    }
}

__global__ __launch_bounds__(256) void bn_add_relu_kernel(
    const unsigned short* __restrict__ y2, const float* __restrict__ x,
    const float* __restrict__ stats,
    const float* __restrict__ gamma, const float* __restrict__ beta,
    float* __restrict__ out)
{
    size_t idx = (size_t)blockIdx.x*256 + threadIdx.x;
    int c = (int)((idx / P_) % C_);
    float v = (b2f(y2[idx]) - stats[c]) * stats[C_ + c] * gamma[c] + beta[c] + x[idx];
    out[idx] = fmaxf(v, 0.f);
}

// ---------------------------------------------------------------------------
extern "C" void kernel_launch(void* const* d_in, const int* in_sizes, int n_in,
                              void* d_out, int out_size, void* d_ws, size_t ws_size,
                              hipStream_t stream) {
    const float* x     = (const float*)d_in[0];
    const float* w_off = (const float*)d_in[1];
    const float* b_off = (const float*)d_in[2];
    const float* w1    = (const float*)d_in[3];
    const float* g1    = (const float*)d_in[4];
    const float* be1   = (const float*)d_in[5];
    const float* w2    = (const float*)d_in[6];
    const float* b2    = (const float*)d_in[7];
    const float* g2    = (const float*)d_in[8];
    const float* be2   = (const float*)d_in[9];
    float* out = (float*)d_out;

    // workspace (~55 MB)
    float* st1  = (float*)d_ws;                              // 128 (scale/shift)
    float* st2  = st1 + 128;                                 // 128 (mean/rstd)
    float* part = st2 + 128;                                 // 98*128
    unsigned short* off = (unsigned short*)(part + 98*128);  // 648*P bf16 (32.5 MB, per-n)
    unsigned short* xt  = off + (size_t)CO_OFF_*P_;          // N*P*64 bf16 (6.4 MB)
    unsigned short* y1t = xt  + (size_t)N_*P_*C_;            // N*P*64 bf16 (6.4 MB)
    unsigned short* y2  = y1t + (size_t)N_*P_*C_;            // N*64*P bf16 (6.4 MB)
    unsigned short* A1k = y2  + (size_t)N_*C_*P_;            // 768*1728 bf16 (2.65 MB)
    unsigned short* A1t = A1k + (size_t)MP_*KK_;             // 64*1728 bf16
    unsigned short* A2t = A1t + (size_t)C_*KK_;              // 64*1728 bf16

    // prep
    transpose_xt_kernel<<<N_*(P_/64), 256, 0, stream>>>(x, xt);
    permA1k_kernel<<<(MP_*KK_+255)/256, 256, 0, stream>>>(w_off, A1k);
    perm_w_kernel<<<(C_*KK_+255)/256, 256, 0, stream>>>(w1, A1t);
    perm_w_kernel<<<(C_*KK_+255)/256, 256, 0, stream>>>(w2, A2t);

    // per-n: conv_off fused -> off; deform fused -> y1t
    for (int n = 0; n < N_; ++n) {
        conv_off_fused<<<1176, 256, 0, stream>>>(A1k, xt + (size_t)n*P_*C_, b_off, off);
        deform_fused<<<P_/64, 256, 0, stream>>>(xt + (size_t)n*P_*C_, off, A1t,
                                                y1t + (size_t)n*P_*C_);
    }

    // BN1 scale/shift
    stats_partial_kernel<<<98, 256, 0, stream>>>(y1t, part);
    stats_final_kernel<<<1, 64, 0, stream>>>(part, g1, be1, st1);

    // per-n: conv2 fused (BN1+ReLU on read) -> y2
    for (int n = 0; n < N_; ++n)
        conv2_fused<<<P_/64, 256, 0, stream>>>(y1t + (size_t)n*P_*C_, st1, A2t, b2,
                                               y2 + (size_t)n*C_*P_);

    // BN2 + residual + ReLU -> out (fp32)
    bn_stats_kernel<<<C_, 256, 0, stream>>>(y2, st2);
    bn_add_relu_kernel<<<(N_*C_*P_)/256, 256, 0, stream>>>(y2, x, st2, g2, be2, out);
}

// Round 7
// 830.075 us; speedup vs baseline: 1.4811x; 1.0870x over previous
//
#include <hip/hip_runtime.h>
#include <hip/hip_bf16.h>

#define N_ 2
#define C_ 64
#define D_ 8
#define H_ 56
#define W_ 56
#define HW_ (H_*W_)        // 3136
#define P_ (D_*HW_)        // 25088
#define G_ 8
#define CPG_ 8
#define K_ 27
#define CO_OFF_ 648        // G * 3 * K
#define MP_ 768            // conv_off M padded to 6*128
#define KK_ 1728           // GEMM K dim (= 27*64, k-major: ktap*64 + ci)
#define KB_ (KK_*2)        // bytes per bf16 row

typedef __attribute__((ext_vector_type(8))) short shortx8;
typedef __attribute__((ext_vector_type(4))) float floatx4;
#define AS1 __attribute__((address_space(1)))
#define AS3 __attribute__((address_space(3)))

__device__ inline float b2f(unsigned short u) {
    union { unsigned u; float f; } x; x.u = ((unsigned)u) << 16; return x.f;
}
__device__ inline unsigned short f2b(float f) {
    union { float f; unsigned u; } x; x.f = f;
    unsigned r = (x.u + 0x7fffu + ((x.u >> 16) & 1u)) >> 16;   // RNE
    return (unsigned short)r;
}
__device__ inline float lof(unsigned u) { union { unsigned u; float f; } x; x.u = u << 16; return x.f; }
__device__ inline float hif(unsigned u) { union { unsigned u; float f; } x; x.u = u & 0xffff0000u; return x.f; }

// ---------------------------------------------------------------------------
// x [N][64][P] fp32 -> xt [N][P][64] bf16  (64p x 64c LDS tile transpose)
// ---------------------------------------------------------------------------
__global__ __launch_bounds__(256) void transpose_xt_kernel(
    const float* __restrict__ x, unsigned short* __restrict__ xt)
{
    __shared__ unsigned short tile[64][65];
    int b  = blockIdx.x;
    int n  = b / (P_/64);
    int p0 = (b % (P_/64))*64;
    int tid = threadIdx.x;
    int j  = tid & 63;
    int c0 = (tid >> 6)*16;
    for (int r = 0; r < 16; ++r)
        tile[c0 + r][j] = f2b(x[((size_t)n*C_ + c0 + r)*P_ + p0 + j]);
    __syncthreads();
    unsigned* dst = (unsigned*)(xt + ((size_t)n*P_ + p0)*C_);
    #pragma unroll
    for (int it = 0; it < 8; ++it) {
        int wi  = it*256 + tid;
        int row = wi >> 5;
        int c   = (wi & 31)*2;
        unsigned lo = tile[c][row], hi = tile[c+1][row];
        dst[(size_t)row*32 + (wi & 31)] = lo | (hi << 16);
    }
}

// w_off [648][64][27] fp32 -> A1k [768][kk*64+ci] bf16 (k-major, zero-pad rows)
__global__ __launch_bounds__(256) void permA1k_kernel(
    const float* __restrict__ w, unsigned short* __restrict__ A)
{
    int i = blockIdx.x*256 + threadIdx.x;
    if (i >= MP_*KK_) return;
    int m = i / KK_, r = i % KK_;
    int kk = r / 64, ci = r % 64;
    A[i] = (m < CO_OFF_) ? f2b(w[((size_t)m*C_ + ci)*K_ + kk]) : (unsigned short)0;
}

// w [O=64][I=64][27] fp32 -> At[o][k*64+i] bf16 (k-major)
__global__ __launch_bounds__(256) void perm_w_kernel(
    const float* __restrict__ w, unsigned short* __restrict__ At)
{
    int tid = blockIdx.x*256 + threadIdx.x;
    if (tid >= C_*KK_) return;
    int o  = tid / KK_;
    int r  = tid % KK_;
    int k  = r / 64, i = r % 64;
    At[tid] = f2b(w[((size_t)o*C_ + i)*K_ + k]);
}

// ---------------------------------------------------------------------------
// conv_off fused: 128x128 tile, BK=64 (one tap), both n in one grid.
// B-stage: wave w fills LDS chunks w*4+j with lane-contiguous 16B writes
// (conflict-free phases); source = shifted 16B reads of xt (L1/L2-resident).
// ---------------------------------------------------------------------------
__global__ __launch_bounds__(256) void conv_off_fused(
    const unsigned short* __restrict__ A,    // A1k [768][1728]
    const unsigned short* __restrict__ xt,   // [N][P][64] bf16
    const float* __restrict__ bias,          // [648]
    unsigned short* __restrict__ off)        // [N][648][P] bf16
{
    __shared__ __align__(16) short As[16*512];
    __shared__ __align__(16) short Bs[16*512];
    int tid = threadIdx.x;
    int w = tid >> 6, lane = tid & 63;
    int n   = blockIdx.x / 1176;
    int bid = blockIdx.x % 1176;
    int mt, nt;
    if (bid < 1152) { int c = bid/48, r = bid%48; mt = r >> 3; nt = c*8 + (r&7); }
    else            { int r = bid - 1152;         mt = r >> 2; nt = 192 + (r&3); }
    int m0 = mt*128, p0 = nt*128;
    int lm = lane & 15, lq = lane >> 4;

    const unsigned short* xtn = xt + (size_t)n*P_*C_;
    unsigned short* out = off + (size_t)n*CO_OFF_*P_;

    const char* Ab0 = (const char*)A + (size_t)(m0 + w*32 + lm)*KB_ + lq*16;
    const char* Ab1 = Ab0 + (size_t)16*KB_;

    // B-task invariants: task j -> chunk = w*4+j (ks=chunk>>3, ntile=chunk&7)
    int octj[4], pj[4], dj[4], hj[4], wj[4];
    #pragma unroll
    for (int j = 0; j < 4; ++j) {
        int chunk = w*4 + j;
        octj[j] = (chunk >> 3)*4 + lq;
        int r = (chunk & 7)*16 + lm;
        pj[j] = p0 + r;
        dj[j] = pj[j] / HW_;
        int hw2 = pj[j] % HW_;
        hj[j] = hw2 / W_;
        wj[j] = hw2 % W_;
    }

    int mh = w >> 1, nh = w & 1;
    floatx4 acc[4][4];
    #pragma unroll
    for (int i = 0; i < 4; ++i)
        #pragma unroll
        for (int j = 0; j < 4; ++j)
            acc[i][j] = (floatx4){0.f, 0.f, 0.f, 0.f};

    for (int kt = 0; kt < 27; ++kt) {
        int kd = kt/9 - 1, kh = (kt/3)%3 - 1, kw = kt%3 - 1;
        int delta = kd*HW_ + kh*W_ + kw;
        __syncthreads();
        __builtin_amdgcn_global_load_lds((const AS1 unsigned*)(Ab0 + kt*128),      (AS3 unsigned*)(As + (w*2)*512),     16, 0, 0);
        __builtin_amdgcn_global_load_lds((const AS1 unsigned*)(Ab1 + kt*128),      (AS3 unsigned*)(As + (w*2+1)*512),   16, 0, 0);
        __builtin_amdgcn_global_load_lds((const AS1 unsigned*)(Ab0 + kt*128 + 64), (AS3 unsigned*)(As + (8+w*2)*512),   16, 0, 0);
        __builtin_amdgcn_global_load_lds((const AS1 unsigned*)(Ab1 + kt*128 + 64), (AS3 unsigned*)(As + (8+w*2+1)*512), 16, 0, 0);
        #pragma unroll
        for (int j = 0; j < 4; ++j) {
            int chunk = w*4 + j;
            bool v = ((unsigned)(dj[j]+kd) < (unsigned)D_) &&
                     ((unsigned)(hj[j]+kh) < (unsigned)H_) &&
                     ((unsigned)(wj[j]+kw) < (unsigned)W_);
            uint4 val = {0u,0u,0u,0u};
            if (v) val = *(const uint4*)(xtn + (size_t)(pj[j] + delta)*C_ + octj[j]*8);
            *(uint4*)&Bs[chunk*512 + lane*8] = val;
        }
        __syncthreads();
        #pragma unroll
        for (int ks = 0; ks < 2; ++ks) {
            shortx8 a[4], b[4];
            #pragma unroll
            for (int i = 0; i < 4; ++i) a[i] = *(const shortx8*)&As[(ks*8 + 4*mh + i)*512 + lane*8];
            #pragma unroll
            for (int j = 0; j < 4; ++j) b[j] = *(const shortx8*)&Bs[(ks*8 + 4*nh + j)*512 + lane*8];
            #pragma unroll
            for (int i = 0; i < 4; ++i)
                #pragma unroll
                for (int j = 0; j < 4; ++j)
                    acc[i][j] = __builtin_amdgcn_mfma_f32_16x16x32_bf16(a[i], b[j], acc[i][j], 0, 0, 0);
        }
    }

    #pragma unroll
    for (int i = 0; i < 4; ++i) {
        int cob = m0 + (4*mh+i)*16 + lq*4;
        #pragma unroll
        for (int r = 0; r < 4; ++r) {
            int co = cob + r;
            if (co < CO_OFF_) {
                float bv = bias[co];
                #pragma unroll
                for (int j = 0; j < 4; ++j) {
                    int col = p0 + (4*nh+j)*16 + lm;
                    out[(size_t)co*P_ + col] = f2b(acc[i][j][r] + bv);
                }
            }
        }
    }
}

// ---------------------------------------------------------------------------
// deform fused: 64x64 tile, both n in one grid. B built by trilinear gather
// from xt (write pattern already phase-contiguous). Output y1t [P][64].
// ---------------------------------------------------------------------------
__global__ __launch_bounds__(256) void deform_fused(
    const unsigned short* __restrict__ xt,   // [N][P][64] bf16
    const unsigned short* __restrict__ off,  // [N][648][P] bf16
    const unsigned short* __restrict__ A,    // A1t [64][1728]
    unsigned short* __restrict__ y1t)        // [N][P][64] bf16
{
    __shared__ __align__(16) short SH[8192];  // As = SH[0..4095], Bs = SH[4096..]
    short* Asb = SH;
    short* Bsb = SH + 4096;
    int tid = threadIdx.x;
    int w = tid >> 6, lane = tid & 63;
    int n  = blockIdx.x / (P_/64);
    int p0 = (blockIdx.x % (P_/64))*64;
    int lm = lane & 15, lq = lane >> 4;

    const unsigned short* offn = off + (size_t)n*CO_OFF_*P_;
    const uint4* xg0 = (const uint4*)(xt + (size_t)n*P_*C_);

    const char* Ab = (const char*)A + (size_t)(w*16 + lm)*KB_ + lq*16;

    int r = lane;
    int p = p0 + r;
    int d = p / HW_;
    int hw2 = p % HW_;
    int h = hw2 / W_;
    int ww = hw2 % W_;

    int mh = w >> 1, nh = w & 1;
    floatx4 acc[2][2];
    #pragma unroll
    for (int i = 0; i < 2; ++i)
        #pragma unroll
        for (int j = 0; j < 2; ++j)
            acc[i][j] = (floatx4){0.f, 0.f, 0.f, 0.f};

    for (int kt = 0; kt < 27; ++kt) {
        int kd = kt/9 - 1, kh = (kt/3)%3 - 1, kw = kt%3 - 1;
        __syncthreads();
        __builtin_amdgcn_global_load_lds((const AS1 unsigned*)(Ab + kt*128),      (AS3 unsigned*)(Asb + w*512),     16, 0, 0);
        __builtin_amdgcn_global_load_lds((const AS1 unsigned*)(Ab + kt*128 + 64), (AS3 unsigned*)(Asb + (4+w)*512), 16, 0, 0);
        #pragma unroll
        for (int it = 0; it < 2; ++it) {
            int g = w + it*4;
            size_t ob = ((size_t)(g*K_ + kt)*3)*P_ + p;
            float pd = (float)(d + kd) + b2f(offn[ob]);
            float ph = (float)(h + kh) + b2f(offn[ob + P_]);
            float pw = (float)(ww + kw) + b2f(offn[ob + 2*(size_t)P_]);
            float fd0 = floorf(pd), fh0 = floorf(ph), fw0 = floorf(pw);
            int d0 = (int)fd0, h0 = (int)fh0, w0i = (int)fw0;
            float fd = pd - fd0, fh = ph - fh0, fw = pw - fw0;
            float res[CPG_];
            #pragma unroll
            for (int c = 0; c < CPG_; ++c) res[c] = 0.f;
            #pragma unroll
            for (int cd = 0; cd < 2; ++cd) {
                int id = d0 + cd;
                float wdt = cd ? fd : 1.f - fd;
                bool vdd = (unsigned)id < (unsigned)D_;
                int idc = min(max(id, 0), D_-1);
                #pragma unroll
                for (int ch = 0; ch < 2; ++ch) {
                    int ih = h0 + ch;
                    float wht = ch ? fh : 1.f - fh;
                    bool vhh = (unsigned)ih < (unsigned)H_;
                    int ihc = min(max(ih, 0), H_-1);
                    #pragma unroll
                    for (int cw = 0; cw < 2; ++cw) {
                        int iw = w0i + cw;
                        float wwt = cw ? fw : 1.f - fw;
                        bool vww = (unsigned)iw < (unsigned)W_;
                        int iwc = min(max(iw, 0), W_-1);
                        float wgt = (vdd && vhh && vww) ? wdt*wht*wwt : 0.f;
                        int lin = (idc*H_ + ihc)*W_ + iwc;
                        uint4 v4 = xg0[(size_t)lin*(C_/8) + g];
                        res[0] = fmaf(wgt, lof(v4.x), res[0]);
                        res[1] = fmaf(wgt, hif(v4.x), res[1]);
                        res[2] = fmaf(wgt, lof(v4.y), res[2]);
                        res[3] = fmaf(wgt, hif(v4.y), res[3]);
                        res[4] = fmaf(wgt, lof(v4.z), res[4]);
                        res[5] = fmaf(wgt, hif(v4.z), res[5]);
                        res[6] = fmaf(wgt, lof(v4.w), res[6]);
                        res[7] = fmaf(wgt, hif(v4.w), res[7]);
                    }
                }
            }
            uint4 o4;
            o4.x = (unsigned)f2b(res[0]) | ((unsigned)f2b(res[1]) << 16);
            o4.y = (unsigned)f2b(res[2]) | ((unsigned)f2b(res[3]) << 16);
            o4.z = (unsigned)f2b(res[4]) | ((unsigned)f2b(res[5]) << 16);
            o4.w = (unsigned)f2b(res[6]) | ((unsigned)f2b(res[7]) << 16);
            int chunk = (g>>2)*4 + (r>>4);
            *(uint4*)&Bsb[chunk*512 + ((g&3)*16 + (r&15))*8] = o4;
        }
        __syncthreads();
        #pragma unroll
        for (int ks = 0; ks < 2; ++ks) {
            shortx8 a[2], b[2];
            #pragma unroll
            for (int i = 0; i < 2; ++i) a[i] = *(const shortx8*)&Asb[(ks*4 + 2*mh+i)*512 + lane*8];
            #pragma unroll
            for (int j = 0; j < 2; ++j) b[j] = *(const shortx8*)&Bsb[(ks*4 + 2*nh+j)*512 + lane*8];
            #pragma unroll
            for (int i = 0; i < 2; ++i)
                #pragma unroll
                for (int j = 0; j < 2; ++j)
                    acc[i][j] = __builtin_amdgcn_mfma_f32_16x16x32_bf16(a[i], b[j], acc[i][j], 0, 0, 0);
        }
    }

    // epilogue: transpose 64o x 64p tile to y1t[p][o] via LDS (stride 72)
    __syncthreads();
    #pragma unroll
    for (int i = 0; i < 2; ++i) {
        int ob = mh*32 + i*16 + lq*4;
        #pragma unroll
        for (int j = 0; j < 2; ++j) {
            int pc = nh*32 + j*16 + lm;
            #pragma unroll
            for (int rr = 0; rr < 4; ++rr)
                SH[pc*72 + ob + rr] = (short)f2b(acc[i][j][rr]);
        }
    }
    __syncthreads();
    {
        int row = tid >> 2, seg = tid & 3;
        uint4 v0 = *(const uint4*)&SH[row*72 + seg*16];
        uint4 v1 = *(const uint4*)&SH[row*72 + seg*16 + 8];
        uint4* dst = (uint4*)(y1t + ((size_t)n*P_ + p0 + row)*C_ + seg*16);
        dst[0] = v0;
        dst[1] = v1;
    }
}

// ---------------------------------------------------------------------------
// conv2 fused: 64x64 tile, both n. B = BN1+ReLU(y1t) shifted; wave-owns-chunk
// LDS writes (conflict-free). Output y2 [N][64][P].
// ---------------------------------------------------------------------------
__global__ __launch_bounds__(256) void conv2_fused(
    const unsigned short* __restrict__ y1t,  // [N][P][64] bf16
    const float* __restrict__ st1,           // [64] scale, [64] shift
    const unsigned short* __restrict__ A,    // A2t [64][1728]
    const float* __restrict__ bias,          // [64]
    unsigned short* __restrict__ y2)         // [N][64][P] bf16
{
    __shared__ __align__(16) short SH[8192];
    short* Asb = SH;
    short* Bsb = SH + 4096;
    __shared__ float sc[64], sf[64];
    int tid = threadIdx.x;
    if (tid < 64) sc[tid] = st1[tid];
    else if (tid < 128) sf[tid-64] = st1[tid];
    int w = tid >> 6, lane = tid & 63;
    int n  = blockIdx.x / (P_/64);
    int p0 = (blockIdx.x % (P_/64))*64;
    int lm = lane & 15, lq = lane >> 4;

    const unsigned short* y1n = y1t + (size_t)n*P_*C_;
    unsigned short* y2n = y2 + (size_t)n*C_*P_;

    const char* Ab = (const char*)A + (size_t)(w*16 + lm)*KB_ + lq*16;

    // B-task invariants: task j -> chunk = w*2+j (ks=chunk>>2, ntile=chunk&3)
    int octj[2], pj[2], dj[2], hj[2], wj[2];
    #pragma unroll
    for (int j = 0; j < 2; ++j) {
        int chunk = w*2 + j;
        octj[j] = (chunk >> 2)*4 + lq;
        int r = (chunk & 3)*16 + lm;
        pj[j] = p0 + r;
        dj[j] = pj[j] / HW_;
        int hw2 = pj[j] % HW_;
        hj[j] = hw2 / W_;
        wj[j] = hw2 % W_;
    }

    int mh = w >> 1, nh = w & 1;
    floatx4 acc[2][2];
    #pragma unroll
    for (int i = 0; i < 2; ++i)
        #pragma unroll
        for (int j = 0; j < 2; ++j)
            acc[i][j] = (floatx4){0.f, 0.f, 0.f, 0.f};

    for (int kt = 0; kt < 27; ++kt) {
        int kd = kt/9 - 1, kh = (kt/3)%3 - 1, kw = kt%3 - 1;
        int delta = kd*HW_ + kh*W_ + kw;
        __syncthreads();
        __builtin_amdgcn_global_load_lds((const AS1 unsigned*)(Ab + kt*128),      (AS3 unsigned*)(Asb + w*512),     16, 0, 0);
        __builtin_amdgcn_global_load_lds((const AS1 unsigned*)(Ab + kt*128 + 64), (AS3 unsigned*)(Asb + (4+w)*512), 16, 0, 0);
        #pragma unroll
        for (int j = 0; j < 2; ++j) {
            int chunk = w*2 + j;
            bool v = ((unsigned)(dj[j]+kd) < (unsigned)D_) &&
                     ((unsigned)(hj[j]+kh) < (unsigned)H_) &&
                     ((unsigned)(wj[j]+kw) < (unsigned)W_);
            uint4 o4 = {0u,0u,0u,0u};
            if (v) {
                uint4 val = *(const uint4*)(y1n + (size_t)(pj[j] + delta)*C_ + octj[j]*8);
                int cb = octj[j]*8;
                float r0 = fmaxf(lof(val.x)*sc[cb+0] + sf[cb+0], 0.f);
                float r1 = fmaxf(hif(val.x)*sc[cb+1] + sf[cb+1], 0.f);
                float r2 = fmaxf(lof(val.y)*sc[cb+2] + sf[cb+2], 0.f);
                float r3 = fmaxf(hif(val.y)*sc[cb+3] + sf[cb+3], 0.f);
                float r4 = fmaxf(lof(val.z)*sc[cb+4] + sf[cb+4], 0.f);
                float r5 = fmaxf(hif(val.z)*sc[cb+5] + sf[cb+5], 0.f);
                float r6 = fmaxf(lof(val.w)*sc[cb+6] + sf[cb+6], 0.f);
                float r7 = fmaxf(hif(val.w)*sc[cb+7] + sf[cb+7], 0.f);
                o4.x = (unsigned)f2b(r0) | ((unsigned)f2b(r1) << 16);
                o4.y = (unsigned)f2b(r2) | ((unsigned)f2b(r3) << 16);
                o4.z = (unsigned)f2b(r4) | ((unsigned)f2b(r5) << 16);
                o4.w = (unsigned)f2b(r6) | ((unsigned)f2b(r7) << 16);
            }
            *(uint4*)&Bsb[chunk*512 + lane*8] = o4;
        }
        __syncthreads();
        #pragma unroll
        for (int ks = 0; ks < 2; ++ks) {
            shortx8 a[2], b[2];
            #pragma unroll
            for (int i = 0; i < 2; ++i) a[i] = *(const shortx8*)&Asb[(ks*4 + 2*mh+i)*512 + lane*8];
            #pragma unroll
            for (int j = 0; j < 2; ++j) b[j] = *(const shortx8*)&Bsb[(ks*4 + 2*nh+j)*512 + lane*8];
            #pragma unroll
            for (int i = 0; i < 2; ++i)
                #pragma unroll
                for (int j = 0; j < 2; ++j)
                    acc[i][j] = __builtin_amdgcn_mfma_f32_16x16x32_bf16(a[i], b[j], acc[i][j], 0, 0, 0);
        }
    }

    #pragma unroll
    for (int i = 0; i < 2; ++i) {
        int cob = (2*mh+i)*16 + lq*4;
        #pragma unroll
        for (int r = 0; r < 4; ++r) {
            int co = cob + r;
            float bv = bias[co];
            #pragma unroll
            for (int j = 0; j < 2; ++j) {
                int col = p0 + (2*nh+j)*16 + lm;
                y2n[(size_t)co*P_ + col] = f2b(acc[i][j][r] + bv);
            }
        }
    }
}

// ---------------------------------------------------------------------------
// BN1 stats from y1t [N*P][64]: partial sums per 512-row block, then finalize
// ---------------------------------------------------------------------------
__global__ __launch_bounds__(256) void stats_partial_kernel(
    const unsigned short* __restrict__ y1t, float* __restrict__ part)
{
    int b = blockIdx.x, tid = threadIdx.x;
    int c = tid & 63, sub = tid >> 6;
    float s = 0.f, q = 0.f;
    for (int rr = 0; rr < 128; ++rr) {
        int row = b*512 + sub*128 + rr;
        float v = b2f(y1t[(size_t)row*C_ + c]);
        s += v;
        q = fmaf(v, v, q);
    }
    __shared__ float ss[256], qq[256];
    ss[tid] = s; qq[tid] = q;
    __syncthreads();
    if (tid < 64) {
        float S = ss[tid] + ss[64+tid] + ss[128+tid] + ss[192+tid];
        float Q = qq[tid] + qq[64+tid] + qq[128+tid] + qq[192+tid];
        part[b*128 + tid]      = S;
        part[b*128 + 64 + tid] = Q;
    }
}

__global__ void stats_final_kernel(
    const float* __restrict__ part,
    const float* __restrict__ gamma, const float* __restrict__ beta,
    float* __restrict__ st1)
{
    int c = threadIdx.x;  // 64 threads
    float S = 0.f, Q = 0.f;
    for (int b = 0; b < 98; ++b) {
        S += part[b*128 + c];
        Q += part[b*128 + 64 + c];
    }
    const float inv = 1.f / (float)(N_*P_);
    float m = S * inv;
    float var = Q * inv - m*m;
    float scale = rsqrtf(var + 1e-5f) * gamma[c];
    st1[c]      = scale;
    st1[64 + c] = beta[c] - m*scale;
}

// ---------------------------------------------------------------------------
__global__ __launch_bounds__(256) void bn_stats_kernel(
    const unsigned short* __restrict__ src, float* __restrict__ stats)
{
    int c   = blockIdx.x;
    int tid = threadIdx.x;
    float s = 0.f, q = 0.f;
    for (int n = 0; n < N_; ++n) {
        const unsigned short* p = src + ((size_t)n*C_ + c)*P_;
        for (int i = tid; i < P_; i += 256) {
            float v = b2f(p[i]);
            s += v;
            q = fmaf(v, v, q);
        }
    }
    #pragma unroll
    for (int o = 32; o; o >>= 1) {
        s += __shfl_down(s, o);
        q += __shfl_down(q, o);
    }
    __shared__ float sh[2][4];
    int wave = tid >> 6;
    if ((tid & 63) == 0) { sh[0][wave] = s; sh[1][wave] = q; }
    __syncthreads();
    if (tid == 0) {
        float S = sh[0][0] + sh[0][1] + sh[0][2] + sh[0][3];
        float Q = sh[1][0] + sh[1][1] + sh[1][2] + sh[1][3];
        const float inv = 1.f / (float)(N_*P_);
        float m  = S * inv;
        float var = Q * inv - m*m;
        stats[c]      = m;
        stats[C_ + c] = rsqrtf(var + 1e-5f);
    }
}

__global__ __launch_bounds__(256) void bn_add_relu_kernel(
    const unsigned short* __restrict__ y2, const float* __restrict__ x,
    const float* __restrict__ stats,
    const float* __restrict__ gamma, const float* __restrict__ beta,
    float* __restrict__ out)
{
    size_t idx = (size_t)blockIdx.x*256 + threadIdx.x;
    int c = (int)((idx / P_) % C_);
    float v = (b2f(y2[idx]) - stats[c]) * stats[C_ + c] * gamma[c] + beta[c] + x[idx];
    out[idx] = fmaxf(v, 0.f);
}

// ---------------------------------------------------------------------------
extern "C" void kernel_launch(void* const* d_in, const int* in_sizes, int n_in,
                              void* d_out, int out_size, void* d_ws, size_t ws_size,
                              hipStream_t stream) {
    const float* x     = (const float*)d_in[0];
    const float* w_off = (const float*)d_in[1];
    const float* b_off = (const float*)d_in[2];
    const float* w1    = (const float*)d_in[3];
    const float* g1    = (const float*)d_in[4];
    const float* be1   = (const float*)d_in[5];
    const float* w2    = (const float*)d_in[6];
    const float* b2    = (const float*)d_in[7];
    const float* g2    = (const float*)d_in[8];
    const float* be2   = (const float*)d_in[9];
    float* out = (float*)d_out;

    // workspace (~88 MB)
    float* st1  = (float*)d_ws;                              // 128 (scale/shift)
    float* st2  = st1 + 128;                                 // 128 (mean/rstd)
    float* part = st2 + 128;                                 // 98*128
    unsigned short* off = (unsigned short*)(part + 98*128);  // N*648*P bf16 (65 MB)
    unsigned short* xt  = off + (size_t)N_*CO_OFF_*P_;       // N*P*64 bf16 (6.4 MB)
    unsigned short* y1t = xt  + (size_t)N_*P_*C_;            // N*P*64 bf16 (6.4 MB)
    unsigned short* y2  = y1t + (size_t)N_*P_*C_;            // N*64*P bf16 (6.4 MB)
    unsigned short* A1k = y2  + (size_t)N_*C_*P_;            // 768*1728 bf16 (2.65 MB)
    unsigned short* A1t = A1k + (size_t)MP_*KK_;             // 64*1728 bf16
    unsigned short* A2t = A1t + (size_t)C_*KK_;              // 64*1728 bf16

    // prep
    transpose_xt_kernel<<<N_*(P_/64), 256, 0, stream>>>(x, xt);
    permA1k_kernel<<<(MP_*KK_+255)/256, 256, 0, stream>>>(w_off, A1k);
    perm_w_kernel<<<(C_*KK_+255)/256, 256, 0, stream>>>(w1, A1t);
    perm_w_kernel<<<(C_*KK_+255)/256, 256, 0, stream>>>(w2, A2t);

    // conv_off fused -> off (both n)
    conv_off_fused<<<2*1176, 256, 0, stream>>>(A1k, xt, b_off, off);

    // deform fused -> y1t (both n)
    deform_fused<<<N_*(P_/64), 256, 0, stream>>>(xt, off, A1t, y1t);

    // BN1 scale/shift
    stats_partial_kernel<<<98, 256, 0, stream>>>(y1t, part);
    stats_final_kernel<<<1, 64, 0, stream>>>(part, g1, be1, st1);

    // conv2 fused (BN1+ReLU on read) -> y2 (both n)
    conv2_fused<<<N_*(P_/64), 256, 0, stream>>>(y1t, st1, A2t, b2, y2);

    // BN2 + residual + ReLU -> out (fp32)
    bn_stats_kernel<<<C_, 256, 0, stream>>>(y2, st2);
    bn_add_relu_kernel<<<(N_*C_*P_)/256, 256, 0, stream>>>(y2, x, st2, g2, be2, out);
}

// Round 8
// 689.357 us; speedup vs baseline: 1.7835x; 1.2041x over previous
//
#include <hip/hip_runtime.h>
#include <hip/hip_bf16.h>

#define N_ 2
#define C_ 64
#define D_ 8
#define H_ 56
#define W_ 56
#define HW_ (H_*W_)        // 3136
#define P_ (D_*HW_)        // 25088
#define G_ 8
#define CPG_ 8
#define K_ 27
#define CO_OFF_ 648        // G * 3 * K
#define MP_ 768            // conv_off M padded to 6*128
#define KK_ 1728           // GEMM K dim (= 27*64, k-major: ktap*64 + ci)
#define KB_ (KK_*2)        // bytes per bf16 row

typedef __attribute__((ext_vector_type(8))) short shortx8;
typedef __attribute__((ext_vector_type(4))) float floatx4;
#define AS1 __attribute__((address_space(1)))
#define AS3 __attribute__((address_space(3)))

__device__ inline float b2f(unsigned short u) {
    union { unsigned u; float f; } x; x.u = ((unsigned)u) << 16; return x.f;
}
__device__ inline unsigned short f2b(float f) {
    union { float f; unsigned u; } x; x.f = f;
    unsigned r = (x.u + 0x7fffu + ((x.u >> 16) & 1u)) >> 16;   // RNE
    return (unsigned short)r;
}
__device__ inline float lof(unsigned u) { union { unsigned u; float f; } x; x.u = u << 16; return x.f; }
__device__ inline float hif(unsigned u) { union { unsigned u; float f; } x; x.u = u & 0xffff0000u; return x.f; }

// ---------------------------------------------------------------------------
// x [N][64][P] fp32 -> xt [N][P][64] bf16  (64p x 64c LDS tile transpose)
// ---------------------------------------------------------------------------
__global__ __launch_bounds__(256) void transpose_xt_kernel(
    const float* __restrict__ x, unsigned short* __restrict__ xt)
{
    __shared__ unsigned short tile[64][65];
    int b  = blockIdx.x;
    int n  = b / (P_/64);
    int p0 = (b % (P_/64))*64;
    int tid = threadIdx.x;
    int j  = tid & 63;
    int c0 = (tid >> 6)*16;
    for (int r = 0; r < 16; ++r)
        tile[c0 + r][j] = f2b(x[((size_t)n*C_ + c0 + r)*P_ + p0 + j]);
    __syncthreads();
    unsigned* dst = (unsigned*)(xt + ((size_t)n*P_ + p0)*C_);
    #pragma unroll
    for (int it = 0; it < 8; ++it) {
        int wi  = it*256 + tid;
        int row = wi >> 5;
        int c   = (wi & 31)*2;
        unsigned lo = tile[c][row], hi = tile[c+1][row];
        dst[(size_t)row*32 + (wi & 31)] = lo | (hi << 16);
    }
}

// w_off [648][64][27] fp32 -> A1k [768][kk*64+ci] bf16 (k-major, zero-pad rows)
__global__ __launch_bounds__(256) void permA1k_kernel(
    const float* __restrict__ w, unsigned short* __restrict__ A)
{
    int i = blockIdx.x*256 + threadIdx.x;
    if (i >= MP_*KK_) return;
    int m = i / KK_, r = i % KK_;
    int kk = r / 64, ci = r % 64;
    A[i] = (m < CO_OFF_) ? f2b(w[((size_t)m*C_ + ci)*K_ + kk]) : (unsigned short)0;
}

// w [O=64][I=64][27] fp32 -> At[o][k*64+i] bf16 (k-major)
__global__ __launch_bounds__(256) void perm_w_kernel(
    const float* __restrict__ w, unsigned short* __restrict__ At)
{
    int tid = blockIdx.x*256 + threadIdx.x;
    if (tid >= C_*KK_) return;
    int o  = tid / KK_;
    int r  = tid % KK_;
    int k  = r / 64, i = r % 64;
    At[tid] = f2b(w[((size_t)o*C_ + i)*K_ + k]);
}

// ---------------------------------------------------------------------------
// conv_off fused: 128x128 tile, BK=64 (one tap), both n in one grid.
// B-stage: octet-per-row mapping (lane&7 = k-octet, lane>>3 = p row) so one
// load octet = one full 128B xt line. LDS write XOR-swizzled (col ^ koct),
// read compensates with lm ^ (ks*4+lq): conflict-free both sides.
// ---------------------------------------------------------------------------
__global__ __launch_bounds__(256) void conv_off_fused(
    const unsigned short* __restrict__ A,    // A1k [768][1728]
    const unsigned short* __restrict__ xt,   // [N][P][64] bf16
    const float* __restrict__ bias,          // [648]
    unsigned short* __restrict__ off)        // [N][648][P] bf16
{
    __shared__ __align__(16) short As[16*512];
    __shared__ __align__(16) short Bs[16*512];
    int tid = threadIdx.x;
    int w = tid >> 6, lane = tid & 63;
    int n   = blockIdx.x / 1176;
    int bid = blockIdx.x % 1176;
    int mt, nt;
    if (bid < 1152) { int c = bid/48, r = bid%48; mt = r >> 3; nt = c*8 + (r&7); }
    else            { int r = bid - 1152;         mt = r >> 2; nt = 192 + (r&3); }
    int m0 = mt*128, p0 = nt*128;
    int lm = lane & 15, lq = lane >> 4;

    const unsigned short* xtn = xt + (size_t)n*P_*C_;
    unsigned short* out = off + (size_t)n*CO_OFF_*P_;

    const char* Ab0 = (const char*)A + (size_t)(m0 + w*32 + lm)*KB_ + lq*16;
    const char* Ab1 = Ab0 + (size_t)16*KB_;

    // B-task invariants: oct = lane&7 (k-octet), 4 p-rows per thread
    int oct = lane & 7;
    int prj[4], dj[4], hj[4], wj[4];
    #pragma unroll
    for (int j = 0; j < 4; ++j) {
        int prow = j*32 + w*8 + (lane >> 3);
        prj[j] = prow;
        int p = p0 + prow;
        dj[j] = p / HW_;
        int hw2 = p % HW_;
        hj[j] = hw2 / W_;
        wj[j] = hw2 % W_;
    }

    int mh = w >> 1, nh = w & 1;
    floatx4 acc[4][4];
    #pragma unroll
    for (int i = 0; i < 4; ++i)
        #pragma unroll
        for (int j = 0; j < 4; ++j)
            acc[i][j] = (floatx4){0.f, 0.f, 0.f, 0.f};

    for (int kt = 0; kt < 27; ++kt) {
        int kd = kt/9 - 1, kh = (kt/3)%3 - 1, kw = kt%3 - 1;
        int delta = kd*HW_ + kh*W_ + kw;
        __syncthreads();
        __builtin_amdgcn_global_load_lds((const AS1 unsigned*)(Ab0 + kt*128),      (AS3 unsigned*)(As + (w*2)*512),     16, 0, 0);
        __builtin_amdgcn_global_load_lds((const AS1 unsigned*)(Ab1 + kt*128),      (AS3 unsigned*)(As + (w*2+1)*512),   16, 0, 0);
        __builtin_amdgcn_global_load_lds((const AS1 unsigned*)(Ab0 + kt*128 + 64), (AS3 unsigned*)(As + (8+w*2)*512),   16, 0, 0);
        __builtin_amdgcn_global_load_lds((const AS1 unsigned*)(Ab1 + kt*128 + 64), (AS3 unsigned*)(As + (8+w*2+1)*512), 16, 0, 0);
        #pragma unroll
        for (int j = 0; j < 4; ++j) {
            bool v = ((unsigned)(dj[j]+kd) < (unsigned)D_) &&
                     ((unsigned)(hj[j]+kh) < (unsigned)H_) &&
                     ((unsigned)(wj[j]+kw) < (unsigned)W_);
            uint4 val = {0u,0u,0u,0u};
            if (v) val = *(const uint4*)(xtn + (size_t)(p0 + prj[j] + delta)*C_ + oct*8);
            int chunk = (oct>>2)*8 + (prj[j]>>4);
            *(uint4*)&Bs[chunk*512 + ((oct&3)*16 + ((prj[j]&15) ^ oct))*8] = val;
        }
        __syncthreads();
        #pragma unroll
        for (int ks = 0; ks < 2; ++ks) {
            int swzB = (lq*16 + (lm ^ (ks*4 + lq)))*8;
            shortx8 a[4], b[4];
            #pragma unroll
            for (int i = 0; i < 4; ++i) a[i] = *(const shortx8*)&As[(ks*8 + 4*mh + i)*512 + lane*8];
            #pragma unroll
            for (int j = 0; j < 4; ++j) b[j] = *(const shortx8*)&Bs[(ks*8 + 4*nh + j)*512 + swzB];
            #pragma unroll
            for (int i = 0; i < 4; ++i)
                #pragma unroll
                for (int j = 0; j < 4; ++j)
                    acc[i][j] = __builtin_amdgcn_mfma_f32_16x16x32_bf16(a[i], b[j], acc[i][j], 0, 0, 0);
        }
    }

    #pragma unroll
    for (int i = 0; i < 4; ++i) {
        int cob = m0 + (4*mh+i)*16 + lq*4;
        #pragma unroll
        for (int r = 0; r < 4; ++r) {
            int co = cob + r;
            if (co < CO_OFF_) {
                float bv = bias[co];
                #pragma unroll
                for (int j = 0; j < 4; ++j) {
                    int col = p0 + (4*nh+j)*16 + lm;
                    out[(size_t)co*P_ + col] = f2b(acc[i][j][r] + bv);
                }
            }
        }
    }
}

// ---------------------------------------------------------------------------
// deform fused: 64x64 tile, both n. Octet-per-p gather mapping: lane&7 = g,
// lane>>3 = p row -> the 8 g's of one p sample near-identical positions, so
// corner-load octets merge to ~1-2 lines. XOR-swizzled B writes.
// ---------------------------------------------------------------------------
__global__ __launch_bounds__(256) void deform_fused(
    const unsigned short* __restrict__ xt,   // [N][P][64] bf16
    const unsigned short* __restrict__ off,  // [N][648][P] bf16
    const unsigned short* __restrict__ A,    // A1t [64][1728]
    unsigned short* __restrict__ y1t)        // [N][P][64] bf16
{
    __shared__ __align__(16) short SH[8192];  // As = SH[0..4095], Bs = SH[4096..]
    short* Asb = SH;
    short* Bsb = SH + 4096;
    int tid = threadIdx.x;
    int w = tid >> 6, lane = tid & 63;
    int n  = blockIdx.x / (P_/64);
    int p0 = (blockIdx.x % (P_/64))*64;
    int lm = lane & 15, lq = lane >> 4;

    const unsigned short* offn = off + (size_t)n*CO_OFF_*P_;
    const uint4* xg0 = (const uint4*)(xt + (size_t)n*P_*C_);

    const char* Ab = (const char*)A + (size_t)(w*16 + lm)*KB_ + lq*16;

    // task invariants: g = lane&7, 2 p-rows per thread
    int g = lane & 7;
    int prI[2], dI[2], hI[2], wI[2];
    #pragma unroll
    for (int it = 0; it < 2; ++it) {
        int prow = it*32 + w*8 + (lane >> 3);
        prI[it] = prow;
        int p = p0 + prow;
        dI[it] = p / HW_;
        int hw2 = p % HW_;
        hI[it] = hw2 / W_;
        wI[it] = hw2 % W_;
    }

    int mh = w >> 1, nh = w & 1;
    floatx4 acc[2][2];
    #pragma unroll
    for (int i = 0; i < 2; ++i)
        #pragma unroll
        for (int j = 0; j < 2; ++j)
            acc[i][j] = (floatx4){0.f, 0.f, 0.f, 0.f};

    for (int kt = 0; kt < 27; ++kt) {
        int kd = kt/9 - 1, kh = (kt/3)%3 - 1, kw = kt%3 - 1;
        __syncthreads();
        __builtin_amdgcn_global_load_lds((const AS1 unsigned*)(Ab + kt*128),      (AS3 unsigned*)(Asb + w*512),     16, 0, 0);
        __builtin_amdgcn_global_load_lds((const AS1 unsigned*)(Ab + kt*128 + 64), (AS3 unsigned*)(Asb + (4+w)*512), 16, 0, 0);
        #pragma unroll
        for (int it = 0; it < 2; ++it) {
            int prow = prI[it];
            int p = p0 + prow;
            size_t ob = ((size_t)(g*K_ + kt)*3)*P_ + p;
            float pd = (float)(dI[it] + kd) + b2f(offn[ob]);
            float ph = (float)(hI[it] + kh) + b2f(offn[ob + P_]);
            float pw = (float)(wI[it] + kw) + b2f(offn[ob + 2*(size_t)P_]);
            float fd0 = floorf(pd), fh0 = floorf(ph), fw0 = floorf(pw);
            int d0 = (int)fd0, h0 = (int)fh0, w0i = (int)fw0;
            float fd = pd - fd0, fh = ph - fh0, fw = pw - fw0;
            float res[CPG_];
            #pragma unroll
            for (int c = 0; c < CPG_; ++c) res[c] = 0.f;
            #pragma unroll
            for (int cd = 0; cd < 2; ++cd) {
                int id = d0 + cd;
                float wdt = cd ? fd : 1.f - fd;
                bool vdd = (unsigned)id < (unsigned)D_;
                int idc = min(max(id, 0), D_-1);
                #pragma unroll
                for (int ch = 0; ch < 2; ++ch) {
                    int ih = h0 + ch;
                    float wht = ch ? fh : 1.f - fh;
                    bool vhh = (unsigned)ih < (unsigned)H_;
                    int ihc = min(max(ih, 0), H_-1);
                    #pragma unroll
                    for (int cw = 0; cw < 2; ++cw) {
                        int iw = w0i + cw;
                        float wwt = cw ? fw : 1.f - fw;
                        bool vww = (unsigned)iw < (unsigned)W_;
                        int iwc = min(max(iw, 0), W_-1);
                        float wgt = (vdd && vhh && vww) ? wdt*wht*wwt : 0.f;
                        int lin = (idc*H_ + ihc)*W_ + iwc;
                        uint4 v4 = xg0[(size_t)lin*(C_/8) + g];
                        res[0] = fmaf(wgt, lof(v4.x), res[0]);
                        res[1] = fmaf(wgt, hif(v4.x), res[1]);
                        res[2] = fmaf(wgt, lof(v4.y), res[2]);
                        res[3] = fmaf(wgt, hif(v4.y), res[3]);
                        res[4] = fmaf(wgt, lof(v4.z), res[4]);
                        res[5] = fmaf(wgt, hif(v4.z), res[5]);
                        res[6] = fmaf(wgt, lof(v4.w), res[6]);
                        res[7] = fmaf(wgt, hif(v4.w), res[7]);
                    }
                }
            }
            uint4 o4;
            o4.x = (unsigned)f2b(res[0]) | ((unsigned)f2b(res[1]) << 16);
            o4.y = (unsigned)f2b(res[2]) | ((unsigned)f2b(res[3]) << 16);
            o4.z = (unsigned)f2b(res[4]) | ((unsigned)f2b(res[5]) << 16);
            o4.w = (unsigned)f2b(res[6]) | ((unsigned)f2b(res[7]) << 16);
            int chunk = (g>>2)*4 + (prow>>4);
            *(uint4*)&Bsb[chunk*512 + ((g&3)*16 + ((prow&15) ^ g))*8] = o4;
        }
        __syncthreads();
        #pragma unroll
        for (int ks = 0; ks < 2; ++ks) {
            int swzB = (lq*16 + (lm ^ (ks*4 + lq)))*8;
            shortx8 a[2], b[2];
            #pragma unroll
            for (int i = 0; i < 2; ++i) a[i] = *(const shortx8*)&Asb[(ks*4 + 2*mh+i)*512 + lane*8];
            #pragma unroll
            for (int j = 0; j < 2; ++j) b[j] = *(const shortx8*)&Bsb[(ks*4 + 2*nh+j)*512 + swzB];
            #pragma unroll
            for (int i = 0; i < 2; ++i)
                #pragma unroll
                for (int j = 0; j < 2; ++j)
                    acc[i][j] = __builtin_amdgcn_mfma_f32_16x16x32_bf16(a[i], b[j], acc[i][j], 0, 0, 0);
        }
    }

    // epilogue: transpose 64o x 64p tile to y1t[p][o] via LDS (stride 72)
    __syncthreads();
    #pragma unroll
    for (int i = 0; i < 2; ++i) {
        int ob = mh*32 + i*16 + lq*4;
        #pragma unroll
        for (int j = 0; j < 2; ++j) {
            int pc = nh*32 + j*16 + lm;
            #pragma unroll
            for (int rr = 0; rr < 4; ++rr)
                SH[pc*72 + ob + rr] = (short)f2b(acc[i][j][rr]);
        }
    }
    __syncthreads();
    {
        int row = tid >> 2, seg = tid & 3;
        uint4 v0 = *(const uint4*)&SH[row*72 + seg*16];
        uint4 v1 = *(const uint4*)&SH[row*72 + seg*16 + 8];
        uint4* dst = (uint4*)(y1t + ((size_t)n*P_ + p0 + row)*C_ + seg*16);
        dst[0] = v0;
        dst[1] = v1;
    }
}

// ---------------------------------------------------------------------------
// conv2 fused: 64x64 tile, both n. B = BN1+ReLU(y1t) shifted; octet-per-row
// mapping (one full line per load octet) + XOR-swizzled LDS writes.
// ---------------------------------------------------------------------------
__global__ __launch_bounds__(256) void conv2_fused(
    const unsigned short* __restrict__ y1t,  // [N][P][64] bf16
    const float* __restrict__ st1,           // [64] scale, [64] shift
    const unsigned short* __restrict__ A,    // A2t [64][1728]
    const float* __restrict__ bias,          // [64]
    unsigned short* __restrict__ y2)         // [N][64][P] bf16
{
    __shared__ __align__(16) short SH[8192];
    short* Asb = SH;
    short* Bsb = SH + 4096;
    __shared__ float sc[64], sf[64];
    int tid = threadIdx.x;
    if (tid < 64) sc[tid] = st1[tid];
    else if (tid < 128) sf[tid-64] = st1[tid];
    int w = tid >> 6, lane = tid & 63;
    int n  = blockIdx.x / (P_/64);
    int p0 = (blockIdx.x % (P_/64))*64;
    int lm = lane & 15, lq = lane >> 4;

    const unsigned short* y1n = y1t + (size_t)n*P_*C_;
    unsigned short* y2n = y2 + (size_t)n*C_*P_;

    const char* Ab = (const char*)A + (size_t)(w*16 + lm)*KB_ + lq*16;

    // task invariants: oct = lane&7, 2 p-rows per thread
    int oct = lane & 7;
    int cb = oct*8;
    int prJ[2], dJ[2], hJ[2], wJ[2];
    #pragma unroll
    for (int j = 0; j < 2; ++j) {
        int prow = j*32 + w*8 + (lane >> 3);
        prJ[j] = prow;
        int p = p0 + prow;
        dJ[j] = p / HW_;
        int hw2 = p % HW_;
        hJ[j] = hw2 / W_;
        wJ[j] = hw2 % W_;
    }

    int mh = w >> 1, nh = w & 1;
    floatx4 acc[2][2];
    #pragma unroll
    for (int i = 0; i < 2; ++i)
        #pragma unroll
        for (int j = 0; j < 2; ++j)
            acc[i][j] = (floatx4){0.f, 0.f, 0.f, 0.f};

    for (int kt = 0; kt < 27; ++kt) {
        int kd = kt/9 - 1, kh = (kt/3)%3 - 1, kw = kt%3 - 1;
        int delta = kd*HW_ + kh*W_ + kw;
        __syncthreads();
        __builtin_amdgcn_global_load_lds((const AS1 unsigned*)(Ab + kt*128),      (AS3 unsigned*)(Asb + w*512),     16, 0, 0);
        __builtin_amdgcn_global_load_lds((const AS1 unsigned*)(Ab + kt*128 + 64), (AS3 unsigned*)(Asb + (4+w)*512), 16, 0, 0);
        #pragma unroll
        for (int j = 0; j < 2; ++j) {
            bool v = ((unsigned)(dJ[j]+kd) < (unsigned)D_) &&
                     ((unsigned)(hJ[j]+kh) < (unsigned)H_) &&
                     ((unsigned)(wJ[j]+kw) < (unsigned)W_);
            uint4 o4 = {0u,0u,0u,0u};
            if (v) {
                uint4 val = *(const uint4*)(y1n + (size_t)(p0 + prJ[j] + delta)*C_ + oct*8);
                float r0 = fmaxf(lof(val.x)*sc[cb+0] + sf[cb+0], 0.f);
                float r1 = fmaxf(hif(val.x)*sc[cb+1] + sf[cb+1], 0.f);
                float r2 = fmaxf(lof(val.y)*sc[cb+2] + sf[cb+2], 0.f);
                float r3 = fmaxf(hif(val.y)*sc[cb+3] + sf[cb+3], 0.f);
                float r4 = fmaxf(lof(val.z)*sc[cb+4] + sf[cb+4], 0.f);
                float r5 = fmaxf(hif(val.z)*sc[cb+5] + sf[cb+5], 0.f);
                float r6 = fmaxf(lof(val.w)*sc[cb+6] + sf[cb+6], 0.f);
                float r7 = fmaxf(hif(val.w)*sc[cb+7] + sf[cb+7], 0.f);
                o4.x = (unsigned)f2b(r0) | ((unsigned)f2b(r1) << 16);
                o4.y = (unsigned)f2b(r2) | ((unsigned)f2b(r3) << 16);
                o4.z = (unsigned)f2b(r4) | ((unsigned)f2b(r5) << 16);
                o4.w = (unsigned)f2b(r6) | ((unsigned)f2b(r7) << 16);
            }
            int chunk = (oct>>2)*4 + (prJ[j]>>4);
            *(uint4*)&Bsb[chunk*512 + ((oct&3)*16 + ((prJ[j]&15) ^ oct))*8] = o4;
        }
        __syncthreads();
        #pragma unroll
        for (int ks = 0; ks < 2; ++ks) {
            int swzB = (lq*16 + (lm ^ (ks*4 + lq)))*8;
            shortx8 a[2], b[2];
            #pragma unroll
            for (int i = 0; i < 2; ++i) a[i] = *(const shortx8*)&Asb[(ks*4 + 2*mh+i)*512 + lane*8];
            #pragma unroll
            for (int j = 0; j < 2; ++j) b[j] = *(const shortx8*)&Bsb[(ks*4 + 2*nh+j)*512 + swzB];
            #pragma unroll
            for (int i = 0; i < 2; ++i)
                #pragma unroll
                for (int j = 0; j < 2; ++j)
                    acc[i][j] = __builtin_amdgcn_mfma_f32_16x16x32_bf16(a[i], b[j], acc[i][j], 0, 0, 0);
        }
    }

    #pragma unroll
    for (int i = 0; i < 2; ++i) {
        int cob = (2*mh+i)*16 + lq*4;
        #pragma unroll
        for (int r = 0; r < 4; ++r) {
            int co = cob + r;
            float bv = bias[co];
            #pragma unroll
            for (int j = 0; j < 2; ++j) {
                int col = p0 + (2*nh+j)*16 + lm;
                y2n[(size_t)co*P_ + col] = f2b(acc[i][j][r] + bv);
            }
        }
    }
}

// ---------------------------------------------------------------------------
// BN1 stats from y1t [N*P][64]: partial sums per 512-row block, then finalize
// ---------------------------------------------------------------------------
__global__ __launch_bounds__(256) void stats_partial_kernel(
    const unsigned short* __restrict__ y1t, float* __restrict__ part)
{
    int b = blockIdx.x, tid = threadIdx.x;
    int c = tid & 63, sub = tid >> 6;
    float s = 0.f, q = 0.f;
    for (int rr = 0; rr < 128; ++rr) {
        int row = b*512 + sub*128 + rr;
        float v = b2f(y1t[(size_t)row*C_ + c]);
        s += v;
        q = fmaf(v, v, q);
    }
    __shared__ float ss[256], qq[256];
    ss[tid] = s; qq[tid] = q;
    __syncthreads();
    if (tid < 64) {
        float S = ss[tid] + ss[64+tid] + ss[128+tid] + ss[192+tid];
        float Q = qq[tid] + qq[64+tid] + qq[128+tid] + qq[192+tid];
        part[b*128 + tid]      = S;
        part[b*128 + 64 + tid] = Q;
    }
}

__global__ void stats_final_kernel(
    const float* __restrict__ part,
    const float* __restrict__ gamma, const float* __restrict__ beta,
    float* __restrict__ st1)
{
    int c = threadIdx.x;  // 64 threads
    float S = 0.f, Q = 0.f;
    for (int b = 0; b < 98; ++b) {
        S += part[b*128 + c];
        Q += part[b*128 + 64 + c];
    }
    const float inv = 1.f / (float)(N_*P_);
    float m = S * inv;
    float var = Q * inv - m*m;
    float scale = rsqrtf(var + 1e-5f) * gamma[c];
    st1[c]      = scale;
    st1[64 + c] = beta[c] - m*scale;
}

// ---------------------------------------------------------------------------
__global__ __launch_bounds__(256) void bn_stats_kernel(
    const unsigned short* __restrict__ src, float* __restrict__ stats)
{
    int c   = blockIdx.x;
    int tid = threadIdx.x;
    float s = 0.f, q = 0.f;
    for (int n = 0; n < N_; ++n) {
        const unsigned short* p = src + ((size_t)n*C_ + c)*P_;
        for (int i = tid; i < P_; i += 256) {
            float v = b2f(p[i]);
            s += v;
            q = fmaf(v, v, q);
        }
    }
    #pragma unroll
    for (int o = 32; o; o >>= 1) {
        s += __shfl_down(s, o);
        q += __shfl_down(q, o);
    }
    __shared__ float sh[2][4];
    int wave = tid >> 6;
    if ((tid & 63) == 0) { sh[0][wave] = s; sh[1][wave] = q; }
    __syncthreads();
    if (tid == 0) {
        float S = sh[0][0] + sh[0][1] + sh[0][2] + sh[0][3];
        float Q = sh[1][0] + sh[1][1] + sh[1][2] + sh[1][3];
        const float inv = 1.f / (float)(N_*P_);
        float m  = S * inv;
        float var = Q * inv - m*m;
        stats[c]      = m;
        stats[C_ + c] = rsqrtf(var + 1e-5f);
    }
}

__global__ __launch_bounds__(256) void bn_add_relu_kernel(
    const unsigned short* __restrict__ y2, const float* __restrict__ x,
    const float* __restrict__ stats,
    const float* __restrict__ gamma, const float* __restrict__ beta,
    float* __restrict__ out)
{
    size_t idx = (size_t)blockIdx.x*256 + threadIdx.x;
    int c = (int)((idx / P_) % C_);
    float v = (b2f(y2[idx]) - stats[c]) * stats[C_ + c] * gamma[c] + beta[c] + x[idx];
    out[idx] = fmaxf(v, 0.f);
}

// ---------------------------------------------------------------------------
extern "C" void kernel_launch(void* const* d_in, const int* in_sizes, int n_in,
                              void* d_out, int out_size, void* d_ws, size_t ws_size,
                              hipStream_t stream) {
    const float* x     = (const float*)d_in[0];
    const float* w_off = (const float*)d_in[1];
    const float* b_off = (const float*)d_in[2];
    const float* w1    = (const float*)d_in[3];
    const float* g1    = (const float*)d_in[4];
    const float* be1   = (const float*)d_in[5];
    const float* w2    = (const float*)d_in[6];
    const float* b2    = (const float*)d_in[7];
    const float* g2    = (const float*)d_in[8];
    const float* be2   = (const float*)d_in[9];
    float* out = (float*)d_out;

    // workspace (~88 MB)
    float* st1  = (float*)d_ws;                              // 128 (scale/shift)
    float* st2  = st1 + 128;                                 // 128 (mean/rstd)
    float* part = st2 + 128;                                 // 98*128
    unsigned short* off = (unsigned short*)(part + 98*128);  // N*648*P bf16 (65 MB)
    unsigned short* xt  = off + (size_t)N_*CO_OFF_*P_;       // N*P*64 bf16 (6.4 MB)
    unsigned short* y1t = xt  + (size_t)N_*P_*C_;            // N*P*64 bf16 (6.4 MB)
    unsigned short* y2  = y1t + (size_t)N_*P_*C_;            // N*64*P bf16 (6.4 MB)
    unsigned short* A1k = y2  + (size_t)N_*C_*P_;            // 768*1728 bf16 (2.65 MB)
    unsigned short* A1t = A1k + (size_t)MP_*KK_;             // 64*1728 bf16
    unsigned short* A2t = A1t + (size_t)C_*KK_;              // 64*1728 bf16

    // prep
    transpose_xt_kernel<<<N_*(P_/64), 256, 0, stream>>>(x, xt);
    permA1k_kernel<<<(MP_*KK_+255)/256, 256, 0, stream>>>(w_off, A1k);
    perm_w_kernel<<<(C_*KK_+255)/256, 256, 0, stream>>>(w1, A1t);
    perm_w_kernel<<<(C_*KK_+255)/256, 256, 0, stream>>>(w2, A2t);

    // conv_off fused -> off (both n)
    conv_off_fused<<<2*1176, 256, 0, stream>>>(A1k, xt, b_off, off);

    // deform fused -> y1t (both n)
    deform_fused<<<N_*(P_/64), 256, 0, stream>>>(xt, off, A1t, y1t);

    // BN1 scale/shift
    stats_partial_kernel<<<98, 256, 0, stream>>>(y1t, part);
    stats_final_kernel<<<1, 64, 0, stream>>>(part, g1, be1, st1);

    // conv2 fused (BN1+ReLU on read) -> y2 (both n)
    conv2_fused<<<N_*(P_/64), 256, 0, stream>>>(y1t, st1, A2t, b2, y2);

    // BN2 + residual + ReLU -> out (fp32)
    bn_stats_kernel<<<C_, 256, 0, stream>>>(y2, st2);
    bn_add_relu_kernel<<<(N_*C_*P_)/256, 256, 0, stream>>>(y2, x, st2, g2, be2, out);
}

// Round 9
// 591.987 us; speedup vs baseline: 2.0768x; 1.1645x over previous
//
#include <hip/hip_runtime.h>
#include <hip/hip_bf16.h>

#define N_ 2
#define C_ 64
#define D_ 8
#define H_ 56
#define W_ 56
#define HW_ (H_*W_)        // 3136
#define P_ (D_*HW_)        // 25088
#define G_ 8
#define CPG_ 8
#define K_ 27
#define CO_OFF_ 648        // G * 3 * K
#define MP_ 768            // conv_off M padded to 6*128
#define KK_ 1728           // GEMM K dim (= 27*64, k-major: ktap*64 + ci)
#define KB_ (KK_*2)        // bytes per bf16 row

typedef __attribute__((ext_vector_type(8))) short shortx8;
typedef __attribute__((ext_vector_type(4))) float floatx4;
#define AS1 __attribute__((address_space(1)))
#define AS3 __attribute__((address_space(3)))

__device__ inline float b2f(unsigned short u) {
    union { unsigned u; float f; } x; x.u = ((unsigned)u) << 16; return x.f;
}
__device__ inline unsigned short f2b(float f) {
    union { float f; unsigned u; } x; x.f = f;
    unsigned r = (x.u + 0x7fffu + ((x.u >> 16) & 1u)) >> 16;   // RNE
    return (unsigned short)r;
}
__device__ inline float lof(unsigned u) { union { unsigned u; float f; } x; x.u = u << 16; return x.f; }
__device__ inline float hif(unsigned u) { union { unsigned u; float f; } x; x.u = u & 0xffff0000u; return x.f; }

// ---------------------------------------------------------------------------
// x [N][64][P] fp32 -> xt [N][P][64] bf16  (64p x 64c LDS tile transpose)
// ---------------------------------------------------------------------------
__global__ __launch_bounds__(256) void transpose_xt_kernel(
    const float* __restrict__ x, unsigned short* __restrict__ xt)
{
    __shared__ unsigned short tile[64][65];
    int b  = blockIdx.x;
    int n  = b / (P_/64);
    int p0 = (b % (P_/64))*64;
    int tid = threadIdx.x;
    int j  = tid & 63;
    int c0 = (tid >> 6)*16;
    for (int r = 0; r < 16; ++r)
        tile[c0 + r][j] = f2b(x[((size_t)n*C_ + c0 + r)*P_ + p0 + j]);
    __syncthreads();
    unsigned* dst = (unsigned*)(xt + ((size_t)n*P_ + p0)*C_);
    #pragma unroll
    for (int it = 0; it < 8; ++it) {
        int wi  = it*256 + tid;
        int row = wi >> 5;
        int c   = (wi & 31)*2;
        unsigned lo = tile[c][row], hi = tile[c+1][row];
        dst[(size_t)row*32 + (wi & 31)] = lo | (hi << 16);
    }
}

// w_off [648][64][27] fp32 -> A1k [768][kk*64+ci] bf16 (k-major, zero-pad rows)
__global__ __launch_bounds__(256) void permA1k_kernel(
    const float* __restrict__ w, unsigned short* __restrict__ A)
{
    int i = blockIdx.x*256 + threadIdx.x;
    if (i >= MP_*KK_) return;
    int m = i / KK_, r = i % KK_;
    int kk = r / 64, ci = r % 64;
    A[i] = (m < CO_OFF_) ? f2b(w[((size_t)m*C_ + ci)*K_ + kk]) : (unsigned short)0;
}

// w [O=64][I=64][27] fp32 -> At[o][k*64+i] bf16 (k-major)
__global__ __launch_bounds__(256) void perm_w_kernel(
    const float* __restrict__ w, unsigned short* __restrict__ At)
{
    int tid = blockIdx.x*256 + threadIdx.x;
    if (tid >= C_*KK_) return;
    int o  = tid / KK_;
    int r  = tid % KK_;
    int k  = r / 64, i = r % 64;
    At[tid] = f2b(w[((size_t)o*C_ + i)*K_ + k]);
}

// ---------------------------------------------------------------------------
// conv_off fused, software-pipelined: A double-buffered in LDS (prefetched
// during previous MFMA phase), B prefetched into regs one kt ahead. Between
// the two barriers only reg->LDS ds_writes remain.
// ---------------------------------------------------------------------------
__global__ __launch_bounds__(256) void conv_off_fused(
    const unsigned short* __restrict__ A,    // A1k [768][1728]
    const unsigned short* __restrict__ xt,   // [N][P][64] bf16
    const float* __restrict__ bias,          // [648]
    unsigned short* __restrict__ off)        // [N][648][P] bf16
{
    __shared__ __align__(16) short As[2][16*512];
    __shared__ __align__(16) short Bs[16*512];
    int tid = threadIdx.x;
    int w = tid >> 6, lane = tid & 63;
    int n   = blockIdx.x / 1176;
    int bid = blockIdx.x % 1176;
    int mt, nt;
    if (bid < 1152) { int c = bid/48, r = bid%48; mt = r >> 3; nt = c*8 + (r&7); }
    else            { int r = bid - 1152;         mt = r >> 2; nt = 192 + (r&3); }
    int m0 = mt*128, p0 = nt*128;
    int lm = lane & 15, lq = lane >> 4;

    const unsigned short* xtn = xt + (size_t)n*P_*C_;
    unsigned short* out = off + (size_t)n*CO_OFF_*P_;

    const char* Ab0 = (const char*)A + (size_t)(m0 + w*32 + lm)*KB_ + lq*16;
    const char* Ab1 = Ab0 + (size_t)16*KB_;

    // B-task invariants: oct = lane&7 (k-octet), 4 p-rows per thread
    int oct = lane & 7;
    int prj[4], dj[4], hj[4], wj[4];
    #pragma unroll
    for (int j = 0; j < 4; ++j) {
        int prow = j*32 + w*8 + (lane >> 3);
        prj[j] = prow;
        int p = p0 + prow;
        dj[j] = p / HW_;
        int hw2 = p % HW_;
        hj[j] = hw2 / W_;
        wj[j] = hw2 % W_;
    }

    auto stageA = [&](int kt, int buf) {
        __builtin_amdgcn_global_load_lds((const AS1 unsigned*)(Ab0 + kt*128),      (AS3 unsigned*)(&As[buf][(w*2)*512]),     16, 0, 0);
        __builtin_amdgcn_global_load_lds((const AS1 unsigned*)(Ab1 + kt*128),      (AS3 unsigned*)(&As[buf][(w*2+1)*512]),   16, 0, 0);
        __builtin_amdgcn_global_load_lds((const AS1 unsigned*)(Ab0 + kt*128 + 64), (AS3 unsigned*)(&As[buf][(8+w*2)*512]),   16, 0, 0);
        __builtin_amdgcn_global_load_lds((const AS1 unsigned*)(Ab1 + kt*128 + 64), (AS3 unsigned*)(&As[buf][(8+w*2+1)*512]), 16, 0, 0);
    };
    auto loadB = [&](int kt, uint4* B) {
        int kd = kt/9 - 1, kh = (kt/3)%3 - 1, kw = kt%3 - 1;
        int delta = kd*HW_ + kh*W_ + kw;
        #pragma unroll
        for (int j = 0; j < 4; ++j) {
            bool v = ((unsigned)(dj[j]+kd) < (unsigned)D_) &&
                     ((unsigned)(hj[j]+kh) < (unsigned)H_) &&
                     ((unsigned)(wj[j]+kw) < (unsigned)W_);
            uint4 val = {0u,0u,0u,0u};
            if (v) val = *(const uint4*)(xtn + (size_t)(p0 + prj[j] + delta)*C_ + oct*8);
            B[j] = val;
        }
    };

    int mh = w >> 1, nh = w & 1;
    floatx4 acc[4][4];
    #pragma unroll
    for (int i = 0; i < 4; ++i)
        #pragma unroll
        for (int j = 0; j < 4; ++j)
            acc[i][j] = (floatx4){0.f, 0.f, 0.f, 0.f};

    uint4 Bcur[4], Bnext[4];
    #pragma unroll
    for (int j = 0; j < 4; ++j) Bnext[j] = (uint4){0u,0u,0u,0u};
    stageA(0, 0);
    loadB(0, Bcur);

    for (int kt = 0; kt < 27; ++kt) {
        int buf = kt & 1;
        __syncthreads();   // drains last iter's prefetches (already complete)
        #pragma unroll
        for (int j = 0; j < 4; ++j) {
            int chunk = (oct>>2)*8 + (prj[j]>>4);
            *(uint4*)&Bs[chunk*512 + ((oct&3)*16 + ((prj[j]&15) ^ oct))*8] = Bcur[j];
        }
        __syncthreads();   // only ds_writes pending: cheap drain
        if (kt < 26) { stageA(kt+1, buf^1); loadB(kt+1, Bnext); }
        #pragma unroll
        for (int ks = 0; ks < 2; ++ks) {
            int swzB = (lq*16 + (lm ^ (ks*4 + lq)))*8;
            shortx8 a[4], b[4];
            #pragma unroll
            for (int i = 0; i < 4; ++i) a[i] = *(const shortx8*)&As[buf][(ks*8 + 4*mh + i)*512 + lane*8];
            #pragma unroll
            for (int j = 0; j < 4; ++j) b[j] = *(const shortx8*)&Bs[(ks*8 + 4*nh + j)*512 + swzB];
            #pragma unroll
            for (int i = 0; i < 4; ++i)
                #pragma unroll
                for (int j = 0; j < 4; ++j)
                    acc[i][j] = __builtin_amdgcn_mfma_f32_16x16x32_bf16(a[i], b[j], acc[i][j], 0, 0, 0);
        }
        #pragma unroll
        for (int j = 0; j < 4; ++j) Bcur[j] = Bnext[j];
    }

    #pragma unroll
    for (int i = 0; i < 4; ++i) {
        int cob = m0 + (4*mh+i)*16 + lq*4;
        #pragma unroll
        for (int r = 0; r < 4; ++r) {
            int co = cob + r;
            if (co < CO_OFF_) {
                float bv = bias[co];
                #pragma unroll
                for (int j = 0; j < 4; ++j) {
                    int col = p0 + (4*nh+j)*16 + lm;
                    out[(size_t)co*P_ + col] = f2b(acc[i][j][r] + bv);
                }
            }
        }
    }
}

// ---------------------------------------------------------------------------
// deform fused, pipelined: A double-buffered, off-values prefetched one kt
// ahead. Corner gathers stay in the B-stage (L1/L2-hot xt).
// ---------------------------------------------------------------------------
__global__ __launch_bounds__(256) void deform_fused(
    const unsigned short* __restrict__ xt,   // [N][P][64] bf16
    const unsigned short* __restrict__ off,  // [N][648][P] bf16
    const unsigned short* __restrict__ A,    // A1t [64][1728]
    unsigned short* __restrict__ y1t)        // [N][P][64] bf16
{
    __shared__ __align__(16) short SH[12288]; // As dbuf 2x4096, Bs 4096
    short* Bsb = SH + 8192;
    int tid = threadIdx.x;
    int w = tid >> 6, lane = tid & 63;
    int n  = blockIdx.x / (P_/64);
    int p0 = (blockIdx.x % (P_/64))*64;
    int lm = lane & 15, lq = lane >> 4;

    const unsigned short* offn = off + (size_t)n*CO_OFF_*P_;
    const uint4* xg0 = (const uint4*)(xt + (size_t)n*P_*C_);

    const char* Ab = (const char*)A + (size_t)(w*16 + lm)*KB_ + lq*16;

    // task invariants: g = lane&7, 2 p-rows per thread
    int g = lane & 7;
    int prI[2], dI[2], hI[2], wI[2];
    #pragma unroll
    for (int it = 0; it < 2; ++it) {
        int prow = it*32 + w*8 + (lane >> 3);
        prI[it] = prow;
        int p = p0 + prow;
        dI[it] = p / HW_;
        int hw2 = p % HW_;
        hI[it] = hw2 / W_;
        wI[it] = hw2 % W_;
    }

    auto stageA = [&](int kt, int buf) {
        __builtin_amdgcn_global_load_lds((const AS1 unsigned*)(Ab + kt*128),      (AS3 unsigned*)(SH + buf*4096 + w*512),     16, 0, 0);
        __builtin_amdgcn_global_load_lds((const AS1 unsigned*)(Ab + kt*128 + 64), (AS3 unsigned*)(SH + buf*4096 + (4+w)*512), 16, 0, 0);
    };
    auto loadOff = [&](int kt, float o[2][3]) {
        #pragma unroll
        for (int it = 0; it < 2; ++it) {
            size_t ob = ((size_t)(g*K_ + kt)*3)*P_ + p0 + prI[it];
            o[it][0] = b2f(offn[ob]);
            o[it][1] = b2f(offn[ob + P_]);
            o[it][2] = b2f(offn[ob + 2*(size_t)P_]);
        }
    };

    int mh = w >> 1, nh = w & 1;
    floatx4 acc[2][2];
    #pragma unroll
    for (int i = 0; i < 2; ++i)
        #pragma unroll
        for (int j = 0; j < 2; ++j)
            acc[i][j] = (floatx4){0.f, 0.f, 0.f, 0.f};

    float offC[2][3], offN[2][3];
    #pragma unroll
    for (int it = 0; it < 2; ++it) offN[it][0] = offN[it][1] = offN[it][2] = 0.f;
    stageA(0, 0);
    loadOff(0, offC);

    for (int kt = 0; kt < 27; ++kt) {
        int buf = kt & 1;
        int kd = kt/9 - 1, kh = (kt/3)%3 - 1, kw = kt%3 - 1;
        __syncthreads();
        #pragma unroll
        for (int it = 0; it < 2; ++it) {
            int prow = prI[it];
            float pd = (float)(dI[it] + kd) + offC[it][0];
            float ph = (float)(hI[it] + kh) + offC[it][1];
            float pw = (float)(wI[it] + kw) + offC[it][2];
            float fd0 = floorf(pd), fh0 = floorf(ph), fw0 = floorf(pw);
            int d0 = (int)fd0, h0 = (int)fh0, w0i = (int)fw0;
            float fd = pd - fd0, fh = ph - fh0, fw = pw - fw0;
            float res[CPG_];
            #pragma unroll
            for (int c = 0; c < CPG_; ++c) res[c] = 0.f;
            #pragma unroll
            for (int cd = 0; cd < 2; ++cd) {
                int id = d0 + cd;
                float wdt = cd ? fd : 1.f - fd;
                bool vdd = (unsigned)id < (unsigned)D_;
                int idc = min(max(id, 0), D_-1);
                #pragma unroll
                for (int ch = 0; ch < 2; ++ch) {
                    int ih = h0 + ch;
                    float wht = ch ? fh : 1.f - fh;
                    bool vhh = (unsigned)ih < (unsigned)H_;
                    int ihc = min(max(ih, 0), H_-1);
                    #pragma unroll
                    for (int cw = 0; cw < 2; ++cw) {
                        int iw = w0i + cw;
                        float wwt = cw ? fw : 1.f - fw;
                        bool vww = (unsigned)iw < (unsigned)W_;
                        int iwc = min(max(iw, 0), W_-1);
                        float wgt = (vdd && vhh && vww) ? wdt*wht*wwt : 0.f;
                        int lin = (idc*H_ + ihc)*W_ + iwc;
                        uint4 v4 = xg0[(size_t)lin*(C_/8) + g];
                        res[0] = fmaf(wgt, lof(v4.x), res[0]);
                        res[1] = fmaf(wgt, hif(v4.x), res[1]);
                        res[2] = fmaf(wgt, lof(v4.y), res[2]);
                        res[3] = fmaf(wgt, hif(v4.y), res[3]);
                        res[4] = fmaf(wgt, lof(v4.z), res[4]);
                        res[5] = fmaf(wgt, hif(v4.z), res[5]);
                        res[6] = fmaf(wgt, lof(v4.w), res[6]);
                        res[7] = fmaf(wgt, hif(v4.w), res[7]);
                    }
                }
            }
            uint4 o4;
            o4.x = (unsigned)f2b(res[0]) | ((unsigned)f2b(res[1]) << 16);
            o4.y = (unsigned)f2b(res[2]) | ((unsigned)f2b(res[3]) << 16);
            o4.z = (unsigned)f2b(res[4]) | ((unsigned)f2b(res[5]) << 16);
            o4.w = (unsigned)f2b(res[6]) | ((unsigned)f2b(res[7]) << 16);
            int chunk = (g>>2)*4 + (prow>>4);
            *(uint4*)&Bsb[chunk*512 + ((g&3)*16 + ((prow&15) ^ g))*8] = o4;
        }
        __syncthreads();
        if (kt < 26) { stageA(kt+1, buf^1); loadOff(kt+1, offN); }
        #pragma unroll
        for (int ks = 0; ks < 2; ++ks) {
            int swzB = (lq*16 + (lm ^ (ks*4 + lq)))*8;
            shortx8 a[2], b[2];
            #pragma unroll
            for (int i = 0; i < 2; ++i) a[i] = *(const shortx8*)&SH[buf*4096 + (ks*4 + 2*mh+i)*512 + lane*8];
            #pragma unroll
            for (int j = 0; j < 2; ++j) b[j] = *(const shortx8*)&Bsb[(ks*4 + 2*nh+j)*512 + swzB];
            #pragma unroll
            for (int i = 0; i < 2; ++i)
                #pragma unroll
                for (int j = 0; j < 2; ++j)
                    acc[i][j] = __builtin_amdgcn_mfma_f32_16x16x32_bf16(a[i], b[j], acc[i][j], 0, 0, 0);
        }
        #pragma unroll
        for (int it = 0; it < 2; ++it) {
            offC[it][0] = offN[it][0];
            offC[it][1] = offN[it][1];
            offC[it][2] = offN[it][2];
        }
    }

    // epilogue: transpose 64o x 64p tile to y1t[p][o] via LDS (stride 72)
    __syncthreads();
    #pragma unroll
    for (int i = 0; i < 2; ++i) {
        int ob = mh*32 + i*16 + lq*4;
        #pragma unroll
        for (int j = 0; j < 2; ++j) {
            int pc = nh*32 + j*16 + lm;
            #pragma unroll
            for (int rr = 0; rr < 4; ++rr)
                SH[pc*72 + ob + rr] = (short)f2b(acc[i][j][rr]);
        }
    }
    __syncthreads();
    {
        int row = tid >> 2, seg = tid & 3;
        uint4 v0 = *(const uint4*)&SH[row*72 + seg*16];
        uint4 v1 = *(const uint4*)&SH[row*72 + seg*16 + 8];
        uint4* dst = (uint4*)(y1t + ((size_t)n*P_ + p0 + row)*C_ + seg*16);
        dst[0] = v0;
        dst[1] = v1;
    }
}

// ---------------------------------------------------------------------------
// conv2 fused, pipelined: A double-buffered, raw y1t vals + masks prefetched;
// BN1+ReLU applied at LDS-write time.
// ---------------------------------------------------------------------------
__global__ __launch_bounds__(256) void conv2_fused(
    const unsigned short* __restrict__ y1t,  // [N][P][64] bf16
    const float* __restrict__ st1,           // [64] scale, [64] shift
    const unsigned short* __restrict__ A,    // A2t [64][1728]
    const float* __restrict__ bias,          // [64]
    unsigned short* __restrict__ y2)         // [N][64][P] bf16
{
    __shared__ __align__(16) short SH[12288]; // As dbuf 2x4096, Bs 4096
    short* Bsb = SH + 8192;
    __shared__ float sc[64], sf[64];
    int tid = threadIdx.x;
    if (tid < 64) sc[tid] = st1[tid];
    else if (tid < 128) sf[tid-64] = st1[tid];
    int w = tid >> 6, lane = tid & 63;
    int n  = blockIdx.x / (P_/64);
    int p0 = (blockIdx.x % (P_/64))*64;
    int lm = lane & 15, lq = lane >> 4;

    const unsigned short* y1n = y1t + (size_t)n*P_*C_;
    unsigned short* y2n = y2 + (size_t)n*C_*P_;

    const char* Ab = (const char*)A + (size_t)(w*16 + lm)*KB_ + lq*16;

    // task invariants: oct = lane&7, 2 p-rows per thread
    int oct = lane & 7;
    int cb = oct*8;
    int prJ[2], dJ[2], hJ[2], wJ[2];
    #pragma unroll
    for (int j = 0; j < 2; ++j) {
        int prow = j*32 + w*8 + (lane >> 3);
        prJ[j] = prow;
        int p = p0 + prow;
        dJ[j] = p / HW_;
        int hw2 = p % HW_;
        hJ[j] = hw2 / W_;
        wJ[j] = hw2 % W_;
    }

    auto stageA = [&](int kt, int buf) {
        __builtin_amdgcn_global_load_lds((const AS1 unsigned*)(Ab + kt*128),      (AS3 unsigned*)(SH + buf*4096 + w*512),     16, 0, 0);
        __builtin_amdgcn_global_load_lds((const AS1 unsigned*)(Ab + kt*128 + 64), (AS3 unsigned*)(SH + buf*4096 + (4+w)*512), 16, 0, 0);
    };
    auto loadV = [&](int kt, uint4* V, int* M) {
        int kd = kt/9 - 1, kh = (kt/3)%3 - 1, kw = kt%3 - 1;
        int delta = kd*HW_ + kh*W_ + kw;
        #pragma unroll
        for (int j = 0; j < 2; ++j) {
            bool v = ((unsigned)(dJ[j]+kd) < (unsigned)D_) &&
                     ((unsigned)(hJ[j]+kh) < (unsigned)H_) &&
                     ((unsigned)(wJ[j]+kw) < (unsigned)W_);
            uint4 val = {0u,0u,0u,0u};
            if (v) val = *(const uint4*)(y1n + (size_t)(p0 + prJ[j] + delta)*C_ + oct*8);
            V[j] = val;
            M[j] = v ? 1 : 0;
        }
    };

    int mh = w >> 1, nh = w & 1;
    floatx4 acc[2][2];
    #pragma unroll
    for (int i = 0; i < 2; ++i)
        #pragma unroll
        for (int j = 0; j < 2; ++j)
            acc[i][j] = (floatx4){0.f, 0.f, 0.f, 0.f};

    uint4 Vcur[2], Vnext[2];
    int Mcur[2], Mnext[2];
    #pragma unroll
    for (int j = 0; j < 2; ++j) { Vnext[j] = (uint4){0u,0u,0u,0u}; Mnext[j] = 0; }
    stageA(0, 0);
    loadV(0, Vcur, Mcur);

    for (int kt = 0; kt < 27; ++kt) {
        int buf = kt & 1;
        __syncthreads();
        #pragma unroll
        for (int j = 0; j < 2; ++j) {
            uint4 o4 = {0u,0u,0u,0u};
            if (Mcur[j]) {
                uint4 val = Vcur[j];
                float r0 = fmaxf(lof(val.x)*sc[cb+0] + sf[cb+0], 0.f);
                float r1 = fmaxf(hif(val.x)*sc[cb+1] + sf[cb+1], 0.f);
                float r2 = fmaxf(lof(val.y)*sc[cb+2] + sf[cb+2], 0.f);
                float r3 = fmaxf(hif(val.y)*sc[cb+3] + sf[cb+3], 0.f);
                float r4 = fmaxf(lof(val.z)*sc[cb+4] + sf[cb+4], 0.f);
                float r5 = fmaxf(hif(val.z)*sc[cb+5] + sf[cb+5], 0.f);
                float r6 = fmaxf(lof(val.w)*sc[cb+6] + sf[cb+6], 0.f);
                float r7 = fmaxf(hif(val.w)*sc[cb+7] + sf[cb+7], 0.f);
                o4.x = (unsigned)f2b(r0) | ((unsigned)f2b(r1) << 16);
                o4.y = (unsigned)f2b(r2) | ((unsigned)f2b(r3) << 16);
                o4.z = (unsigned)f2b(r4) | ((unsigned)f2b(r5) << 16);
                o4.w = (unsigned)f2b(r6) | ((unsigned)f2b(r7) << 16);
            }
            int chunk = (oct>>2)*4 + (prJ[j]>>4);
            *(uint4*)&Bsb[chunk*512 + ((oct&3)*16 + ((prJ[j]&15) ^ oct))*8] = o4;
        }
        __syncthreads();
        if (kt < 26) { stageA(kt+1, buf^1); loadV(kt+1, Vnext, Mnext); }
        #pragma unroll
        for (int ks = 0; ks < 2; ++ks) {
            int swzB = (lq*16 + (lm ^ (ks*4 + lq)))*8;
            shortx8 a[2], b[2];
            #pragma unroll
            for (int i = 0; i < 2; ++i) a[i] = *(const shortx8*)&SH[buf*4096 + (ks*4 + 2*mh+i)*512 + lane*8];
            #pragma unroll
            for (int j = 0; j < 2; ++j) b[j] = *(const shortx8*)&Bsb[(ks*4 + 2*nh+j)*512 + swzB];
            #pragma unroll
            for (int i = 0; i < 2; ++i)
                #pragma unroll
                for (int j = 0; j < 2; ++j)
                    acc[i][j] = __builtin_amdgcn_mfma_f32_16x16x32_bf16(a[i], b[j], acc[i][j], 0, 0, 0);
        }
        #pragma unroll
        for (int j = 0; j < 2; ++j) { Vcur[j] = Vnext[j]; Mcur[j] = Mnext[j]; }
    }

    #pragma unroll
    for (int i = 0; i < 2; ++i) {
        int cob = (2*mh+i)*16 + lq*4;
        #pragma unroll
        for (int r = 0; r < 4; ++r) {
            int co = cob + r;
            float bv = bias[co];
            #pragma unroll
            for (int j = 0; j < 2; ++j) {
                int col = p0 + (2*nh+j)*16 + lm;
                y2n[(size_t)co*P_ + col] = f2b(acc[i][j][r] + bv);
            }
        }
    }
}

// ---------------------------------------------------------------------------
// BN1 stats from y1t [N*P][64]: partial sums per 512-row block, then finalize
// ---------------------------------------------------------------------------
__global__ __launch_bounds__(256) void stats_partial_kernel(
    const unsigned short* __restrict__ y1t, float* __restrict__ part)
{
    int b = blockIdx.x, tid = threadIdx.x;
    int c = tid & 63, sub = tid >> 6;
    float s = 0.f, q = 0.f;
    for (int rr = 0; rr < 128; ++rr) {
        int row = b*512 + sub*128 + rr;
        float v = b2f(y1t[(size_t)row*C_ + c]);
        s += v;
        q = fmaf(v, v, q);
    }
    __shared__ float ss[256], qq[256];
    ss[tid] = s; qq[tid] = q;
    __syncthreads();
    if (tid < 64) {
        float S = ss[tid] + ss[64+tid] + ss[128+tid] + ss[192+tid];
        float Q = qq[tid] + qq[64+tid] + qq[128+tid] + qq[192+tid];
        part[b*128 + tid]      = S;
        part[b*128 + 64 + tid] = Q;
    }
}

__global__ void stats_final_kernel(
    const float* __restrict__ part,
    const float* __restrict__ gamma, const float* __restrict__ beta,
    float* __restrict__ st1)
{
    int c = threadIdx.x;  // 64 threads
    float S = 0.f, Q = 0.f;
    for (int b = 0; b < 98; ++b) {
        S += part[b*128 + c];
        Q += part[b*128 + 64 + c];
    }
    const float inv = 1.f / (float)(N_*P_);
    float m = S * inv;
    float var = Q * inv - m*m;
    float scale = rsqrtf(var + 1e-5f) * gamma[c];
    st1[c]      = scale;
    st1[64 + c] = beta[c] - m*scale;
}

// ---------------------------------------------------------------------------
__global__ __launch_bounds__(256) void bn_stats_kernel(
    const unsigned short* __restrict__ src, float* __restrict__ stats)
{
    int c   = blockIdx.x;
    int tid = threadIdx.x;
    float s = 0.f, q = 0.f;
    for (int n = 0; n < N_; ++n) {
        const unsigned short* p = src + ((size_t)n*C_ + c)*P_;
        for (int i = tid; i < P_; i += 256) {
            float v = b2f(p[i]);
            s += v;
            q = fmaf(v, v, q);
        }
    }
    #pragma unroll
    for (int o = 32; o; o >>= 1) {
        s += __shfl_down(s, o);
        q += __shfl_down(q, o);
    }
    __shared__ float sh[2][4];
    int wave = tid >> 6;
    if ((tid & 63) == 0) { sh[0][wave] = s; sh[1][wave] = q; }
    __syncthreads();
    if (tid == 0) {
        float S = sh[0][0] + sh[0][1] + sh[0][2] + sh[0][3];
        float Q = sh[1][0] + sh[1][1] + sh[1][2] + sh[1][3];
        const float inv = 1.f / (float)(N_*P_);
        float m  = S * inv;
        float var = Q * inv - m*m;
        stats[c]      = m;
        stats[C_ + c] = rsqrtf(var + 1e-5f);
    }
}

__global__ __launch_bounds__(256) void bn_add_relu_kernel(
    const unsigned short* __restrict__ y2, const float* __restrict__ x,
    const float* __restrict__ stats,
    const float* __restrict__ gamma, const float* __restrict__ beta,
    float* __restrict__ out)
{
    size_t idx = (size_t)blockIdx.x*256 + threadIdx.x;
    int c = (int)((idx / P_) % C_);
    float v = (b2f(y2[idx]) - stats[c]) * stats[C_ + c] * gamma[c] + beta[c] + x[idx];
    out[idx] = fmaxf(v, 0.f);
}

// ---------------------------------------------------------------------------
extern "C" void kernel_launch(void* const* d_in, const int* in_sizes, int n_in,
                              void* d_out, int out_size, void* d_ws, size_t ws_size,
                              hipStream_t stream) {
    const float* x     = (const float*)d_in[0];
    const float* w_off = (const float*)d_in[1];
    const float* b_off = (const float*)d_in[2];
    const float* w1    = (const float*)d_in[3];
    const float* g1    = (const float*)d_in[4];
    const float* be1   = (const float*)d_in[5];
    const float* w2    = (const float*)d_in[6];
    const float* b2    = (const float*)d_in[7];
    const float* g2    = (const float*)d_in[8];
    const float* be2   = (const float*)d_in[9];
    float* out = (float*)d_out;

    // workspace (~88 MB)
    float* st1  = (float*)d_ws;                              // 128 (scale/shift)
    float* st2  = st1 + 128;                                 // 128 (mean/rstd)
    float* part = st2 + 128;                                 // 98*128
    unsigned short* off = (unsigned short*)(part + 98*128);  // N*648*P bf16 (65 MB)
    unsigned short* xt  = off + (size_t)N_*CO_OFF_*P_;       // N*P*64 bf16 (6.4 MB)
    unsigned short* y1t = xt  + (size_t)N_*P_*C_;            // N*P*64 bf16 (6.4 MB)
    unsigned short* y2  = y1t + (size_t)N_*P_*C_;            // N*64*P bf16 (6.4 MB)
    unsigned short* A1k = y2  + (size_t)N_*C_*P_;            // 768*1728 bf16 (2.65 MB)
    unsigned short* A1t = A1k + (size_t)MP_*KK_;             // 64*1728 bf16
    unsigned short* A2t = A1t + (size_t)C_*KK_;              // 64*1728 bf16

    // prep
    transpose_xt_kernel<<<N_*(P_/64), 256, 0, stream>>>(x, xt);
    permA1k_kernel<<<(MP_*KK_+255)/256, 256, 0, stream>>>(w_off, A1k);
    perm_w_kernel<<<(C_*KK_+255)/256, 256, 0, stream>>>(w1, A1t);
    perm_w_kernel<<<(C_*KK_+255)/256, 256, 0, stream>>>(w2, A2t);

    // conv_off fused -> off (both n)
    conv_off_fused<<<2*1176, 256, 0, stream>>>(A1k, xt, b_off, off);

    // deform fused -> y1t (both n)
    deform_fused<<<N_*(P_/64), 256, 0, stream>>>(xt, off, A1t, y1t);

    // BN1 scale/shift
    stats_partial_kernel<<<98, 256, 0, stream>>>(y1t, part);
    stats_final_kernel<<<1, 64, 0, stream>>>(part, g1, be1, st1);

    // conv2 fused (BN1+ReLU on read) -> y2 (both n)
    conv2_fused<<<N_*(P_/64), 256, 0, stream>>>(y1t, st1, A2t, b2, y2);

    // BN2 + residual + ReLU -> out (fp32)
    bn_stats_kernel<<<C_, 256, 0, stream>>>(y2, st2);
    bn_add_relu_kernel<<<(N_*C_*P_)/256, 256, 0, stream>>>(y2, x, st2, g2, be2, out);
}

// Round 10
// 571.265 us; speedup vs baseline: 2.1522x; 1.0363x over previous
//
#include <hip/hip_runtime.h>
#include <hip/hip_bf16.h>

#define N_ 2
#define C_ 64
#define D_ 8
#define H_ 56
#define W_ 56
#define HW_ (H_*W_)        // 3136
#define P_ (D_*HW_)        // 25088
#define G_ 8
#define CPG_ 8
#define K_ 27
#define CO_OFF_ 648        // G * 3 * K
#define MP_ 768            // conv_off M padded to 6*128
#define KK_ 1728           // GEMM K dim (= 27*64, k-major: ktap*64 + ci)
#define KB_ (KK_*2)        // bytes per bf16 row

typedef __attribute__((ext_vector_type(8))) short shortx8;
typedef __attribute__((ext_vector_type(4))) float floatx4;
#define AS1 __attribute__((address_space(1)))
#define AS3 __attribute__((address_space(3)))

__device__ inline float b2f(unsigned short u) {
    union { unsigned u; float f; } x; x.u = ((unsigned)u) << 16; return x.f;
}
__device__ inline unsigned short f2b(float f) {
    union { float f; unsigned u; } x; x.f = f;
    unsigned r = (x.u + 0x7fffu + ((x.u >> 16) & 1u)) >> 16;   // RNE
    return (unsigned short)r;
}
__device__ inline float lof(unsigned u) { union { unsigned u; float f; } x; x.u = u << 16; return x.f; }
__device__ inline float hif(unsigned u) { union { unsigned u; float f; } x; x.u = u & 0xffff0000u; return x.f; }

// ---------------------------------------------------------------------------
// x [N][64][P] fp32 -> xt [N][P][64] bf16  (64p x 64c LDS tile transpose)
// ---------------------------------------------------------------------------
__global__ __launch_bounds__(256) void transpose_xt_kernel(
    const float* __restrict__ x, unsigned short* __restrict__ xt)
{
    __shared__ unsigned short tile[64][65];
    int b  = blockIdx.x;
    int n  = b / (P_/64);
    int p0 = (b % (P_/64))*64;
    int tid = threadIdx.x;
    int j  = tid & 63;
    int c0 = (tid >> 6)*16;
    for (int r = 0; r < 16; ++r)
        tile[c0 + r][j] = f2b(x[((size_t)n*C_ + c0 + r)*P_ + p0 + j]);
    __syncthreads();
    unsigned* dst = (unsigned*)(xt + ((size_t)n*P_ + p0)*C_);
    #pragma unroll
    for (int it = 0; it < 8; ++it) {
        int wi  = it*256 + tid;
        int row = wi >> 5;
        int c   = (wi & 31)*2;
        unsigned lo = tile[c][row], hi = tile[c+1][row];
        dst[(size_t)row*32 + (wi & 31)] = lo | (hi << 16);
    }
}

// w_off [648][64][27] fp32 -> A1k [768][kk*64+ci] bf16 (k-major, zero-pad rows)
__global__ __launch_bounds__(256) void permA1k_kernel(
    const float* __restrict__ w, unsigned short* __restrict__ A)
{
    int i = blockIdx.x*256 + threadIdx.x;
    if (i >= MP_*KK_) return;
    int m = i / KK_, r = i % KK_;
    int kk = r / 64, ci = r % 64;
    A[i] = (m < CO_OFF_) ? f2b(w[((size_t)m*C_ + ci)*K_ + kk]) : (unsigned short)0;
}

// w [O=64][I=64][27] fp32 -> At[o][k*64+i] bf16 (k-major)
__global__ __launch_bounds__(256) void perm_w_kernel(
    const float* __restrict__ w, unsigned short* __restrict__ At)
{
    int tid = blockIdx.x*256 + threadIdx.x;
    if (tid >= C_*KK_) return;
    int o  = tid / KK_;
    int r  = tid % KK_;
    int k  = r / 64, i = r % 64;
    At[tid] = f2b(w[((size_t)o*C_ + i)*K_ + k]);
}

// ---------------------------------------------------------------------------
// conv_off fused, software-pipelined (unchanged from R9): A dbuf in LDS,
// B values prefetched to regs; inter-barrier = 4 ds_writes.
// ---------------------------------------------------------------------------
__global__ __launch_bounds__(256) void conv_off_fused(
    const unsigned short* __restrict__ A,    // A1k [768][1728]
    const unsigned short* __restrict__ xt,   // [N][P][64] bf16
    const float* __restrict__ bias,          // [648]
    unsigned short* __restrict__ off)        // [N][648][P] bf16
{
    __shared__ __align__(16) short As[2][16*512];
    __shared__ __align__(16) short Bs[16*512];
    int tid = threadIdx.x;
    int w = tid >> 6, lane = tid & 63;
    int n   = blockIdx.x / 1176;
    int bid = blockIdx.x % 1176;
    int mt, nt;
    if (bid < 1152) { int c = bid/48, r = bid%48; mt = r >> 3; nt = c*8 + (r&7); }
    else            { int r = bid - 1152;         mt = r >> 2; nt = 192 + (r&3); }
    int m0 = mt*128, p0 = nt*128;
    int lm = lane & 15, lq = lane >> 4;

    const unsigned short* xtn = xt + (size_t)n*P_*C_;
    unsigned short* out = off + (size_t)n*CO_OFF_*P_;

    const char* Ab0 = (const char*)A + (size_t)(m0 + w*32 + lm)*KB_ + lq*16;
    const char* Ab1 = Ab0 + (size_t)16*KB_;

    int oct = lane & 7;
    int prj[4], dj[4], hj[4], wj[4];
    #pragma unroll
    for (int j = 0; j < 4; ++j) {
        int prow = j*32 + w*8 + (lane >> 3);
        prj[j] = prow;
        int p = p0 + prow;
        dj[j] = p / HW_;
        int hw2 = p % HW_;
        hj[j] = hw2 / W_;
        wj[j] = hw2 % W_;
    }

    auto stageA = [&](int kt, int buf) {
        __builtin_amdgcn_global_load_lds((const AS1 unsigned*)(Ab0 + kt*128),      (AS3 unsigned*)(&As[buf][(w*2)*512]),     16, 0, 0);
        __builtin_amdgcn_global_load_lds((const AS1 unsigned*)(Ab1 + kt*128),      (AS3 unsigned*)(&As[buf][(w*2+1)*512]),   16, 0, 0);
        __builtin_amdgcn_global_load_lds((const AS1 unsigned*)(Ab0 + kt*128 + 64), (AS3 unsigned*)(&As[buf][(8+w*2)*512]),   16, 0, 0);
        __builtin_amdgcn_global_load_lds((const AS1 unsigned*)(Ab1 + kt*128 + 64), (AS3 unsigned*)(&As[buf][(8+w*2+1)*512]), 16, 0, 0);
    };
    auto loadB = [&](int kt, uint4* B) {
        int kd = kt/9 - 1, kh = (kt/3)%3 - 1, kw = kt%3 - 1;
        int delta = kd*HW_ + kh*W_ + kw;
        #pragma unroll
        for (int j = 0; j < 4; ++j) {
            bool v = ((unsigned)(dj[j]+kd) < (unsigned)D_) &&
                     ((unsigned)(hj[j]+kh) < (unsigned)H_) &&
                     ((unsigned)(wj[j]+kw) < (unsigned)W_);
            uint4 val = {0u,0u,0u,0u};
            if (v) val = *(const uint4*)(xtn + (size_t)(p0 + prj[j] + delta)*C_ + oct*8);
            B[j] = val;
        }
    };

    int mh = w >> 1, nh = w & 1;
    floatx4 acc[4][4];
    #pragma unroll
    for (int i = 0; i < 4; ++i)
        #pragma unroll
        for (int j = 0; j < 4; ++j)
            acc[i][j] = (floatx4){0.f, 0.f, 0.f, 0.f};

    uint4 Bcur[4], Bnext[4];
    #pragma unroll
    for (int j = 0; j < 4; ++j) Bnext[j] = (uint4){0u,0u,0u,0u};
    stageA(0, 0);
    loadB(0, Bcur);

    for (int kt = 0; kt < 27; ++kt) {
        int buf = kt & 1;
        __syncthreads();
        #pragma unroll
        for (int j = 0; j < 4; ++j) {
            int chunk = (oct>>2)*8 + (prj[j]>>4);
            *(uint4*)&Bs[chunk*512 + ((oct&3)*16 + ((prj[j]&15) ^ oct))*8] = Bcur[j];
        }
        __syncthreads();
        if (kt < 26) { stageA(kt+1, buf^1); loadB(kt+1, Bnext); }
        #pragma unroll
        for (int ks = 0; ks < 2; ++ks) {
            int swzB = (lq*16 + (lm ^ (ks*4 + lq)))*8;
            shortx8 a[4], b[4];
            #pragma unroll
            for (int i = 0; i < 4; ++i) a[i] = *(const shortx8*)&As[buf][(ks*8 + 4*mh + i)*512 + lane*8];
            #pragma unroll
            for (int j = 0; j < 4; ++j) b[j] = *(const shortx8*)&Bs[(ks*8 + 4*nh + j)*512 + swzB];
            #pragma unroll
            for (int i = 0; i < 4; ++i)
                #pragma unroll
                for (int j = 0; j < 4; ++j)
                    acc[i][j] = __builtin_amdgcn_mfma_f32_16x16x32_bf16(a[i], b[j], acc[i][j], 0, 0, 0);
        }
        #pragma unroll
        for (int j = 0; j < 4; ++j) Bcur[j] = Bnext[j];
    }

    #pragma unroll
    for (int i = 0; i < 4; ++i) {
        int cob = m0 + (4*mh+i)*16 + lq*4;
        #pragma unroll
        for (int r = 0; r < 4; ++r) {
            int co = cob + r;
            if (co < CO_OFF_) {
                float bv = bias[co];
                #pragma unroll
                for (int j = 0; j < 4; ++j) {
                    int col = p0 + (4*nh+j)*16 + lm;
                    out[(size_t)co*P_ + col] = f2b(acc[i][j][r] + bv);
                }
            }
        }
    }
}

// ---------------------------------------------------------------------------
// deform fused, 2-deep pipeline: offs loaded 2 kt ahead, corner loads issued
// 1 kt ahead; FMA-reduce+pack after MFMA issue. Inter-barrier = 2 ds_writes.
// ---------------------------------------------------------------------------
__global__ __launch_bounds__(256) void deform_fused(
    const unsigned short* __restrict__ xt,   // [N][P][64] bf16
    const unsigned short* __restrict__ off,  // [N][648][P] bf16
    const unsigned short* __restrict__ A,    // A1t [64][1728]
    unsigned short* __restrict__ y1t)        // [N][P][64] bf16
{
    __shared__ __align__(16) short SH[12288]; // As dbuf 2x4096, Bs 4096
    short* Bsb = SH + 8192;
    int tid = threadIdx.x;
    int w = tid >> 6, lane = tid & 63;
    int n  = blockIdx.x / (P_/64);
    int p0 = (blockIdx.x % (P_/64))*64;
    int lm = lane & 15, lq = lane >> 4;

    const unsigned short* offn = off + (size_t)n*CO_OFF_*P_;
    const uint4* xg0 = (const uint4*)(xt + (size_t)n*P_*C_);

    const char* Ab = (const char*)A + (size_t)(w*16 + lm)*KB_ + lq*16;

    // task invariants: g = lane&7, 2 p-rows per thread
    int g = lane & 7;
    int prI[2], dI[2], hI[2], wI[2];
    #pragma unroll
    for (int it = 0; it < 2; ++it) {
        int prow = it*32 + w*8 + (lane >> 3);
        prI[it] = prow;
        int p = p0 + prow;
        dI[it] = p / HW_;
        int hw2 = p % HW_;
        hI[it] = hw2 / W_;
        wI[it] = hw2 % W_;
    }

    auto stageA = [&](int kt, int buf) {
        __builtin_amdgcn_global_load_lds((const AS1 unsigned*)(Ab + kt*128),      (AS3 unsigned*)(SH + buf*4096 + w*512),     16, 0, 0);
        __builtin_amdgcn_global_load_lds((const AS1 unsigned*)(Ab + kt*128 + 64), (AS3 unsigned*)(SH + buf*4096 + (4+w)*512), 16, 0, 0);
    };
    auto loadOff = [&](int kt, float o[2][3]) {
        #pragma unroll
        for (int it = 0; it < 2; ++it) {
            size_t ob = ((size_t)(g*K_ + kt)*3)*P_ + p0 + prI[it];
            o[it][0] = b2f(offn[ob]);
            o[it][1] = b2f(offn[ob + P_]);
            o[it][2] = b2f(offn[ob + 2*(size_t)P_]);
        }
    };
    // issue 16 corner loads + compute weights (uses only off values + invariants)
    auto issueCorners = [&](int kt, float o[2][3], uint4 V[2][8], float Wt[2][8]) {
        int kd = kt/9 - 1, kh = (kt/3)%3 - 1, kw = kt%3 - 1;
        #pragma unroll
        for (int it = 0; it < 2; ++it) {
            float pd = (float)(dI[it] + kd) + o[it][0];
            float ph = (float)(hI[it] + kh) + o[it][1];
            float pw = (float)(wI[it] + kw) + o[it][2];
            float fd0 = floorf(pd), fh0 = floorf(ph), fw0 = floorf(pw);
            int d0 = (int)fd0, h0 = (int)fh0, w0i = (int)fw0;
            float fd = pd - fd0, fh = ph - fh0, fw = pw - fw0;
            int idx = 0;
            #pragma unroll
            for (int cd = 0; cd < 2; ++cd) {
                int id = d0 + cd;
                float wdt = cd ? fd : 1.f - fd;
                bool vdd = (unsigned)id < (unsigned)D_;
                int idc = min(max(id, 0), D_-1);
                #pragma unroll
                for (int ch = 0; ch < 2; ++ch) {
                    int ih = h0 + ch;
                    float wht = ch ? fh : 1.f - fh;
                    bool vhh = (unsigned)ih < (unsigned)H_;
                    int ihc = min(max(ih, 0), H_-1);
                    #pragma unroll
                    for (int cw = 0; cw < 2; ++cw) {
                        int iw = w0i + cw;
                        float wwt = cw ? fw : 1.f - fw;
                        bool vww = (unsigned)iw < (unsigned)W_;
                        int iwc = min(max(iw, 0), W_-1);
                        int lin = (idc*H_ + ihc)*W_ + iwc;
                        V[it][idx]  = xg0[(size_t)lin*(C_/8) + g];
                        Wt[it][idx] = (vdd && vhh && vww) ? wdt*wht*wwt : 0.f;
                        ++idx;
                    }
                }
            }
        }
    };
    auto reduceCorners = [&](uint4 V[2][8], float Wt[2][8], uint4 o4[2]) {
        #pragma unroll
        for (int it = 0; it < 2; ++it) {
            float res[CPG_];
            #pragma unroll
            for (int c = 0; c < CPG_; ++c) res[c] = 0.f;
            #pragma unroll
            for (int c = 0; c < 8; ++c) {
                uint4 v4 = V[it][c];
                float wgt = Wt[it][c];
                res[0] = fmaf(wgt, lof(v4.x), res[0]);
                res[1] = fmaf(wgt, hif(v4.x), res[1]);
                res[2] = fmaf(wgt, lof(v4.y), res[2]);
                res[3] = fmaf(wgt, hif(v4.y), res[3]);
                res[4] = fmaf(wgt, lof(v4.z), res[4]);
                res[5] = fmaf(wgt, hif(v4.z), res[5]);
                res[6] = fmaf(wgt, lof(v4.w), res[6]);
                res[7] = fmaf(wgt, hif(v4.w), res[7]);
            }
            o4[it].x = (unsigned)f2b(res[0]) | ((unsigned)f2b(res[1]) << 16);
            o4[it].y = (unsigned)f2b(res[2]) | ((unsigned)f2b(res[3]) << 16);
            o4[it].z = (unsigned)f2b(res[4]) | ((unsigned)f2b(res[5]) << 16);
            o4[it].w = (unsigned)f2b(res[6]) | ((unsigned)f2b(res[7]) << 16);
        }
    };

    int mh = w >> 1, nh = w & 1;
    floatx4 acc[2][2];
    #pragma unroll
    for (int i = 0; i < 2; ++i)
        #pragma unroll
        for (int j = 0; j < 2; ++j)
            acc[i][j] = (floatx4){0.f, 0.f, 0.f, 0.f};

    float offA[2][3], offB[2][3], offT[2][3];
    uint4 Vv[2][8]; float Wt[2][8];
    uint4 o4cur[2];

    stageA(0, 0);
    loadOff(0, offA);
    loadOff(1, offB);
    issueCorners(0, offA, Vv, Wt);
    reduceCorners(Vv, Wt, o4cur);

    for (int kt = 0; kt < 27; ++kt) {
        int buf = kt & 1;
        __syncthreads();
        #pragma unroll
        for (int it = 0; it < 2; ++it) {
            int prow = prI[it];
            int chunk = (g>>2)*4 + (prow>>4);
            *(uint4*)&Bsb[chunk*512 + ((g&3)*16 + ((prow&15) ^ g))*8] = o4cur[it];
        }
        __syncthreads();
        if (kt < 26) {
            stageA(kt+1, buf^1);
            if (kt < 25) loadOff(kt+2, offT);
            issueCorners(kt+1, offB, Vv, Wt);
        }
        #pragma unroll
        for (int ks = 0; ks < 2; ++ks) {
            int swzB = (lq*16 + (lm ^ (ks*4 + lq)))*8;
            shortx8 a[2], b[2];
            #pragma unroll
            for (int i = 0; i < 2; ++i) a[i] = *(const shortx8*)&SH[buf*4096 + (ks*4 + 2*mh+i)*512 + lane*8];
            #pragma unroll
            for (int j = 0; j < 2; ++j) b[j] = *(const shortx8*)&Bsb[(ks*4 + 2*nh+j)*512 + swzB];
            #pragma unroll
            for (int i = 0; i < 2; ++i)
                #pragma unroll
                for (int j = 0; j < 2; ++j)
                    acc[i][j] = __builtin_amdgcn_mfma_f32_16x16x32_bf16(a[i], b[j], acc[i][j], 0, 0, 0);
        }
        if (kt < 26) {
            reduceCorners(Vv, Wt, o4cur);
            #pragma unroll
            for (int it = 0; it < 2; ++it) {
                offB[it][0] = offT[it][0];
                offB[it][1] = offT[it][1];
                offB[it][2] = offT[it][2];
            }
        }
    }

    // epilogue: transpose 64o x 64p tile to y1t[p][o] via LDS (stride 72)
    __syncthreads();
    #pragma unroll
    for (int i = 0; i < 2; ++i) {
        int ob = mh*32 + i*16 + lq*4;
        #pragma unroll
        for (int j = 0; j < 2; ++j) {
            int pc = nh*32 + j*16 + lm;
            #pragma unroll
            for (int rr = 0; rr < 4; ++rr)
                SH[pc*72 + ob + rr] = (short)f2b(acc[i][j][rr]);
        }
    }
    __syncthreads();
    {
        int row = tid >> 2, seg = tid & 3;
        uint4 v0 = *(const uint4*)&SH[row*72 + seg*16];
        uint4 v1 = *(const uint4*)&SH[row*72 + seg*16 + 8];
        uint4* dst = (uint4*)(y1t + ((size_t)n*P_ + p0 + row)*C_ + seg*16);
        dst[0] = v0;
        dst[1] = v1;
    }
}

// ---------------------------------------------------------------------------
// conv2 fused, pipelined: A dbuf; raw y1t loads issued 1 kt ahead, BN+ReLU+
// pack reduced after MFMA. Inter-barrier = 2 ds_writes.
// ---------------------------------------------------------------------------
__global__ __launch_bounds__(256) void conv2_fused(
    const unsigned short* __restrict__ y1t,  // [N][P][64] bf16
    const float* __restrict__ st1,           // [64] scale, [64] shift
    const unsigned short* __restrict__ A,    // A2t [64][1728]
    const float* __restrict__ bias,          // [64]
    unsigned short* __restrict__ y2)         // [N][64][P] bf16
{
    __shared__ __align__(16) short SH[12288]; // As dbuf 2x4096, Bs 4096
    short* Bsb = SH + 8192;
    __shared__ float sc[64], sf[64];
    int tid = threadIdx.x;
    if (tid < 64) sc[tid] = st1[tid];
    else if (tid < 128) sf[tid-64] = st1[tid];
    int w = tid >> 6, lane = tid & 63;
    int n  = blockIdx.x / (P_/64);
    int p0 = (blockIdx.x % (P_/64))*64;
    int lm = lane & 15, lq = lane >> 4;

    const unsigned short* y1n = y1t + (size_t)n*P_*C_;
    unsigned short* y2n = y2 + (size_t)n*C_*P_;

    const char* Ab = (const char*)A + (size_t)(w*16 + lm)*KB_ + lq*16;

    int oct = lane & 7;
    int cb = oct*8;
    int prJ[2], dJ[2], hJ[2], wJ[2];
    #pragma unroll
    for (int j = 0; j < 2; ++j) {
        int prow = j*32 + w*8 + (lane >> 3);
        prJ[j] = prow;
        int p = p0 + prow;
        dJ[j] = p / HW_;
        int hw2 = p % HW_;
        hJ[j] = hw2 / W_;
        wJ[j] = hw2 % W_;
    }

    auto stageA = [&](int kt, int buf) {
        __builtin_amdgcn_global_load_lds((const AS1 unsigned*)(Ab + kt*128),      (AS3 unsigned*)(SH + buf*4096 + w*512),     16, 0, 0);
        __builtin_amdgcn_global_load_lds((const AS1 unsigned*)(Ab + kt*128 + 64), (AS3 unsigned*)(SH + buf*4096 + (4+w)*512), 16, 0, 0);
    };
    auto issueV = [&](int kt, uint4* V, int* M) {
        int kd = kt/9 - 1, kh = (kt/3)%3 - 1, kw = kt%3 - 1;
        int delta = kd*HW_ + kh*W_ + kw;
        #pragma unroll
        for (int j = 0; j < 2; ++j) {
            bool v = ((unsigned)(dJ[j]+kd) < (unsigned)D_) &&
                     ((unsigned)(hJ[j]+kh) < (unsigned)H_) &&
                     ((unsigned)(wJ[j]+kw) < (unsigned)W_);
            uint4 val = {0u,0u,0u,0u};
            if (v) val = *(const uint4*)(y1n + (size_t)(p0 + prJ[j] + delta)*C_ + oct*8);
            V[j] = val;
            M[j] = v ? 1 : 0;
        }
    };
    auto reduceV = [&](uint4* V, int* M, uint4* O4) {
        #pragma unroll
        for (int j = 0; j < 2; ++j) {
            uint4 o4 = {0u,0u,0u,0u};
            if (M[j]) {
                uint4 val = V[j];
                float r0 = fmaxf(lof(val.x)*sc[cb+0] + sf[cb+0], 0.f);
                float r1 = fmaxf(hif(val.x)*sc[cb+1] + sf[cb+1], 0.f);
                float r2 = fmaxf(lof(val.y)*sc[cb+2] + sf[cb+2], 0.f);
                float r3 = fmaxf(hif(val.y)*sc[cb+3] + sf[cb+3], 0.f);
                float r4 = fmaxf(lof(val.z)*sc[cb+4] + sf[cb+4], 0.f);
                float r5 = fmaxf(hif(val.z)*sc[cb+5] + sf[cb+5], 0.f);
                float r6 = fmaxf(lof(val.w)*sc[cb+6] + sf[cb+6], 0.f);
                float r7 = fmaxf(hif(val.w)*sc[cb+7] + sf[cb+7], 0.f);
                o4.x = (unsigned)f2b(r0) | ((unsigned)f2b(r1) << 16);
                o4.y = (unsigned)f2b(r2) | ((unsigned)f2b(r3) << 16);
                o4.z = (unsigned)f2b(r4) | ((unsigned)f2b(r5) << 16);
                o4.w = (unsigned)f2b(r6) | ((unsigned)f2b(r7) << 16);
            }
            O4[j] = o4;
        }
    };

    int mh = w >> 1, nh = w & 1;
    floatx4 acc[2][2];
    #pragma unroll
    for (int i = 0; i < 2; ++i)
        #pragma unroll
        for (int j = 0; j < 2; ++j)
            acc[i][j] = (floatx4){0.f, 0.f, 0.f, 0.f};

    uint4 Vv[2], O4cur[2];
    int Mm[2];
    stageA(0, 0);
    __syncthreads();           // sc/sf visible before prologue reduceV
    issueV(0, Vv, Mm);
    reduceV(Vv, Mm, O4cur);

    for (int kt = 0; kt < 27; ++kt) {
        int buf = kt & 1;
        __syncthreads();
        #pragma unroll
        for (int j = 0; j < 2; ++j) {
            int chunk = (oct>>2)*4 + (prJ[j]>>4);
            *(uint4*)&Bsb[chunk*512 + ((oct&3)*16 + ((prJ[j]&15) ^ oct))*8] = O4cur[j];
        }
        __syncthreads();
        if (kt < 26) { stageA(kt+1, buf^1); issueV(kt+1, Vv, Mm); }
        #pragma unroll
        for (int ks = 0; ks < 2; ++ks) {
            int swzB = (lq*16 + (lm ^ (ks*4 + lq)))*8;
            shortx8 a[2], b[2];
            #pragma unroll
            for (int i = 0; i < 2; ++i) a[i] = *(const shortx8*)&SH[buf*4096 + (ks*4 + 2*mh+i)*512 + lane*8];
            #pragma unroll
            for (int j = 0; j < 2; ++j) b[j] = *(const shortx8*)&Bsb[(ks*4 + 2*nh+j)*512 + swzB];
            #pragma unroll
            for (int i = 0; i < 2; ++i)
                #pragma unroll
                for (int j = 0; j < 2; ++j)
                    acc[i][j] = __builtin_amdgcn_mfma_f32_16x16x32_bf16(a[i], b[j], acc[i][j], 0, 0, 0);
        }
        if (kt < 26) reduceV(Vv, Mm, O4cur);
    }

    #pragma unroll
    for (int i = 0; i < 2; ++i) {
        int cob = (2*mh+i)*16 + lq*4;
        #pragma unroll
        for (int r = 0; r < 4; ++r) {
            int co = cob + r;
            float bv = bias[co];
            #pragma unroll
            for (int j = 0; j < 2; ++j) {
                int col = p0 + (2*nh+j)*16 + lm;
                y2n[(size_t)co*P_ + col] = f2b(acc[i][j][r] + bv);
            }
        }
    }
}

// ---------------------------------------------------------------------------
// BN1 stats from y1t [N*P][64]: partial sums per 512-row block, then finalize
// ---------------------------------------------------------------------------
__global__ __launch_bounds__(256) void stats_partial_kernel(
    const unsigned short* __restrict__ y1t, float* __restrict__ part)
{
    int b = blockIdx.x, tid = threadIdx.x;
    int c = tid & 63, sub = tid >> 6;
    float s = 0.f, q = 0.f;
    for (int rr = 0; rr < 128; ++rr) {
        int row = b*512 + sub*128 + rr;
        float v = b2f(y1t[(size_t)row*C_ + c]);
        s += v;
        q = fmaf(v, v, q);
    }
    __shared__ float ss[256], qq[256];
    ss[tid] = s; qq[tid] = q;
    __syncthreads();
    if (tid < 64) {
        float S = ss[tid] + ss[64+tid] + ss[128+tid] + ss[192+tid];
        float Q = qq[tid] + qq[64+tid] + qq[128+tid] + qq[192+tid];
        part[b*128 + tid]      = S;
        part[b*128 + 64 + tid] = Q;
    }
}

__global__ void stats_final_kernel(
    const float* __restrict__ part,
    const float* __restrict__ gamma, const float* __restrict__ beta,
    float* __restrict__ st1)
{
    int c = threadIdx.x;  // 64 threads
    float S = 0.f, Q = 0.f;
    for (int b = 0; b < 98; ++b) {
        S += part[b*128 + c];
        Q += part[b*128 + 64 + c];
    }
    const float inv = 1.f / (float)(N_*P_);
    float m = S * inv;
    float var = Q * inv - m*m;
    float scale = rsqrtf(var + 1e-5f) * gamma[c];
    st1[c]      = scale;
    st1[64 + c] = beta[c] - m*scale;
}

// ---------------------------------------------------------------------------
__global__ __launch_bounds__(256) void bn_stats_kernel(
    const unsigned short* __restrict__ src, float* __restrict__ stats)
{
    int c   = blockIdx.x;
    int tid = threadIdx.x;
    float s = 0.f, q = 0.f;
    for (int n = 0; n < N_; ++n) {
        const unsigned short* p = src + ((size_t)n*C_ + c)*P_;
        for (int i = tid; i < P_; i += 256) {
            float v = b2f(p[i]);
            s += v;
            q = fmaf(v, v, q);
        }
    }
    #pragma unroll
    for (int o = 32; o; o >>= 1) {
        s += __shfl_down(s, o);
        q += __shfl_down(q, o);
    }
    __shared__ float sh[2][4];
    int wave = tid >> 6;
    if ((tid & 63) == 0) { sh[0][wave] = s; sh[1][wave] = q; }
    __syncthreads();
    if (tid == 0) {
        float S = sh[0][0] + sh[0][1] + sh[0][2] + sh[0][3];
        float Q = sh[1][0] + sh[1][1] + sh[1][2] + sh[1][3];
        const float inv = 1.f / (float)(N_*P_);
        float m  = S * inv;
        float var = Q * inv - m*m;
        stats[c]      = m;
        stats[C_ + c] = rsqrtf(var + 1e-5f);
    }
}

__global__ __launch_bounds__(256) void bn_add_relu_kernel(
    const unsigned short* __restrict__ y2, const float* __restrict__ x,
    const float* __restrict__ stats,
    const float* __restrict__ gamma, const float* __restrict__ beta,
    float* __restrict__ out)
{
    size_t idx = (size_t)blockIdx.x*256 + threadIdx.x;
    int c = (int)((idx / P_) % C_);
    float v = (b2f(y2[idx]) - stats[c]) * stats[C_ + c] * gamma[c] + beta[c] + x[idx];
    out[idx] = fmaxf(v, 0.f);
}

// ---------------------------------------------------------------------------
extern "C" void kernel_launch(void* const* d_in, const int* in_sizes, int n_in,
                              void* d_out, int out_size, void* d_ws, size_t ws_size,
                              hipStream_t stream) {
    const float* x     = (const float*)d_in[0];
    const float* w_off = (const float*)d_in[1];
    const float* b_off = (const float*)d_in[2];
    const float* w1    = (const float*)d_in[3];
    const float* g1    = (const float*)d_in[4];
    const float* be1   = (const float*)d_in[5];
    const float* w2    = (const float*)d_in[6];
    const float* b2    = (const float*)d_in[7];
    const float* g2    = (const float*)d_in[8];
    const float* be2   = (const float*)d_in[9];
    float* out = (float*)d_out;

    // workspace (~88 MB)
    float* st1  = (float*)d_ws;                              // 128 (scale/shift)
    float* st2  = st1 + 128;                                 // 128 (mean/rstd)
    float* part = st2 + 128;                                 // 98*128
    unsigned short* off = (unsigned short*)(part + 98*128);  // N*648*P bf16 (65 MB)
    unsigned short* xt  = off + (size_t)N_*CO_OFF_*P_;       // N*P*64 bf16 (6.4 MB)
    unsigned short* y1t = xt  + (size_t)N_*P_*C_;            // N*P*64 bf16 (6.4 MB)
    unsigned short* y2  = y1t + (size_t)N_*P_*C_;            // N*64*P bf16 (6.4 MB)
    unsigned short* A1k = y2  + (size_t)N_*C_*P_;            // 768*1728 bf16 (2.65 MB)
    unsigned short* A1t = A1k + (size_t)MP_*KK_;             // 64*1728 bf16
    unsigned short* A2t = A1t + (size_t)C_*KK_;              // 64*1728 bf16

    // prep
    transpose_xt_kernel<<<N_*(P_/64), 256, 0, stream>>>(x, xt);
    permA1k_kernel<<<(MP_*KK_+255)/256, 256, 0, stream>>>(w_off, A1k);
    perm_w_kernel<<<(C_*KK_+255)/256, 256, 0, stream>>>(w1, A1t);
    perm_w_kernel<<<(C_*KK_+255)/256, 256, 0, stream>>>(w2, A2t);

    // conv_off fused -> off (both n)
    conv_off_fused<<<2*1176, 256, 0, stream>>>(A1k, xt, b_off, off);

    // deform fused -> y1t (both n)
    deform_fused<<<N_*(P_/64), 256, 0, stream>>>(xt, off, A1t, y1t);

    // BN1 scale/shift
    stats_partial_kernel<<<98, 256, 0, stream>>>(y1t, part);
    stats_final_kernel<<<1, 64, 0, stream>>>(part, g1, be1, st1);

    // conv2 fused (BN1+ReLU on read) -> y2 (both n)
    conv2_fused<<<N_*(P_/64), 256, 0, stream>>>(y1t, st1, A2t, b2, y2);

    // BN2 + residual + ReLU -> out (fp32)
    bn_stats_kernel<<<C_, 256, 0, stream>>>(y2, st2);
    bn_add_relu_kernel<<<(N_*C_*P_)/256, 256, 0, stream>>>(y2, x, st2, g2, be2, out);
}

// Round 11
// 563.622 us; speedup vs baseline: 2.1813x; 1.0136x over previous
//
#include <hip/hip_runtime.h>
#include <hip/hip_bf16.h>

#define N_ 2
#define C_ 64
#define D_ 8
#define H_ 56
#define W_ 56
#define HW_ (H_*W_)        // 3136
#define P_ (D_*HW_)        // 25088
#define G_ 8
#define CPG_ 8
#define K_ 27
#define CO_OFF_ 648        // G * 3 * K
#define MP_ 768            // conv_off M padded (rows 648+ zero)
#define KK_ 1728           // GEMM K dim (= 27*64, k-major: ktap*64 + ci)
#define KB_ (KK_*2)        // bytes per bf16 row

typedef __attribute__((ext_vector_type(8))) short shortx8;
typedef __attribute__((ext_vector_type(4))) float floatx4;
#define AS1 __attribute__((address_space(1)))
#define AS3 __attribute__((address_space(3)))

__device__ inline float b2f(unsigned short u) {
    union { unsigned u; float f; } x; x.u = ((unsigned)u) << 16; return x.f;
}
__device__ inline unsigned short f2b(float f) {
    union { float f; unsigned u; } x; x.f = f;
    unsigned r = (x.u + 0x7fffu + ((x.u >> 16) & 1u)) >> 16;   // RNE
    return (unsigned short)r;
}
__device__ inline float lof(unsigned u) { union { unsigned u; float f; } x; x.u = u << 16; return x.f; }
__device__ inline float hif(unsigned u) { union { unsigned u; float f; } x; x.u = u & 0xffff0000u; return x.f; }

// ---------------------------------------------------------------------------
// x [N][64][P] fp32 -> xt [N][P][64] bf16  (64p x 64c LDS tile transpose)
// ---------------------------------------------------------------------------
__global__ __launch_bounds__(256) void transpose_xt_kernel(
    const float* __restrict__ x, unsigned short* __restrict__ xt)
{
    __shared__ unsigned short tile[64][65];
    int b  = blockIdx.x;
    int n  = b / (P_/64);
    int p0 = (b % (P_/64))*64;
    int tid = threadIdx.x;
    int j  = tid & 63;
    int c0 = (tid >> 6)*16;
    for (int r = 0; r < 16; ++r)
        tile[c0 + r][j] = f2b(x[((size_t)n*C_ + c0 + r)*P_ + p0 + j]);
    __syncthreads();
    unsigned* dst = (unsigned*)(xt + ((size_t)n*P_ + p0)*C_);
    #pragma unroll
    for (int it = 0; it < 8; ++it) {
        int wi  = it*256 + tid;
        int row = wi >> 5;
        int c   = (wi & 31)*2;
        unsigned lo = tile[c][row], hi = tile[c+1][row];
        dst[(size_t)row*32 + (wi & 31)] = lo | (hi << 16);
    }
}

// w_off [648][64][27] fp32 -> A1k [768][kk*64+ci] bf16 (k-major, zero-pad rows)
__global__ __launch_bounds__(256) void permA1k_kernel(
    const float* __restrict__ w, unsigned short* __restrict__ A)
{
    int i = blockIdx.x*256 + threadIdx.x;
    if (i >= MP_*KK_) return;
    int m = i / KK_, r = i % KK_;
    int kk = r / 64, ci = r % 64;
    A[i] = (m < CO_OFF_) ? f2b(w[((size_t)m*C_ + ci)*K_ + kk]) : (unsigned short)0;
}

// w [O=64][I=64][27] fp32 -> At[o][k*64+i] bf16 (k-major)
__global__ __launch_bounds__(256) void perm_w_kernel(
    const float* __restrict__ w, unsigned short* __restrict__ At)
{
    int tid = blockIdx.x*256 + threadIdx.x;
    if (tid >= C_*KK_) return;
    int o  = tid / KK_;
    int r  = tid % KK_;
    int k  = r / 64, i = r % 64;
    At[tid] = f2b(w[((size_t)o*C_ + i)*K_ + k]);
}

// ---------------------------------------------------------------------------
// conv_off fused main: m-tiles 0..4 only (rows 0..639, all valid). Pipelined.
// ---------------------------------------------------------------------------
__global__ __launch_bounds__(256) void conv_off_fused(
    const unsigned short* __restrict__ A,    // A1k [768][1728]
    const unsigned short* __restrict__ xt,   // [N][P][64] bf16
    const float* __restrict__ bias,          // [648]
    unsigned short* __restrict__ off)        // [N][648][P] bf16
{
    __shared__ __align__(16) short As[2][16*512];
    __shared__ __align__(16) short Bs[16*512];
    int tid = threadIdx.x;
    int w = tid >> 6, lane = tid & 63;
    int n   = blockIdx.x / 980;
    int bid = blockIdx.x % 980;
    int mt, nt;
    if (bid < 960) { int c = bid/40, r = bid%40; mt = r >> 3; nt = c*8 + (r&7); }
    else           { int r = bid - 960;          mt = r >> 2; nt = 192 + (r&3); }
    int m0 = mt*128, p0 = nt*128;
    int lm = lane & 15, lq = lane >> 4;

    const unsigned short* xtn = xt + (size_t)n*P_*C_;
    unsigned short* out = off + (size_t)n*CO_OFF_*P_;

    const char* Ab0 = (const char*)A + (size_t)(m0 + w*32 + lm)*KB_ + lq*16;
    const char* Ab1 = Ab0 + (size_t)16*KB_;

    int oct = lane & 7;
    int prj[4], dj[4], hj[4], wj[4];
    #pragma unroll
    for (int j = 0; j < 4; ++j) {
        int prow = j*32 + w*8 + (lane >> 3);
        prj[j] = prow;
        int p = p0 + prow;
        dj[j] = p / HW_;
        int hw2 = p % HW_;
        hj[j] = hw2 / W_;
        wj[j] = hw2 % W_;
    }

    auto stageA = [&](int kt, int buf) {
        __builtin_amdgcn_global_load_lds((const AS1 unsigned*)(Ab0 + kt*128),      (AS3 unsigned*)(&As[buf][(w*2)*512]),     16, 0, 0);
        __builtin_amdgcn_global_load_lds((const AS1 unsigned*)(Ab1 + kt*128),      (AS3 unsigned*)(&As[buf][(w*2+1)*512]),   16, 0, 0);
        __builtin_amdgcn_global_load_lds((const AS1 unsigned*)(Ab0 + kt*128 + 64), (AS3 unsigned*)(&As[buf][(8+w*2)*512]),   16, 0, 0);
        __builtin_amdgcn_global_load_lds((const AS1 unsigned*)(Ab1 + kt*128 + 64), (AS3 unsigned*)(&As[buf][(8+w*2+1)*512]), 16, 0, 0);
    };
    auto loadB = [&](int kt, uint4* B) {
        int kd = kt/9 - 1, kh = (kt/3)%3 - 1, kw = kt%3 - 1;
        int delta = kd*HW_ + kh*W_ + kw;
        #pragma unroll
        for (int j = 0; j < 4; ++j) {
            bool v = ((unsigned)(dj[j]+kd) < (unsigned)D_) &&
                     ((unsigned)(hj[j]+kh) < (unsigned)H_) &&
                     ((unsigned)(wj[j]+kw) < (unsigned)W_);
            uint4 val = {0u,0u,0u,0u};
            if (v) val = *(const uint4*)(xtn + (size_t)(p0 + prj[j] + delta)*C_ + oct*8);
            B[j] = val;
        }
    };

    int mh = w >> 1, nh = w & 1;
    floatx4 acc[4][4];
    #pragma unroll
    for (int i = 0; i < 4; ++i)
        #pragma unroll
        for (int j = 0; j < 4; ++j)
            acc[i][j] = (floatx4){0.f, 0.f, 0.f, 0.f};

    uint4 Bcur[4], Bnext[4];
    #pragma unroll
    for (int j = 0; j < 4; ++j) Bnext[j] = (uint4){0u,0u,0u,0u};
    stageA(0, 0);
    loadB(0, Bcur);

    for (int kt = 0; kt < 27; ++kt) {
        int buf = kt & 1;
        __syncthreads();
        #pragma unroll
        for (int j = 0; j < 4; ++j) {
            int chunk = (oct>>2)*8 + (prj[j]>>4);
            *(uint4*)&Bs[chunk*512 + ((oct&3)*16 + ((prj[j]&15) ^ oct))*8] = Bcur[j];
        }
        __syncthreads();
        if (kt < 26) { stageA(kt+1, buf^1); loadB(kt+1, Bnext); }
        #pragma unroll
        for (int ks = 0; ks < 2; ++ks) {
            int swzB = (lq*16 + (lm ^ (ks*4 + lq)))*8;
            shortx8 a[4], b[4];
            #pragma unroll
            for (int i = 0; i < 4; ++i) a[i] = *(const shortx8*)&As[buf][(ks*8 + 4*mh + i)*512 + lane*8];
            #pragma unroll
            for (int j = 0; j < 4; ++j) b[j] = *(const shortx8*)&Bs[(ks*8 + 4*nh + j)*512 + swzB];
            #pragma unroll
            for (int i = 0; i < 4; ++i)
                #pragma unroll
                for (int j = 0; j < 4; ++j)
                    acc[i][j] = __builtin_amdgcn_mfma_f32_16x16x32_bf16(a[i], b[j], acc[i][j], 0, 0, 0);
        }
        #pragma unroll
        for (int j = 0; j < 4; ++j) Bcur[j] = Bnext[j];
    }

    #pragma unroll
    for (int i = 0; i < 4; ++i) {
        int cob = m0 + (4*mh+i)*16 + lq*4;
        #pragma unroll
        for (int r = 0; r < 4; ++r) {
            int co = cob + r;    // < 640 always (mt <= 4)
            float bv = bias[co];
            #pragma unroll
            for (int j = 0; j < 4; ++j) {
                int col = p0 + (4*nh+j)*16 + lm;
                out[(size_t)co*P_ + col] = f2b(acc[i][j][r] + bv);
            }
        }
    }
}

// ---------------------------------------------------------------------------
// conv_off tail: rows 640..655 (648..655 are zero-padded in A1k). 16x128 tile.
// All 27 kt of A staged to LDS once up-front; B register-pipelined.
// ---------------------------------------------------------------------------
__global__ __launch_bounds__(256) void conv_off_tail(
    const unsigned short* __restrict__ A,    // A1k [768][1728]
    const unsigned short* __restrict__ xt,   // [N][P][64] bf16
    const float* __restrict__ bias,          // [648]
    unsigned short* __restrict__ off)        // [N][648][P] bf16
{
    __shared__ __align__(16) short As[54*512];   // 54 chunks (27 kt x 2 ks)
    __shared__ __align__(16) short Bs[16*512];
    int tid = threadIdx.x;
    int w = tid >> 6, lane = tid & 63;
    int n  = blockIdx.x / 196;
    int p0 = (blockIdx.x % 196)*128;
    int lm = lane & 15, lq = lane >> 4;

    const unsigned short* xtn = xt + (size_t)n*P_*C_;
    unsigned short* out = off + (size_t)n*CO_OFF_*P_;

    // stage entire 16-row A strip (rows 640+lm)
    const char* Abase = (const char*)A + (size_t)(640 + lm)*KB_ + lq*16;
    for (int ch = w; ch < 54; ch += 4)
        __builtin_amdgcn_global_load_lds((const AS1 unsigned*)(Abase + ch*64),
                                         (AS3 unsigned*)(As + ch*512), 16, 0, 0);

    int oct = lane & 7;
    int prj[4], dj[4], hj[4], wj[4];
    #pragma unroll
    for (int j = 0; j < 4; ++j) {
        int prow = j*32 + w*8 + (lane >> 3);
        prj[j] = prow;
        int p = p0 + prow;
        dj[j] = p / HW_;
        int hw2 = p % HW_;
        hj[j] = hw2 / W_;
        wj[j] = hw2 % W_;
    }
    auto loadB = [&](int kt, uint4* B) {
        int kd = kt/9 - 1, kh = (kt/3)%3 - 1, kw = kt%3 - 1;
        int delta = kd*HW_ + kh*W_ + kw;
        #pragma unroll
        for (int j = 0; j < 4; ++j) {
            bool v = ((unsigned)(dj[j]+kd) < (unsigned)D_) &&
                     ((unsigned)(hj[j]+kh) < (unsigned)H_) &&
                     ((unsigned)(wj[j]+kw) < (unsigned)W_);
            uint4 val = {0u,0u,0u,0u};
            if (v) val = *(const uint4*)(xtn + (size_t)(p0 + prj[j] + delta)*C_ + oct*8);
            B[j] = val;
        }
    };

    floatx4 acc[2];
    acc[0] = (floatx4){0.f,0.f,0.f,0.f};
    acc[1] = (floatx4){0.f,0.f,0.f,0.f};

    uint4 Bcur[4], Bnext[4];
    #pragma unroll
    for (int j = 0; j < 4; ++j) Bnext[j] = (uint4){0u,0u,0u,0u};
    loadB(0, Bcur);

    for (int kt = 0; kt < 27; ++kt) {
        __syncthreads();
        #pragma unroll
        for (int j = 0; j < 4; ++j) {
            int chunk = (oct>>2)*8 + (prj[j]>>4);
            *(uint4*)&Bs[chunk*512 + ((oct&3)*16 + ((prj[j]&15) ^ oct))*8] = Bcur[j];
        }
        __syncthreads();
        if (kt < 26) loadB(kt+1, Bnext);
        #pragma unroll
        for (int ks = 0; ks < 2; ++ks) {
            int swzB = (lq*16 + (lm ^ (ks*4 + lq)))*8;
            shortx8 a = *(const shortx8*)&As[(kt*2 + ks)*512 + lane*8];
            #pragma unroll
            for (int j = 0; j < 2; ++j) {
                shortx8 b = *(const shortx8*)&Bs[(ks*8 + w*2 + j)*512 + swzB];
                acc[j] = __builtin_amdgcn_mfma_f32_16x16x32_bf16(a, b, acc[j], 0, 0, 0);
            }
        }
        #pragma unroll
        for (int j = 0; j < 4; ++j) Bcur[j] = Bnext[j];
    }

    #pragma unroll
    for (int j = 0; j < 2; ++j) {
        #pragma unroll
        for (int r = 0; r < 4; ++r) {
            int co = 640 + lq*4 + r;
            if (co < CO_OFF_) {
                int col = p0 + w*32 + j*16 + lm;
                out[(size_t)co*P_ + col] = f2b(acc[j][r] + bias[co]);
            }
        }
    }
}

// ---------------------------------------------------------------------------
// deform fused, N=32 tiles (2x blocks for latency hiding), 2-deep pipeline.
// One gather task per thread: g = lane&7, prow = tid>>3 (0..31).
// ---------------------------------------------------------------------------
__global__ __launch_bounds__(256) void deform_fused(
    const unsigned short* __restrict__ xt,   // [N][P][64] bf16
    const unsigned short* __restrict__ off,  // [N][648][P] bf16
    const unsigned short* __restrict__ A,    // A1t [64][1728]
    unsigned short* __restrict__ y1t)        // [N][P][64] bf16
{
    __shared__ __align__(16) short SH[10240]; // As dbuf 2x4096, Bs 2048
    short* Bsb = SH + 8192;
    int tid = threadIdx.x;
    int w = tid >> 6, lane = tid & 63;
    int n  = blockIdx.x / (P_/32);
    int p0 = (blockIdx.x % (P_/32))*32;
    int lm = lane & 15, lq = lane >> 4;

    const unsigned short* offn = off + (size_t)n*CO_OFF_*P_;
    const uint4* xg0 = (const uint4*)(xt + (size_t)n*P_*C_);

    const char* Ab = (const char*)A + (size_t)(w*16 + lm)*KB_ + lq*16;

    int g = lane & 7;
    int prow = tid >> 3;          // 0..31
    int p = p0 + prow;
    int dd = p / HW_;
    int hw2 = p % HW_;
    int hh = hw2 / W_;
    int ww = hw2 % W_;

    auto stageA = [&](int kt, int buf) {
        __builtin_amdgcn_global_load_lds((const AS1 unsigned*)(Ab + kt*128),      (AS3 unsigned*)(SH + buf*4096 + w*512),     16, 0, 0);
        __builtin_amdgcn_global_load_lds((const AS1 unsigned*)(Ab + kt*128 + 64), (AS3 unsigned*)(SH + buf*4096 + (4+w)*512), 16, 0, 0);
    };
    auto loadOff = [&](int kt, float* o) {
        size_t ob = ((size_t)(g*K_ + kt)*3)*P_ + p;
        o[0] = b2f(offn[ob]);
        o[1] = b2f(offn[ob + P_]);
        o[2] = b2f(offn[ob + 2*(size_t)P_]);
    };
    auto issueCorners = [&](int kt, float* o, uint4* V, float* Wt) {
        int kd = kt/9 - 1, kh = (kt/3)%3 - 1, kw = kt%3 - 1;
        float pd = (float)(dd + kd) + o[0];
        float ph = (float)(hh + kh) + o[1];
        float pw = (float)(ww + kw) + o[2];
        float fd0 = floorf(pd), fh0 = floorf(ph), fw0 = floorf(pw);
        int d0 = (int)fd0, h0 = (int)fh0, w0i = (int)fw0;
        float fd = pd - fd0, fh = ph - fh0, fw = pw - fw0;
        int idx = 0;
        #pragma unroll
        for (int cd = 0; cd < 2; ++cd) {
            int id = d0 + cd;
            float wdt = cd ? fd : 1.f - fd;
            bool vdd = (unsigned)id < (unsigned)D_;
            int idc = min(max(id, 0), D_-1);
            #pragma unroll
            for (int ch = 0; ch < 2; ++ch) {
                int ih = h0 + ch;
                float wht = ch ? fh : 1.f - fh;
                bool vhh = (unsigned)ih < (unsigned)H_;
                int ihc = min(max(ih, 0), H_-1);
                #pragma unroll
                for (int cw = 0; cw < 2; ++cw) {
                    int iw = w0i + cw;
                    float wwt = cw ? fw : 1.f - fw;
                    bool vww = (unsigned)iw < (unsigned)W_;
                    int iwc = min(max(iw, 0), W_-1);
                    int lin = (idc*H_ + ihc)*W_ + iwc;
                    V[idx]  = xg0[(size_t)lin*(C_/8) + g];
                    Wt[idx] = (vdd && vhh && vww) ? wdt*wht*wwt : 0.f;
                    ++idx;
                }
            }
        }
    };
    auto reduceCorners = [&](uint4* V, float* Wt, uint4& o4) {
        float res[CPG_];
        #pragma unroll
        for (int c = 0; c < CPG_; ++c) res[c] = 0.f;
        #pragma unroll
        for (int c = 0; c < 8; ++c) {
            uint4 v4 = V[c];
            float wgt = Wt[c];
            res[0] = fmaf(wgt, lof(v4.x), res[0]);
            res[1] = fmaf(wgt, hif(v4.x), res[1]);
            res[2] = fmaf(wgt, lof(v4.y), res[2]);
            res[3] = fmaf(wgt, hif(v4.y), res[3]);
            res[4] = fmaf(wgt, lof(v4.z), res[4]);
            res[5] = fmaf(wgt, hif(v4.z), res[5]);
            res[6] = fmaf(wgt, lof(v4.w), res[6]);
            res[7] = fmaf(wgt, hif(v4.w), res[7]);
        }
        o4.x = (unsigned)f2b(res[0]) | ((unsigned)f2b(res[1]) << 16);
        o4.y = (unsigned)f2b(res[2]) | ((unsigned)f2b(res[3]) << 16);
        o4.z = (unsigned)f2b(res[4]) | ((unsigned)f2b(res[5]) << 16);
        o4.w = (unsigned)f2b(res[6]) | ((unsigned)f2b(res[7]) << 16);
    };

    int mh = w >> 1, nh = w & 1;
    floatx4 acc[2];
    acc[0] = (floatx4){0.f,0.f,0.f,0.f};
    acc[1] = (floatx4){0.f,0.f,0.f,0.f};

    float offA[3], offB[3], offT[3];
    uint4 Vv[8]; float Wt[8];
    uint4 o4cur;

    stageA(0, 0);
    loadOff(0, offA);
    loadOff(1, offB);
    issueCorners(0, offA, Vv, Wt);
    reduceCorners(Vv, Wt, o4cur);

    for (int kt = 0; kt < 27; ++kt) {
        int buf = kt & 1;
        __syncthreads();
        {
            int chunk = (g>>2)*2 + (prow>>4);
            *(uint4*)&Bsb[chunk*512 + ((g&3)*16 + ((prow&15) ^ g))*8] = o4cur;
        }
        __syncthreads();
        if (kt < 26) {
            stageA(kt+1, buf^1);
            if (kt < 25) loadOff(kt+2, offT);
            issueCorners(kt+1, offB, Vv, Wt);
        }
        #pragma unroll
        for (int ks = 0; ks < 2; ++ks) {
            int swzB = (lq*16 + (lm ^ (ks*4 + lq)))*8;
            shortx8 b = *(const shortx8*)&Bsb[(ks*2 + nh)*512 + swzB];
            #pragma unroll
            for (int i = 0; i < 2; ++i) {
                shortx8 a = *(const shortx8*)&SH[buf*4096 + (ks*4 + 2*mh+i)*512 + lane*8];
                acc[i] = __builtin_amdgcn_mfma_f32_16x16x32_bf16(a, b, acc[i], 0, 0, 0);
            }
        }
        if (kt < 26) {
            reduceCorners(Vv, Wt, o4cur);
            offB[0] = offT[0]; offB[1] = offT[1]; offB[2] = offT[2];
        }
    }

    // epilogue: transpose 64o x 32p tile to y1t[p][o] via LDS (stride 72)
    __syncthreads();
    #pragma unroll
    for (int i = 0; i < 2; ++i) {
        int ob = mh*32 + i*16 + lq*4;
        int pc = nh*16 + lm;
        #pragma unroll
        for (int rr = 0; rr < 4; ++rr)
            SH[pc*72 + ob + rr] = (short)f2b(acc[i][rr]);
    }
    __syncthreads();
    {
        int row = tid >> 3, seg = tid & 7;   // 32 rows x 8 segs of 8 shorts
        uint4 v = *(const uint4*)&SH[row*72 + seg*8];
        *(uint4*)(y1t + ((size_t)n*P_ + p0 + row)*C_ + seg*8) = v;
    }
}

// ---------------------------------------------------------------------------
// conv2 fused, N=32 tiles, pipelined. One B task/thread.
// ---------------------------------------------------------------------------
__global__ __launch_bounds__(256) void conv2_fused(
    const unsigned short* __restrict__ y1t,  // [N][P][64] bf16
    const float* __restrict__ st1,           // [64] scale, [64] shift
    const unsigned short* __restrict__ A,    // A2t [64][1728]
    const float* __restrict__ bias,          // [64]
    unsigned short* __restrict__ y2)         // [N][64][P] bf16
{
    __shared__ __align__(16) short SH[10240]; // As dbuf 2x4096, Bs 2048
    short* Bsb = SH + 8192;
    __shared__ float sc[64], sf[64];
    int tid = threadIdx.x;
    if (tid < 64) sc[tid] = st1[tid];
    else if (tid < 128) sf[tid-64] = st1[tid];
    int w = tid >> 6, lane = tid & 63;
    int n  = blockIdx.x / (P_/32);
    int p0 = (blockIdx.x % (P_/32))*32;
    int lm = lane & 15, lq = lane >> 4;

    const unsigned short* y1n = y1t + (size_t)n*P_*C_;
    unsigned short* y2n = y2 + (size_t)n*C_*P_;

    const char* Ab = (const char*)A + (size_t)(w*16 + lm)*KB_ + lq*16;

    int oct = lane & 7;
    int cb = oct*8;
    int prow = tid >> 3;          // 0..31
    int p = p0 + prow;
    int dd = p / HW_;
    int hw2 = p % HW_;
    int hh = hw2 / W_;
    int ww = hw2 % W_;

    auto stageA = [&](int kt, int buf) {
        __builtin_amdgcn_global_load_lds((const AS1 unsigned*)(Ab + kt*128),      (AS3 unsigned*)(SH + buf*4096 + w*512),     16, 0, 0);
        __builtin_amdgcn_global_load_lds((const AS1 unsigned*)(Ab + kt*128 + 64), (AS3 unsigned*)(SH + buf*4096 + (4+w)*512), 16, 0, 0);
    };
    auto issueV = [&](int kt, uint4& V, int& M) {
        int kd = kt/9 - 1, kh = (kt/3)%3 - 1, kw = kt%3 - 1;
        int delta = kd*HW_ + kh*W_ + kw;
        bool v = ((unsigned)(dd+kd) < (unsigned)D_) &&
                 ((unsigned)(hh+kh) < (unsigned)H_) &&
                 ((unsigned)(ww+kw) < (unsigned)W_);
        uint4 val = {0u,0u,0u,0u};
        if (v) val = *(const uint4*)(y1n + (size_t)(p + delta)*C_ + oct*8);
        V = val;
        M = v ? 1 : 0;
    };
    auto reduceV = [&](uint4& V, int M, uint4& O4) {
        uint4 o4 = {0u,0u,0u,0u};
        if (M) {
            float r0 = fmaxf(lof(V.x)*sc[cb+0] + sf[cb+0], 0.f);
            float r1 = fmaxf(hif(V.x)*sc[cb+1] + sf[cb+1], 0.f);
            float r2 = fmaxf(lof(V.y)*sc[cb+2] + sf[cb+2], 0.f);
            float r3 = fmaxf(hif(V.y)*sc[cb+3] + sf[cb+3], 0.f);
            float r4 = fmaxf(lof(V.z)*sc[cb+4] + sf[cb+4], 0.f);
            float r5 = fmaxf(hif(V.z)*sc[cb+5] + sf[cb+5], 0.f);
            float r6 = fmaxf(lof(V.w)*sc[cb+6] + sf[cb+6], 0.f);
            float r7 = fmaxf(hif(V.w)*sc[cb+7] + sf[cb+7], 0.f);
            o4.x = (unsigned)f2b(r0) | ((unsigned)f2b(r1) << 16);
            o4.y = (unsigned)f2b(r2) | ((unsigned)f2b(r3) << 16);
            o4.z = (unsigned)f2b(r4) | ((unsigned)f2b(r5) << 16);
            o4.w = (unsigned)f2b(r6) | ((unsigned)f2b(r7) << 16);
        }
        O4 = o4;
    };

    int mh = w >> 1, nh = w & 1;
    floatx4 acc[2];
    acc[0] = (floatx4){0.f,0.f,0.f,0.f};
    acc[1] = (floatx4){0.f,0.f,0.f,0.f};

    uint4 Vv, O4cur;
    int Mm;
    stageA(0, 0);
    __syncthreads();           // sc/sf visible before prologue reduceV
    issueV(0, Vv, Mm);
    reduceV(Vv, Mm, O4cur);

    for (int kt = 0; kt < 27; ++kt) {
        int buf = kt & 1;
        __syncthreads();
        {
            int chunk = (oct>>2)*2 + (prow>>4);
            *(uint4*)&Bsb[chunk*512 + ((oct&3)*16 + ((prow&15) ^ oct))*8] = O4cur;
        }
        __syncthreads();
        if (kt < 26) { stageA(kt+1, buf^1); issueV(kt+1, Vv, Mm); }
        #pragma unroll
        for (int ks = 0; ks < 2; ++ks) {
            int swzB = (lq*16 + (lm ^ (ks*4 + lq)))*8;
            shortx8 b = *(const shortx8*)&Bsb[(ks*2 + nh)*512 + swzB];
            #pragma unroll
            for (int i = 0; i < 2; ++i) {
                shortx8 a = *(const shortx8*)&SH[buf*4096 + (ks*4 + 2*mh+i)*512 + lane*8];
                acc[i] = __builtin_amdgcn_mfma_f32_16x16x32_bf16(a, b, acc[i], 0, 0, 0);
            }
        }
        if (kt < 26) reduceV(Vv, Mm, O4cur);
    }

    #pragma unroll
    for (int i = 0; i < 2; ++i) {
        int cob = (2*mh+i)*16 + lq*4;
        #pragma unroll
        for (int r = 0; r < 4; ++r) {
            int co = cob + r;
            float bv = bias[co];
            int col = p0 + nh*16 + lm;
            y2n[(size_t)co*P_ + col] = f2b(acc[i][r] + bv);
        }
    }
}

// ---------------------------------------------------------------------------
// BN1 stats from y1t [N*P][64]: partial sums per 512-row block, then finalize
// ---------------------------------------------------------------------------
__global__ __launch_bounds__(256) void stats_partial_kernel(
    const unsigned short* __restrict__ y1t, float* __restrict__ part)
{
    int b = blockIdx.x, tid = threadIdx.x;
    int c = tid & 63, sub = tid >> 6;
    float s = 0.f, q = 0.f;
    for (int rr = 0; rr < 128; ++rr) {
        int row = b*512 + sub*128 + rr;
        float v = b2f(y1t[(size_t)row*C_ + c]);
        s += v;
        q = fmaf(v, v, q);
    }
    __shared__ float ss[256], qq[256];
    ss[tid] = s; qq[tid] = q;
    __syncthreads();
    if (tid < 64) {
        float S = ss[tid] + ss[64+tid] + ss[128+tid] + ss[192+tid];
        float Q = qq[tid] + qq[64+tid] + qq[128+tid] + qq[192+tid];
        part[b*128 + tid]      = S;
        part[b*128 + 64 + tid] = Q;
    }
}

__global__ void stats_final_kernel(
    const float* __restrict__ part,
    const float* __restrict__ gamma, const float* __restrict__ beta,
    float* __restrict__ st1)
{
    int c = threadIdx.x;  // 64 threads
    float S = 0.f, Q = 0.f;
    for (int b = 0; b < 98; ++b) {
        S += part[b*128 + c];
        Q += part[b*128 + 64 + c];
    }
    const float inv = 1.f / (float)(N_*P_);
    float m = S * inv;
    float var = Q * inv - m*m;
    float scale = rsqrtf(var + 1e-5f) * gamma[c];
    st1[c]      = scale;
    st1[64 + c] = beta[c] - m*scale;
}

// ---------------------------------------------------------------------------
__global__ __launch_bounds__(256) void bn_stats_kernel(
    const unsigned short* __restrict__ src, float* __restrict__ stats)
{
    int c   = blockIdx.x;
    int tid = threadIdx.x;
    float s = 0.f, q = 0.f;
    for (int n = 0; n < N_; ++n) {
        const unsigned short* p = src + ((size_t)n*C_ + c)*P_;
        for (int i = tid; i < P_; i += 256) {
            float v = b2f(p[i]);
            s += v;
            q = fmaf(v, v, q);
        }
    }
    #pragma unroll
    for (int o = 32; o; o >>= 1) {
        s += __shfl_down(s, o);
        q += __shfl_down(q, o);
    }
    __shared__ float sh[2][4];
    int wave = tid >> 6;
    if ((tid & 63) == 0) { sh[0][wave] = s; sh[1][wave] = q; }
    __syncthreads();
    if (tid == 0) {
        float S = sh[0][0] + sh[0][1] + sh[0][2] + sh[0][3];
        float Q = sh[1][0] + sh[1][1] + sh[1][2] + sh[1][3];
        const float inv = 1.f / (float)(N_*P_);
        float m  = S * inv;
        float var = Q * inv - m*m;
        stats[c]      = m;
        stats[C_ + c] = rsqrtf(var + 1e-5f);
    }
}

__global__ __launch_bounds__(256) void bn_add_relu_kernel(
    const unsigned short* __restrict__ y2, const float* __restrict__ x,
    const float* __restrict__ stats,
    const float* __restrict__ gamma, const float* __restrict__ beta,
    float* __restrict__ out)
{
    size_t idx = (size_t)blockIdx.x*256 + threadIdx.x;
    int c = (int)((idx / P_) % C_);
    float v = (b2f(y2[idx]) - stats[c]) * stats[C_ + c] * gamma[c] + beta[c] + x[idx];
    out[idx] = fmaxf(v, 0.f);
}

// ---------------------------------------------------------------------------
extern "C" void kernel_launch(void* const* d_in, const int* in_sizes, int n_in,
                              void* d_out, int out_size, void* d_ws, size_t ws_size,
                              hipStream_t stream) {
    const float* x     = (const float*)d_in[0];
    const float* w_off = (const float*)d_in[1];
    const float* b_off = (const float*)d_in[2];
    const float* w1    = (const float*)d_in[3];
    const float* g1    = (const float*)d_in[4];
    const float* be1   = (const float*)d_in[5];
    const float* w2    = (const float*)d_in[6];
    const float* b2    = (const float*)d_in[7];
    const float* g2    = (const float*)d_in[8];
    const float* be2   = (const float*)d_in[9];
    float* out = (float*)d_out;

    // workspace (~88 MB)
    float* st1  = (float*)d_ws;                              // 128 (scale/shift)
    float* st2  = st1 + 128;                                 // 128 (mean/rstd)
    float* part = st2 + 128;                                 // 98*128
    unsigned short* off = (unsigned short*)(part + 98*128);  // N*648*P bf16 (65 MB)
    unsigned short* xt  = off + (size_t)N_*CO_OFF_*P_;       // N*P*64 bf16 (6.4 MB)
    unsigned short* y1t = xt  + (size_t)N_*P_*C_;            // N*P*64 bf16 (6.4 MB)
    unsigned short* y2  = y1t + (size_t)N_*P_*C_;            // N*64*P bf16 (6.4 MB)
    unsigned short* A1k = y2  + (size_t)N_*C_*P_;            // 768*1728 bf16 (2.65 MB)
    unsigned short* A1t = A1k + (size_t)MP_*KK_;             // 64*1728 bf16
    unsigned short* A2t = A1t + (size_t)C_*KK_;              // 64*1728 bf16

    // prep
    transpose_xt_kernel<<<N_*(P_/64), 256, 0, stream>>>(x, xt);
    permA1k_kernel<<<(MP_*KK_+255)/256, 256, 0, stream>>>(w_off, A1k);
    perm_w_kernel<<<(C_*KK_+255)/256, 256, 0, stream>>>(w1, A1t);
    perm_w_kernel<<<(C_*KK_+255)/256, 256, 0, stream>>>(w2, A2t);

    // conv_off fused -> off (both n): main (rows 0..639) + tail (640..647)
    conv_off_fused<<<2*980, 256, 0, stream>>>(A1k, xt, b_off, off);
    conv_off_tail<<<2*196, 256, 0, stream>>>(A1k, xt, b_off, off);

    // deform fused -> y1t (both n), N=32 tiles
    deform_fused<<<N_*(P_/32), 256, 0, stream>>>(xt, off, A1t, y1t);

    // BN1 scale/shift
    stats_partial_kernel<<<98, 256, 0, stream>>>(y1t, part);
    stats_final_kernel<<<1, 64, 0, stream>>>(part, g1, be1, st1);

    // conv2 fused (BN1+ReLU on read) -> y2 (both n), N=32 tiles
    conv2_fused<<<N_*(P_/32), 256, 0, stream>>>(y1t, st1, A2t, b2, y2);

    // BN2 + residual + ReLU -> out (fp32)
    bn_stats_kernel<<<C_, 256, 0, stream>>>(y2, st2);
    bn_add_relu_kernel<<<(N_*C_*P_)/256, 256, 0, stream>>>(y2, x, st2, g2, be2, out);
}